// Round 6
// baseline (784.379 us; speedup 1.0000x reference)
//
#include <hip/hip_runtime.h>
#include <hip/hip_fp16.h>
#include <math.h>

#define BN_EPS 1e-5f
#define HF 32          // hidden features
#define BS 256         // nodes per bucket (8-bit dloc)
#define KEDGE 4096     // edges per binsort block
#define MAXNB 1024     // max buckets supported by binsort LDS
#define BCAPS 5632     // max records per bucket held in k_sortb LDS

// fast transcendentals (trans pipe; error ~1e-7 rel, fine vs 2.2e-2 threshold)
__device__ __forceinline__ float fsig(float x) {
    return __builtin_amdgcn_rcpf(1.0f + __expf(-x));
}
__device__ __forceinline__ float ftanh(float x) {
    return 1.0f - 2.0f * __builtin_amdgcn_rcpf(1.0f + __expf(2.0f * x));
}

// ================= tiny utils =================

__global__ void k_zero(int* __restrict__ p, int n) {
    int i = blockIdx.x * blockDim.x + threadIdx.x;
    if (i < n) p[i] = 0;
}

// ================= Phase A: block-local counting sort into buckets =================

__global__ __launch_bounds__(256) void k_binsort(
        const int* __restrict__ src, const int* __restrict__ dst,
        const float* __restrict__ ew, int E, int NB, int bcap,
        int* __restrict__ gcur, uint2* __restrict__ recs) {
    __shared__ uint2 srec[KEDGE];
    __shared__ unsigned short sbk[KEDGE];
    __shared__ int hist[MAXNB], excl[MAXNB], curs[MAXNB], sbase[MAXNB];

    int tid = threadIdx.x;
    int base = blockIdx.x * KEDGE;
    int cnt = min(KEDGE, E - base);

    for (int i = tid; i < NB; i += 256) hist[i] = 0;
    __syncthreads();

    for (int i = tid; i < cnt; i += 256)
        atomicAdd(&hist[dst[base + i] >> 8], 1);
    __syncthreads();

    if (tid < 64) {
        int run = 0;
        for (int c = 0; c < NB; c += 64) {
            int idx = c + tid;
            int v = (idx < NB) ? hist[idx] : 0;
            int incl = v;
#pragma unroll
            for (int o = 1; o < 64; o <<= 1) {
                int up = __shfl_up(incl, o, 64);
                if (tid >= o) incl += up;
            }
            if (idx < NB) { int e = run + incl - v; excl[idx] = e; curs[idx] = e; }
            run += __shfl(incl, 63, 64);
        }
    }
    __syncthreads();

    for (int i = tid; i < cnt; i += 256) {
        int s = src[base + i];
        int d = dst[base + i];
        float w = ew[base + i];
        int b = d >> 8;
        int pos = atomicAdd(&curs[b], 1);
        srec[pos] = make_uint2(((unsigned)s << 8) | (unsigned)(d & 255), __float_as_uint(w));
        sbk[pos] = (unsigned short)b;
    }
    __syncthreads();

    for (int b = tid; b < NB; b += 256) {
        int len = hist[b];
        sbase[b] = len ? atomicAdd(&gcur[b], len) : 0;
    }
    __syncthreads();

    for (int i = tid; i < cnt; i += 256) {
        int b = sbk[i];
        int off = sbase[b] + (i - excl[b]);
        if (off < bcap) recs[(size_t)b * bcap + off] = srec[i];
    }
}

// ================= Phase B: in-bucket sort by dst + CSR ptrs + dinv =================

__global__ __launch_bounds__(512) void k_sortb(
        uint2* __restrict__ recs, const int* __restrict__ gcur, int bcap,
        int* __restrict__ pstart, int* __restrict__ pcnt,
        float* __restrict__ dinv, int n) {
    __shared__ uint2 srec[BCAPS];
    __shared__ int hist[BS], excl[BS], curs[BS];
    __shared__ float wsum[BS];

    int b = blockIdx.x, tid = threadIdx.x;
    int cnt = min(gcur[b], bcap);
    uint2* r = recs + (size_t)b * bcap;

    if (tid < BS) { hist[tid] = 0; wsum[tid] = 1.0f; }  // self-loop weight in wsum
    __syncthreads();

    for (int i = tid; i < cnt; i += 512) {
        uint2 u = r[i];
        srec[i] = u;
        int dl = u.x & 255;
        atomicAdd(&hist[dl], 1);
        atomicAdd(&wsum[dl], __uint_as_float(u.y));
    }
    __syncthreads();

    if (tid < 64) {
        int run = 0;
        for (int c = 0; c < BS; c += 64) {
            int idx = c + tid;
            int v = hist[idx];
            int incl = v;
#pragma unroll
            for (int o = 1; o < 64; o <<= 1) {
                int up = __shfl_up(incl, o, 64);
                if (tid >= o) incl += up;
            }
            int e = run + incl - v;
            excl[idx] = e; curs[idx] = e;
            run += __shfl(incl, 63, 64);
        }
    }
    __syncthreads();

    for (int i = tid; i < cnt; i += 512) {
        uint2 u = srec[i];
        int pos = atomicAdd(&curs[u.x & 255], 1);
        r[pos] = u;
    }

    if (tid < BS) {
        int g = b * BS + tid;
        if (g < n) {
            pstart[g] = b * bcap + excl[tid];
            pcnt[g] = hist[tid];
            dinv[g] = rsqrtf(wsum[tid]);
        }
    }
}

// ================= Phase C: precompute norm per record =================

__global__ __launch_bounds__(256) void k_norm(
        uint2* __restrict__ recs, const int* __restrict__ gcur, int bcap,
        const float* __restrict__ dinv) {
    int b = blockIdx.x >> 2, q = blockIdx.x & 3;
    int cnt = min(gcur[b], bcap);
    int lo = (cnt * q) >> 2, hi = (cnt * (q + 1)) >> 2;
    uint2* r = recs + (size_t)b * bcap;
    for (int i = lo + threadIdx.x; i < hi; i += 256) {
        uint2 u = r[i];
        int s = u.x >> 8;
        int g = b * BS + (int)(u.x & 255);
        float w = __uint_as_float(u.y);
        u.y = __float_as_uint(w * dinv[s] * dinv[g]);
        r[i] = u;
    }
}

// ================= dense feature transforms (fp16 out) =================

__global__ void k_xw1_h(const float* __restrict__ x, const float* __restrict__ W,
                        __half* __restrict__ out, int n) {
    int idx = blockIdx.x * blockDim.x + threadIdx.x;
    if (idx >= n * HF) return;
    int nn = idx >> 5, f = idx & 31;
    const float4 xr = *(const float4*)(x + (size_t)nn * 4);
    float acc = xr.x * W[f] + xr.y * W[32 + f] + xr.z * W[64 + f] + xr.w * W[96 + f];
    out[idx] = __float2half(acc);
}

__global__ void k_xw2_h(const float* __restrict__ Hin, const float* __restrict__ W,
                        __half* __restrict__ out, int n) {
    __shared__ float sW[32 * 32];
    __shared__ float sH[8][32];
    int tid = threadIdx.x;
    for (int i = tid; i < 1024; i += 256) sW[i] = W[i];
    int r = tid >> 5, f = tid & 31;
    int nn = blockIdx.x * 8 + r;
    if (nn < n) sH[r][f] = Hin[(size_t)nn * HF + f];
    __syncthreads();
    if (nn >= n) return;
    float acc = 0.0f;
#pragma unroll
    for (int k = 0; k < 32; ++k) acc += sH[r][k] * sW[k * 32 + f];
    out[(size_t)nn * HF + f] = __float2half(acc);
}

// ================= gather: per-node CSR aggregation + fused epilogue =================

__global__ __launch_bounds__(256) void k_gather(
        const uint2* __restrict__ recs, const int* __restrict__ pstart,
        const int* __restrict__ pcnt, const float* __restrict__ dinv,
        const __half* __restrict__ A,
        const float* __restrict__ bias, const float* __restrict__ gamma,
        const float* __restrict__ beta, const float* __restrict__ mean,
        const float* __restrict__ var,
        float* __restrict__ Hout, int n) {
    int g = blockIdx.x * 64 + (threadIdx.x >> 2);
    int lane = threadIdx.x & 3;
    if (g >= n) return;

    float dig = dinv[g];
    float sl = dig * dig;
    uint4 srow = ((const uint4*)(A + ((size_t)g << 5)))[lane];
    float acc[8];
    {
        const __half2* h = (const __half2*)&srow;
#pragma unroll
        for (int k = 0; k < 4; ++k) {
            float2 f = __half22float2(h[k]);
            acc[2 * k] = sl * f.x; acc[2 * k + 1] = sl * f.y;
        }
    }

    int cn = pcnt[g];
    const uint2* r = recs + pstart[g];
    int e = 0;
    for (; e + 2 <= cn; e += 2) {
        uint2 r0 = r[e], r1 = r[e + 1];
        uint4 row0 = ((const uint4*)(A + ((size_t)(r0.x >> 8) << 5)))[lane];
        uint4 row1 = ((const uint4*)(A + ((size_t)(r1.x >> 8) << 5)))[lane];
        float n0 = __uint_as_float(r0.y), n1 = __uint_as_float(r1.y);
        const __half2* h0 = (const __half2*)&row0;
        const __half2* h1 = (const __half2*)&row1;
#pragma unroll
        for (int k = 0; k < 4; ++k) {
            float2 f0 = __half22float2(h0[k]);
            float2 f1 = __half22float2(h1[k]);
            acc[2 * k]     += n0 * f0.x + n1 * f1.x;
            acc[2 * k + 1] += n0 * f0.y + n1 * f1.y;
        }
    }
    if (e < cn) {
        uint2 r0 = r[e];
        uint4 row0 = ((const uint4*)(A + ((size_t)(r0.x >> 8) << 5)))[lane];
        float n0 = __uint_as_float(r0.y);
        const __half2* h0 = (const __half2*)&row0;
#pragma unroll
        for (int k = 0; k < 4; ++k) {
            float2 f0 = __half22float2(h0[k]);
            acc[2 * k]     += n0 * f0.x;
            acc[2 * k + 1] += n0 * f0.y;
        }
    }

    int fq = lane * 8;
    float o[8];
#pragma unroll
    for (int k = 0; k < 8; ++k) {
        float v = fmaxf(acc[k] + bias[fq + k], 0.0f);
        o[k] = (v - mean[fq + k]) * gamma[fq + k] * rsqrtf(var[fq + k] + BN_EPS) + beta[fq + k];
    }
    float* dst = Hout + ((size_t)g << 5) + fq;
    *(float4*)dst = make_float4(o[0], o[1], o[2], o[3]);
    *(float4*)(dst + 4) = make_float4(o[4], o[5], o[6], o[7]);
}

// ================= fused head: LSTM1 + LSTM2 + linear =================
// One thread per node, FULLY UNROLLED: H1 lives in registers (no LDS, no
// barriers). Weights on the scalar path; transcendentals on the trans pipe.

__global__ __launch_bounds__(256) void k_head(
        const float* __restrict__ h1, const float* __restrict__ h2,
        const float* __restrict__ x,
        const float* __restrict__ wih1, const float* __restrict__ bih1, const float* __restrict__ bhh1,
        const float* __restrict__ wih2, const float* __restrict__ bih2, const float* __restrict__ bhh2,
        const float* __restrict__ lw, const float* __restrict__ lb,
        float* __restrict__ out, int n) {
    int nn = blockIdx.x * 256 + threadIdx.x;
    if (nn >= n) return;

    float skip[64];
    {
        const float4* a = (const float4*)(h1 + (size_t)nn * HF);
        const float4* b = (const float4*)(h2 + (size_t)nn * HF);
#pragma unroll
        for (int q = 0; q < 8; ++q) {
            float4 v = a[q];
            skip[4 * q] = v.x; skip[4 * q + 1] = v.y; skip[4 * q + 2] = v.z; skip[4 * q + 3] = v.w;
        }
#pragma unroll
        for (int q = 0; q < 8; ++q) {
            float4 v = b[q];
            skip[32 + 4 * q] = v.x; skip[33 + 4 * q] = v.y; skip[34 + 4 * q] = v.z; skip[35 + 4 * q] = v.w;
        }
    }

    // LSTM1 (torch gate rows: i=0..31, g=64..95, o=96..127), fully unrolled
    float H1v[32];
#pragma unroll
    for (int j = 0; j < 32; ++j) {
        const float4* wi = (const float4*)(wih1 + (size_t)j * 64);
        const float4* wg = (const float4*)(wih1 + (size_t)(64 + j) * 64);
        const float4* wo = (const float4*)(wih1 + (size_t)(96 + j) * 64);
        float gi = bih1[j] + bhh1[j];
        float gg = bih1[64 + j] + bhh1[64 + j];
        float go = bih1[96 + j] + bhh1[96 + j];
#pragma unroll
        for (int q = 0; q < 16; ++q) {
            float4 a = wi[q], b = wg[q], c = wo[q];
            float s0 = skip[4 * q], s1 = skip[4 * q + 1], s2 = skip[4 * q + 2], s3 = skip[4 * q + 3];
            gi += a.x * s0 + a.y * s1 + a.z * s2 + a.w * s3;
            gg += b.x * s0 + b.y * s1 + b.z * s2 + b.w * s3;
            go += c.x * s0 + c.y * s1 + c.z * s2 + c.w * s3;
        }
        float cc = fsig(gi) * ftanh(gg);
        H1v[j] = fsig(go) * ftanh(cc);
    }

    float oa = lb[0];
#pragma unroll
    for (int k = 0; k < 32; ++k) oa += fmaxf(H1v[k], 0.0f) * lw[k];

    // LSTM2 over H1 (32-wide), fully unrolled, head dot accumulated on the fly
#pragma unroll
    for (int j = 0; j < 32; ++j) {
        const float4* wi = (const float4*)(wih2 + (size_t)j * 32);
        const float4* wg = (const float4*)(wih2 + (size_t)(64 + j) * 32);
        const float4* wo = (const float4*)(wih2 + (size_t)(96 + j) * 32);
        float gi = bih2[j] + bhh2[j];
        float gg = bih2[64 + j] + bhh2[64 + j];
        float go = bih2[96 + j] + bhh2[96 + j];
#pragma unroll
        for (int q = 0; q < 8; ++q) {
            float4 a = wi[q], b = wg[q], c = wo[q];
            float s0 = H1v[4 * q], s1 = H1v[4 * q + 1], s2 = H1v[4 * q + 2], s3 = H1v[4 * q + 3];
            gi += a.x * s0 + a.y * s1 + a.z * s2 + a.w * s3;
            gg += b.x * s0 + b.y * s1 + b.z * s2 + b.w * s3;
            go += c.x * s0 + c.y * s1 + c.z * s2 + c.w * s3;
        }
        float cc = fsig(gi) * ftanh(gg);
        float hh = fsig(go) * ftanh(cc);
        oa += fmaxf(hh, 0.0f) * lw[32 + j];
    }

    const float4 xv = *(const float4*)(x + (size_t)nn * 4);
    oa += fmaxf(xv.x, 0.0f) * lw[64] + fmaxf(xv.y, 0.0f) * lw[65] +
          fmaxf(xv.z, 0.0f) * lw[66] + fmaxf(xv.w, 0.0f) * lw[67];
    out[nn] = oa;
}

// ================= fallback (atomic scatter, fp32) =================

__global__ void k_initdeg(float* __restrict__ deg, int n) {
    int i = blockIdx.x * blockDim.x + threadIdx.x;
    if (i < n) deg[i] = 1.0f;
}

__global__ void k_deg_only(const int* __restrict__ dst, const float* __restrict__ ew,
                           float* __restrict__ deg, int E) {
    int e = blockIdx.x * blockDim.x + threadIdx.x;
    if (e < E) atomicAdd(&deg[dst[e]], ew[e]);
}

__global__ void k_dinv_f(float* __restrict__ deg, int n) {
    int i = blockIdx.x * blockDim.x + threadIdx.x;
    if (i < n) {
        float d = deg[i];
        deg[i] = d > 0.0f ? rsqrtf(d) : 0.0f;
    }
}

__global__ void k_xw1_f(const float* __restrict__ x, const float* __restrict__ W,
                        float* __restrict__ out, int n) {
    int idx = blockIdx.x * blockDim.x + threadIdx.x;
    if (idx >= n * HF) return;
    int nn = idx >> 5, f = idx & 31;
    const float4 xr = *(const float4*)(x + (size_t)nn * 4);
    out[idx] = xr.x * W[f] + xr.y * W[32 + f] + xr.z * W[64 + f] + xr.w * W[96 + f];
}

__global__ void k_xw2_f(const float* __restrict__ Hin, const float* __restrict__ W,
                        float* __restrict__ out, int n) {
    __shared__ float sW[32 * 32];
    __shared__ float sH[8][32];
    int tid = threadIdx.x;
    for (int i = tid; i < 1024; i += 256) sW[i] = W[i];
    int r = tid >> 5, f = tid & 31;
    int nn = blockIdx.x * 8 + r;
    if (nn < n) sH[r][f] = Hin[(size_t)nn * HF + f];
    __syncthreads();
    if (nn >= n) return;
    float acc = 0.0f;
#pragma unroll
    for (int k = 0; k < 32; ++k) acc += sH[r][k] * sW[k * 32 + f];
    out[(size_t)nn * HF + f] = acc;
}

__global__ void k_selfloop(const float* __restrict__ A, const float* __restrict__ dinv,
                           float* __restrict__ B, int n) {
    int idx = blockIdx.x * blockDim.x + threadIdx.x;
    if (idx >= n * HF) return;
    int nn = idx >> 5;
    float di = dinv[nn];
    B[idx] = di * di * A[idx];
}

__global__ void k_scatter(const int* __restrict__ src, const int* __restrict__ dst,
                          const float* __restrict__ ew, const float* __restrict__ dinv,
                          const float* __restrict__ A, float* __restrict__ B, int total) {
    int idx = blockIdx.x * blockDim.x + threadIdx.x;
    if (idx >= total) return;
    int e = idx >> 5, f = idx & 31;
    int s = src[e], d = dst[e];
    float norm = dinv[s] * ew[e] * dinv[d];
    atomicAdd(&B[d * HF + f], norm * A[s * HF + f]);
}

__global__ void k_post(const float* __restrict__ B, const float* __restrict__ bias,
                       const float* __restrict__ gamma, const float* __restrict__ beta,
                       const float* __restrict__ mean, const float* __restrict__ var,
                       float* __restrict__ Hout, int n) {
    int idx = blockIdx.x * blockDim.x + threadIdx.x;
    if (idx >= n * HF) return;
    int f = idx & 31;
    float v = fmaxf(B[idx] + bias[f], 0.0f);
    float sc = gamma[f] * rsqrtf(var[f] + BN_EPS);
    Hout[idx] = (v - mean[f]) * sc + beta[f];
}

// ================= launch =================

extern "C" void kernel_launch(void* const* d_in, const int* in_sizes, int n_in,
                              void* d_out, int out_size, void* d_ws, size_t ws_size,
                              hipStream_t stream) {
    const float* x   = (const float*)d_in[0];
    const int*   ei  = (const int*)d_in[1];
    const float* ew  = (const float*)d_in[2];
    const float* g1w = (const float*)d_in[3];
    const float* g1b = (const float*)d_in[4];
    const float* g2w = (const float*)d_in[5];
    const float* g2b = (const float*)d_in[6];
    const float* bn1g = (const float*)d_in[7];
    const float* bn1b = (const float*)d_in[8];
    const float* bn1m = (const float*)d_in[9];
    const float* bn1v = (const float*)d_in[10];
    const float* bn2g = (const float*)d_in[11];
    const float* bn2b = (const float*)d_in[12];
    const float* bn2m = (const float*)d_in[13];
    const float* bn2v = (const float*)d_in[14];
    const float* w1ih = (const float*)d_in[15];
    const float* b1ih = (const float*)d_in[17];
    const float* b1hh = (const float*)d_in[18];
    const float* w2ih = (const float*)d_in[19];
    const float* b2ih = (const float*)d_in[21];
    const float* b2hh = (const float*)d_in[22];
    const float* lw   = (const float*)d_in[23];
    const float* lb   = (const float*)d_in[24];
    float* out = (float*)d_out;

    const int N = in_sizes[0] / 4;
    const int E = in_sizes[2];
    const int* src = ei;
    const int* dst = ei + E;

    const int T = 256;
    const int NB = (N + BS - 1) / BS;
    long long meanb = ((long long)BS * E) / (N > 0 ? N : 1);
    int bcap = (int)(meanb + meanb / 4 + 128);

    // workspace layout (256B-aligned regions)
    char* p = (char*)d_ws;
    auto alloc = [&](size_t bytes) { char* q = p; p += (bytes + 255) & ~(size_t)255; return q; };
    int*      gcur   = (int*)alloc(sizeof(int) * NB);
    uint2*    recs   = (uint2*)alloc(sizeof(uint2) * (size_t)NB * bcap);
    float*    dinv   = (float*)alloc(sizeof(float) * N);
    int*      pstart = (int*)alloc(sizeof(int) * N);
    int*      pcnt   = (int*)alloc(sizeof(int) * N);
    __half*   A      = (__half*)alloc(sizeof(__half) * (size_t)N * HF);
    float*    C      = (float*)alloc(sizeof(float) * (size_t)N * HF);   // h1
    float*    B2     = (float*)alloc(sizeof(float) * (size_t)N * HF);   // h2
    size_t need = (size_t)(p - (char*)d_ws);

    int bN  = (N + T - 1) / T;
    int bE  = (E + T - 1) / T;
    int bNF = (N * HF + T - 1) / T;
    int bN8 = (N + 7) / 8;
    int bG  = (N + 63) / 64;
    int bH  = (N + 255) / 256;
    int bBin = (E + KEDGE - 1) / KEDGE;

    if (ws_size >= need && NB <= MAXNB && bcap <= BCAPS && N <= (1 << 24)) {
        // ---- build ----
        k_zero<<<(NB + T - 1) / T, T, 0, stream>>>(gcur, NB);
        k_binsort<<<bBin, T, 0, stream>>>(src, dst, ew, E, NB, bcap, gcur, recs);
        k_sortb<<<NB, 512, 0, stream>>>(recs, gcur, bcap, pstart, pcnt, dinv, N);
        k_norm<<<NB * 4, T, 0, stream>>>(recs, gcur, bcap, dinv);

        // ---- layer 1 ----
        k_xw1_h<<<bNF, T, 0, stream>>>(x, g1w, A, N);
        k_gather<<<bG, T, 0, stream>>>(recs, pstart, pcnt, dinv, A,
                                       g1b, bn1g, bn1b, bn1m, bn1v, C, N);
        // ---- layer 2 ----
        k_xw2_h<<<bN8, T, 0, stream>>>(C, g2w, A, N);
        k_gather<<<bG, T, 0, stream>>>(recs, pstart, pcnt, dinv, A,
                                       g2b, bn2g, bn2b, bn2m, bn2v, B2, N);
        // ---- head ----
        k_head<<<bH, T, 0, stream>>>(C, B2, x, w1ih, b1ih, b1hh, w2ih, b2ih, b2hh,
                                     lw, lb, out, N);
    } else {
        // ---- fallback: atomic scatter, fp32 ----
        size_t Npad = ((size_t)N + 255) & ~(size_t)255;
        float* fdinv = (float*)d_ws;
        float* fA = fdinv + Npad;
        float* fB = fA + (size_t)N * HF;
        float* fC = fB + (size_t)N * HF;
        int bEF = (int)(((long long)E * HF + T - 1) / T);

        k_initdeg<<<bN, T, 0, stream>>>(fdinv, N);
        k_deg_only<<<bE, T, 0, stream>>>(dst, ew, fdinv, E);
        k_dinv_f<<<bN, T, 0, stream>>>(fdinv, N);

        k_xw1_f<<<bNF, T, 0, stream>>>(x, g1w, fA, N);
        k_selfloop<<<bNF, T, 0, stream>>>(fA, fdinv, fB, N);
        k_scatter<<<bEF, T, 0, stream>>>(src, dst, ew, fdinv, fA, fB, E * HF);
        k_post<<<bNF, T, 0, stream>>>(fB, g1b, bn1g, bn1b, bn1m, bn1v, fC, N);

        k_xw2_f<<<bN8, T, 0, stream>>>(fC, g2w, fA, N);
        k_selfloop<<<bNF, T, 0, stream>>>(fA, fdinv, fB, N);
        k_scatter<<<bEF, T, 0, stream>>>(src, dst, ew, fdinv, fA, fB, E * HF);
        k_post<<<bNF, T, 0, stream>>>(fB, g2b, bn2g, bn2b, bn2m, bn2v, fB, N);

        k_head<<<bH, T, 0, stream>>>(fC, fB, x, w1ih, b1ih, b1hh, w2ih, b2ih, b2hh,
                                     lw, lb, out, N);
    }
}

// Round 7
// 527.132 us; speedup vs baseline: 1.4880x; 1.4880x over previous
//
#include <hip/hip_runtime.h>
#include <hip/hip_fp16.h>
#include <math.h>

#define BN_EPS 1e-5f
#define HF 32          // hidden features
#define BS 256         // nodes per bucket (8-bit dloc)
#define KEDGE 4096     // edges per binsort block
#define MAXNB 1024     // max buckets supported by binsort LDS
#define BCAPS 5632     // max records per bucket held in k_sortb LDS

// fast transcendentals (trans pipe; error ~1e-7 rel, fine vs 2.2e-2 threshold)
__device__ __forceinline__ float fsig(float x) {
    return __builtin_amdgcn_rcpf(1.0f + __expf(-x));
}
__device__ __forceinline__ float ftanh(float x) {
    return 1.0f - 2.0f * __builtin_amdgcn_rcpf(1.0f + __expf(2.0f * x));
}

// ================= tiny utils =================

__global__ void k_zero(int* __restrict__ p, int n) {
    int i = blockIdx.x * blockDim.x + threadIdx.x;
    if (i < n) p[i] = 0;
}

// ================= Phase A: block-local counting sort into buckets =================

__global__ __launch_bounds__(256) void k_binsort(
        const int* __restrict__ src, const int* __restrict__ dst,
        const float* __restrict__ ew, int E, int NB, int bcap,
        int* __restrict__ gcur, uint2* __restrict__ recs) {
    __shared__ uint2 srec[KEDGE];
    __shared__ unsigned short sbk[KEDGE];
    __shared__ int hist[MAXNB], excl[MAXNB], curs[MAXNB], sbase[MAXNB];

    int tid = threadIdx.x;
    int base = blockIdx.x * KEDGE;
    int cnt = min(KEDGE, E - base);

    for (int i = tid; i < NB; i += 256) hist[i] = 0;
    __syncthreads();

    for (int i = tid; i < cnt; i += 256)
        atomicAdd(&hist[dst[base + i] >> 8], 1);
    __syncthreads();

    if (tid < 64) {
        int run = 0;
        for (int c = 0; c < NB; c += 64) {
            int idx = c + tid;
            int v = (idx < NB) ? hist[idx] : 0;
            int incl = v;
#pragma unroll
            for (int o = 1; o < 64; o <<= 1) {
                int up = __shfl_up(incl, o, 64);
                if (tid >= o) incl += up;
            }
            if (idx < NB) { int e = run + incl - v; excl[idx] = e; curs[idx] = e; }
            run += __shfl(incl, 63, 64);
        }
    }
    __syncthreads();

    for (int i = tid; i < cnt; i += 256) {
        int s = src[base + i];
        int d = dst[base + i];
        float w = ew[base + i];
        int b = d >> 8;
        int pos = atomicAdd(&curs[b], 1);
        srec[pos] = make_uint2(((unsigned)s << 8) | (unsigned)(d & 255), __float_as_uint(w));
        sbk[pos] = (unsigned short)b;
    }
    __syncthreads();

    for (int b = tid; b < NB; b += 256) {
        int len = hist[b];
        sbase[b] = len ? atomicAdd(&gcur[b], len) : 0;
    }
    __syncthreads();

    for (int i = tid; i < cnt; i += 256) {
        int b = sbk[i];
        int off = sbase[b] + (i - excl[b]);
        if (off < bcap) recs[(size_t)b * bcap + off] = srec[i];
    }
}

// ================= Phase B: in-bucket sort by dst + CSR ptrs + dinv =================

__global__ __launch_bounds__(512) void k_sortb(
        uint2* __restrict__ recs, const int* __restrict__ gcur, int bcap,
        int* __restrict__ pstart, int* __restrict__ pcnt,
        float* __restrict__ dinv, int n) {
    __shared__ uint2 srec[BCAPS];
    __shared__ int hist[BS], excl[BS], curs[BS];
    __shared__ float wsum[BS];

    int b = blockIdx.x, tid = threadIdx.x;
    int cnt = min(gcur[b], bcap);
    uint2* r = recs + (size_t)b * bcap;

    if (tid < BS) { hist[tid] = 0; wsum[tid] = 1.0f; }  // self-loop weight in wsum
    __syncthreads();

    for (int i = tid; i < cnt; i += 512) {
        uint2 u = r[i];
        srec[i] = u;
        int dl = u.x & 255;
        atomicAdd(&hist[dl], 1);
        atomicAdd(&wsum[dl], __uint_as_float(u.y));
    }
    __syncthreads();

    if (tid < 64) {
        int run = 0;
        for (int c = 0; c < BS; c += 64) {
            int idx = c + tid;
            int v = hist[idx];
            int incl = v;
#pragma unroll
            for (int o = 1; o < 64; o <<= 1) {
                int up = __shfl_up(incl, o, 64);
                if (tid >= o) incl += up;
            }
            int e = run + incl - v;
            excl[idx] = e; curs[idx] = e;
            run += __shfl(incl, 63, 64);
        }
    }
    __syncthreads();

    for (int i = tid; i < cnt; i += 512) {
        uint2 u = srec[i];
        int pos = atomicAdd(&curs[u.x & 255], 1);
        r[pos] = u;
    }

    if (tid < BS) {
        int g = b * BS + tid;
        if (g < n) {
            pstart[g] = b * bcap + excl[tid];
            pcnt[g] = hist[tid];
            dinv[g] = rsqrtf(wsum[tid]);
        }
    }
}

// ================= Phase C: precompute norm per record =================

__global__ __launch_bounds__(256) void k_norm(
        uint2* __restrict__ recs, const int* __restrict__ gcur, int bcap,
        const float* __restrict__ dinv) {
    int b = blockIdx.x >> 2, q = blockIdx.x & 3;
    int cnt = min(gcur[b], bcap);
    int lo = (cnt * q) >> 2, hi = (cnt * (q + 1)) >> 2;
    uint2* r = recs + (size_t)b * bcap;
    for (int i = lo + threadIdx.x; i < hi; i += 256) {
        uint2 u = r[i];
        int s = u.x >> 8;
        int g = b * BS + (int)(u.x & 255);
        float w = __uint_as_float(u.y);
        u.y = __float_as_uint(w * dinv[s] * dinv[g]);
        r[i] = u;
    }
}

// ================= dense feature transforms (fp16 out) =================

__global__ void k_xw1_h(const float* __restrict__ x, const float* __restrict__ W,
                        __half* __restrict__ out, int n) {
    int idx = blockIdx.x * blockDim.x + threadIdx.x;
    if (idx >= n * HF) return;
    int nn = idx >> 5, f = idx & 31;
    const float4 xr = *(const float4*)(x + (size_t)nn * 4);
    float acc = xr.x * W[f] + xr.y * W[32 + f] + xr.z * W[64 + f] + xr.w * W[96 + f];
    out[idx] = __float2half(acc);
}

__global__ void k_xw2_h(const float* __restrict__ Hin, const float* __restrict__ W,
                        __half* __restrict__ out, int n) {
    __shared__ float sW[32 * 32];
    __shared__ float sH[8][32];
    int tid = threadIdx.x;
    for (int i = tid; i < 1024; i += 256) sW[i] = W[i];
    int r = tid >> 5, f = tid & 31;
    int nn = blockIdx.x * 8 + r;
    if (nn < n) sH[r][f] = Hin[(size_t)nn * HF + f];
    __syncthreads();
    if (nn >= n) return;
    float acc = 0.0f;
#pragma unroll
    for (int k = 0; k < 32; ++k) acc += sH[r][k] * sW[k * 32 + f];
    out[(size_t)nn * HF + f] = __float2half(acc);
}

// ================= gather: per-node CSR aggregation + fused epilogue =================

__global__ __launch_bounds__(256) void k_gather(
        const uint2* __restrict__ recs, const int* __restrict__ pstart,
        const int* __restrict__ pcnt, const float* __restrict__ dinv,
        const __half* __restrict__ A,
        const float* __restrict__ bias, const float* __restrict__ gamma,
        const float* __restrict__ beta, const float* __restrict__ mean,
        const float* __restrict__ var,
        float* __restrict__ Hout, int n) {
    int g = blockIdx.x * 64 + (threadIdx.x >> 2);
    int lane = threadIdx.x & 3;
    if (g >= n) return;

    float dig = dinv[g];
    float sl = dig * dig;
    uint4 srow = ((const uint4*)(A + ((size_t)g << 5)))[lane];
    float acc[8];
    {
        const __half2* h = (const __half2*)&srow;
#pragma unroll
        for (int k = 0; k < 4; ++k) {
            float2 f = __half22float2(h[k]);
            acc[2 * k] = sl * f.x; acc[2 * k + 1] = sl * f.y;
        }
    }

    int cn = pcnt[g];
    const uint2* r = recs + pstart[g];
    int e = 0;
    for (; e + 2 <= cn; e += 2) {
        uint2 r0 = r[e], r1 = r[e + 1];
        uint4 row0 = ((const uint4*)(A + ((size_t)(r0.x >> 8) << 5)))[lane];
        uint4 row1 = ((const uint4*)(A + ((size_t)(r1.x >> 8) << 5)))[lane];
        float n0 = __uint_as_float(r0.y), n1 = __uint_as_float(r1.y);
        const __half2* h0 = (const __half2*)&row0;
        const __half2* h1 = (const __half2*)&row1;
#pragma unroll
        for (int k = 0; k < 4; ++k) {
            float2 f0 = __half22float2(h0[k]);
            float2 f1 = __half22float2(h1[k]);
            acc[2 * k]     += n0 * f0.x + n1 * f1.x;
            acc[2 * k + 1] += n0 * f0.y + n1 * f1.y;
        }
    }
    if (e < cn) {
        uint2 r0 = r[e];
        uint4 row0 = ((const uint4*)(A + ((size_t)(r0.x >> 8) << 5)))[lane];
        float n0 = __uint_as_float(r0.y);
        const __half2* h0 = (const __half2*)&row0;
#pragma unroll
        for (int k = 0; k < 4; ++k) {
            float2 f0 = __half22float2(h0[k]);
            acc[2 * k]     += n0 * f0.x;
            acc[2 * k + 1] += n0 * f0.y;
        }
    }

    int fq = lane * 8;
    float o[8];
#pragma unroll
    for (int k = 0; k < 8; ++k) {
        float v = fmaxf(acc[k] + bias[fq + k], 0.0f);
        o[k] = (v - mean[fq + k]) * gamma[fq + k] * rsqrtf(var[fq + k] + BN_EPS) + beta[fq + k];
    }
    float* dst = Hout + ((size_t)g << 5) + fq;
    *(float4*)dst = make_float4(o[0], o[1], o[2], o[3]);
    *(float4*)(dst + 4) = make_float4(o[4], o[5], o[6], o[7]);
}

// ================= fused head: LSTM1 + LSTM2 + linear =================
// Round-5 structure (rolled j-loops, H1 via private LDS slot — small code,
// low VGPR) + fast transcendentals on the trans pipe.

__global__ __launch_bounds__(256) void k_head(
        const float* __restrict__ h1, const float* __restrict__ h2,
        const float* __restrict__ x,
        const float* __restrict__ wih1, const float* __restrict__ bih1, const float* __restrict__ bhh1,
        const float* __restrict__ wih2, const float* __restrict__ bih2, const float* __restrict__ bhh2,
        const float* __restrict__ lw, const float* __restrict__ lb,
        float* __restrict__ out, int n) {
    __shared__ float sH1[32 * 256];
    int tid = threadIdx.x;
    int nn = blockIdx.x * 256 + tid;
    bool act = nn < n;

    float skip[64];
    if (act) {
        const float4* a = (const float4*)(h1 + (size_t)nn * HF);
        const float4* b = (const float4*)(h2 + (size_t)nn * HF);
#pragma unroll
        for (int q = 0; q < 8; ++q) {
            float4 v = a[q];
            skip[4 * q] = v.x; skip[4 * q + 1] = v.y; skip[4 * q + 2] = v.z; skip[4 * q + 3] = v.w;
        }
#pragma unroll
        for (int q = 0; q < 8; ++q) {
            float4 v = b[q];
            skip[32 + 4 * q] = v.x; skip[33 + 4 * q] = v.y; skip[34 + 4 * q] = v.z; skip[35 + 4 * q] = v.w;
        }
    } else {
#pragma unroll
        for (int q = 0; q < 64; ++q) skip[q] = 0.0f;
    }

#pragma unroll 2
    for (int j = 0; j < 32; ++j) {
        const float4* wi = (const float4*)(wih1 + (size_t)j * 64);
        const float4* wg = (const float4*)(wih1 + (size_t)(64 + j) * 64);
        const float4* wo = (const float4*)(wih1 + (size_t)(96 + j) * 64);
        float gi = bih1[j] + bhh1[j];
        float gg = bih1[64 + j] + bhh1[64 + j];
        float go = bih1[96 + j] + bhh1[96 + j];
#pragma unroll
        for (int q = 0; q < 16; ++q) {
            float4 a = wi[q], b = wg[q], c = wo[q];
            float s0 = skip[4 * q], s1 = skip[4 * q + 1], s2 = skip[4 * q + 2], s3 = skip[4 * q + 3];
            gi += a.x * s0 + a.y * s1 + a.z * s2 + a.w * s3;
            gg += b.x * s0 + b.y * s1 + b.z * s2 + b.w * s3;
            go += c.x * s0 + c.y * s1 + c.z * s2 + c.w * s3;
        }
        float cc = fsig(gi) * ftanh(gg);
        float hh = fsig(go) * ftanh(cc);
        sH1[j * 256 + tid] = hh;
    }

    float H1v[32];
#pragma unroll
    for (int k = 0; k < 32; ++k) H1v[k] = sH1[k * 256 + tid];

    float oa = lb[0];
#pragma unroll
    for (int k = 0; k < 32; ++k) oa += fmaxf(H1v[k], 0.0f) * lw[k];

#pragma unroll 2
    for (int j = 0; j < 32; ++j) {
        const float4* wi = (const float4*)(wih2 + (size_t)j * 32);
        const float4* wg = (const float4*)(wih2 + (size_t)(64 + j) * 32);
        const float4* wo = (const float4*)(wih2 + (size_t)(96 + j) * 32);
        float gi = bih2[j] + bhh2[j];
        float gg = bih2[64 + j] + bhh2[64 + j];
        float go = bih2[96 + j] + bhh2[96 + j];
#pragma unroll
        for (int q = 0; q < 8; ++q) {
            float4 a = wi[q], b = wg[q], c = wo[q];
            float s0 = H1v[4 * q], s1 = H1v[4 * q + 1], s2 = H1v[4 * q + 2], s3 = H1v[4 * q + 3];
            gi += a.x * s0 + a.y * s1 + a.z * s2 + a.w * s3;
            gg += b.x * s0 + b.y * s1 + b.z * s2 + b.w * s3;
            go += c.x * s0 + c.y * s1 + c.z * s2 + c.w * s3;
        }
        float cc = fsig(gi) * ftanh(gg);
        float hh = fsig(go) * ftanh(cc);
        oa += fmaxf(hh, 0.0f) * lw[32 + j];
    }

    if (act) {
        const float4 xv = *(const float4*)(x + (size_t)nn * 4);
        oa += fmaxf(xv.x, 0.0f) * lw[64] + fmaxf(xv.y, 0.0f) * lw[65] +
              fmaxf(xv.z, 0.0f) * lw[66] + fmaxf(xv.w, 0.0f) * lw[67];
        out[nn] = oa;
    }
}

// ================= fallback (atomic scatter, fp32) =================

__global__ void k_initdeg(float* __restrict__ deg, int n) {
    int i = blockIdx.x * blockDim.x + threadIdx.x;
    if (i < n) deg[i] = 1.0f;
}

__global__ void k_deg_only(const int* __restrict__ dst, const float* __restrict__ ew,
                           float* __restrict__ deg, int E) {
    int e = blockIdx.x * blockDim.x + threadIdx.x;
    if (e < E) atomicAdd(&deg[dst[e]], ew[e]);
}

__global__ void k_dinv_f(float* __restrict__ deg, int n) {
    int i = blockIdx.x * blockDim.x + threadIdx.x;
    if (i < n) {
        float d = deg[i];
        deg[i] = d > 0.0f ? rsqrtf(d) : 0.0f;
    }
}

__global__ void k_xw1_f(const float* __restrict__ x, const float* __restrict__ W,
                        float* __restrict__ out, int n) {
    int idx = blockIdx.x * blockDim.x + threadIdx.x;
    if (idx >= n * HF) return;
    int nn = idx >> 5, f = idx & 31;
    const float4 xr = *(const float4*)(x + (size_t)nn * 4);
    out[idx] = xr.x * W[f] + xr.y * W[32 + f] + xr.z * W[64 + f] + xr.w * W[96 + f];
}

__global__ void k_xw2_f(const float* __restrict__ Hin, const float* __restrict__ W,
                        float* __restrict__ out, int n) {
    __shared__ float sW[32 * 32];
    __shared__ float sH[8][32];
    int tid = threadIdx.x;
    for (int i = tid; i < 1024; i += 256) sW[i] = W[i];
    int r = tid >> 5, f = tid & 31;
    int nn = blockIdx.x * 8 + r;
    if (nn < n) sH[r][f] = Hin[(size_t)nn * HF + f];
    __syncthreads();
    if (nn >= n) return;
    float acc = 0.0f;
#pragma unroll
    for (int k = 0; k < 32; ++k) acc += sH[r][k] * sW[k * 32 + f];
    out[(size_t)nn * HF + f] = acc;
}

__global__ void k_selfloop(const float* __restrict__ A, const float* __restrict__ dinv,
                           float* __restrict__ B, int n) {
    int idx = blockIdx.x * blockDim.x + threadIdx.x;
    if (idx >= n * HF) return;
    int nn = idx >> 5;
    float di = dinv[nn];
    B[idx] = di * di * A[idx];
}

__global__ void k_scatter(const int* __restrict__ src, const int* __restrict__ dst,
                          const float* __restrict__ ew, const float* __restrict__ dinv,
                          const float* __restrict__ A, float* __restrict__ B, int total) {
    int idx = blockIdx.x * blockDim.x + threadIdx.x;
    if (idx >= total) return;
    int e = idx >> 5, f = idx & 31;
    int s = src[e], d = dst[e];
    float norm = dinv[s] * ew[e] * dinv[d];
    atomicAdd(&B[d * HF + f], norm * A[s * HF + f]);
}

__global__ void k_post(const float* __restrict__ B, const float* __restrict__ bias,
                       const float* __restrict__ gamma, const float* __restrict__ beta,
                       const float* __restrict__ mean, const float* __restrict__ var,
                       float* __restrict__ Hout, int n) {
    int idx = blockIdx.x * blockDim.x + threadIdx.x;
    if (idx >= n * HF) return;
    int f = idx & 31;
    float v = fmaxf(B[idx] + bias[f], 0.0f);
    float sc = gamma[f] * rsqrtf(var[f] + BN_EPS);
    Hout[idx] = (v - mean[f]) * sc + beta[f];
}

// ================= launch =================

extern "C" void kernel_launch(void* const* d_in, const int* in_sizes, int n_in,
                              void* d_out, int out_size, void* d_ws, size_t ws_size,
                              hipStream_t stream) {
    const float* x   = (const float*)d_in[0];
    const int*   ei  = (const int*)d_in[1];
    const float* ew  = (const float*)d_in[2];
    const float* g1w = (const float*)d_in[3];
    const float* g1b = (const float*)d_in[4];
    const float* g2w = (const float*)d_in[5];
    const float* g2b = (const float*)d_in[6];
    const float* bn1g = (const float*)d_in[7];
    const float* bn1b = (const float*)d_in[8];
    const float* bn1m = (const float*)d_in[9];
    const float* bn1v = (const float*)d_in[10];
    const float* bn2g = (const float*)d_in[11];
    const float* bn2b = (const float*)d_in[12];
    const float* bn2m = (const float*)d_in[13];
    const float* bn2v = (const float*)d_in[14];
    const float* w1ih = (const float*)d_in[15];
    const float* b1ih = (const float*)d_in[17];
    const float* b1hh = (const float*)d_in[18];
    const float* w2ih = (const float*)d_in[19];
    const float* b2ih = (const float*)d_in[21];
    const float* b2hh = (const float*)d_in[22];
    const float* lw   = (const float*)d_in[23];
    const float* lb   = (const float*)d_in[24];
    float* out = (float*)d_out;

    const int N = in_sizes[0] / 4;
    const int E = in_sizes[2];
    const int* src = ei;
    const int* dst = ei + E;

    const int T = 256;
    const int NB = (N + BS - 1) / BS;
    long long meanb = ((long long)BS * E) / (N > 0 ? N : 1);
    int bcap = (int)(meanb + meanb / 4 + 128);

    // workspace layout (256B-aligned regions)
    char* p = (char*)d_ws;
    auto alloc = [&](size_t bytes) { char* q = p; p += (bytes + 255) & ~(size_t)255; return q; };
    int*      gcur   = (int*)alloc(sizeof(int) * NB);
    uint2*    recs   = (uint2*)alloc(sizeof(uint2) * (size_t)NB * bcap);
    float*    dinv   = (float*)alloc(sizeof(float) * N);
    int*      pstart = (int*)alloc(sizeof(int) * N);
    int*      pcnt   = (int*)alloc(sizeof(int) * N);
    __half*   A      = (__half*)alloc(sizeof(__half) * (size_t)N * HF);
    float*    C      = (float*)alloc(sizeof(float) * (size_t)N * HF);   // h1
    float*    B2     = (float*)alloc(sizeof(float) * (size_t)N * HF);   // h2
    size_t need = (size_t)(p - (char*)d_ws);

    int bN  = (N + T - 1) / T;
    int bE  = (E + T - 1) / T;
    int bNF = (N * HF + T - 1) / T;
    int bN8 = (N + 7) / 8;
    int bG  = (N + 63) / 64;
    int bH  = (N + 255) / 256;
    int bBin = (E + KEDGE - 1) / KEDGE;

    if (ws_size >= need && NB <= MAXNB && bcap <= BCAPS && N <= (1 << 24)) {
        // ---- build ----
        k_zero<<<(NB + T - 1) / T, T, 0, stream>>>(gcur, NB);
        k_binsort<<<bBin, T, 0, stream>>>(src, dst, ew, E, NB, bcap, gcur, recs);
        k_sortb<<<NB, 512, 0, stream>>>(recs, gcur, bcap, pstart, pcnt, dinv, N);
        k_norm<<<NB * 4, T, 0, stream>>>(recs, gcur, bcap, dinv);

        // ---- layer 1 ----
        k_xw1_h<<<bNF, T, 0, stream>>>(x, g1w, A, N);
        k_gather<<<bG, T, 0, stream>>>(recs, pstart, pcnt, dinv, A,
                                       g1b, bn1g, bn1b, bn1m, bn1v, C, N);
        // ---- layer 2 ----
        k_xw2_h<<<bN8, T, 0, stream>>>(C, g2w, A, N);
        k_gather<<<bG, T, 0, stream>>>(recs, pstart, pcnt, dinv, A,
                                       g2b, bn2g, bn2b, bn2m, bn2v, B2, N);
        // ---- head ----
        k_head<<<bH, T, 0, stream>>>(C, B2, x, w1ih, b1ih, b1hh, w2ih, b2ih, b2hh,
                                     lw, lb, out, N);
    } else {
        // ---- fallback: atomic scatter, fp32 ----
        size_t Npad = ((size_t)N + 255) & ~(size_t)255;
        float* fdinv = (float*)d_ws;
        float* fA = fdinv + Npad;
        float* fB = fA + (size_t)N * HF;
        float* fC = fB + (size_t)N * HF;
        int bEF = (int)(((long long)E * HF + T - 1) / T);

        k_initdeg<<<bN, T, 0, stream>>>(fdinv, N);
        k_deg_only<<<bE, T, 0, stream>>>(dst, ew, fdinv, E);
        k_dinv_f<<<bN, T, 0, stream>>>(fdinv, N);

        k_xw1_f<<<bNF, T, 0, stream>>>(x, g1w, fA, N);
        k_selfloop<<<bNF, T, 0, stream>>>(fA, fdinv, fB, N);
        k_scatter<<<bEF, T, 0, stream>>>(src, dst, ew, fdinv, fA, fB, E * HF);
        k_post<<<bNF, T, 0, stream>>>(fB, g1b, bn1g, bn1b, bn1m, bn1v, fC, N);

        k_xw2_f<<<bN8, T, 0, stream>>>(fC, g2w, fA, N);
        k_selfloop<<<bNF, T, 0, stream>>>(fA, fdinv, fB, N);
        k_scatter<<<bEF, T, 0, stream>>>(src, dst, ew, fdinv, fA, fB, E * HF);
        k_post<<<bNF, T, 0, stream>>>(fB, g2b, bn2g, bn2b, bn2m, bn2v, fB, N);

        k_head<<<bH, T, 0, stream>>>(fC, fB, x, w1ih, b1ih, b1hh, w2ih, b2ih, b2hh,
                                     lw, lb, out, N);
    }
}

// Round 8
// 517.687 us; speedup vs baseline: 1.5152x; 1.0182x over previous
//
#include <hip/hip_runtime.h>
#include <hip/hip_fp16.h>
#include <math.h>

#define BN_EPS 1e-5f
#define HF 32          // hidden features
#define BS 256         // nodes per bucket (8-bit dloc)
#define KEDGE 4096     // edges per binsort block
#define MAXNB 1024     // max buckets supported by binsort LDS
#define BCAPS 5632     // max records per bucket held in k_sortb LDS

// fast transcendentals (trans pipe; error ~1e-7 rel, fine vs 2.2e-2 threshold)
__device__ __forceinline__ float fsig(float x) {
    return __builtin_amdgcn_rcpf(1.0f + __expf(-x));
}
__device__ __forceinline__ float ftanh(float x) {
    return 1.0f - 2.0f * __builtin_amdgcn_rcpf(1.0f + __expf(2.0f * x));
}

// ================= tiny utils =================

__global__ void k_zero(int* __restrict__ p, int n) {
    int i = blockIdx.x * blockDim.x + threadIdx.x;
    if (i < n) p[i] = 0;
}

// ================= Phase A: block-local counting sort into buckets =================

__global__ __launch_bounds__(256) void k_binsort(
        const int* __restrict__ src, const int* __restrict__ dst,
        const float* __restrict__ ew, int E, int NB, int bcap,
        int* __restrict__ gcur, uint2* __restrict__ recs) {
    __shared__ uint2 srec[KEDGE];
    __shared__ unsigned short sbk[KEDGE];
    __shared__ int hist[MAXNB], excl[MAXNB], curs[MAXNB], sbase[MAXNB];

    int tid = threadIdx.x;
    int base = blockIdx.x * KEDGE;
    int cnt = min(KEDGE, E - base);

    for (int i = tid; i < NB; i += 256) hist[i] = 0;
    __syncthreads();

    for (int i = tid; i < cnt; i += 256)
        atomicAdd(&hist[dst[base + i] >> 8], 1);
    __syncthreads();

    if (tid < 64) {
        int run = 0;
        for (int c = 0; c < NB; c += 64) {
            int idx = c + tid;
            int v = (idx < NB) ? hist[idx] : 0;
            int incl = v;
#pragma unroll
            for (int o = 1; o < 64; o <<= 1) {
                int up = __shfl_up(incl, o, 64);
                if (tid >= o) incl += up;
            }
            if (idx < NB) { int e = run + incl - v; excl[idx] = e; curs[idx] = e; }
            run += __shfl(incl, 63, 64);
        }
    }
    __syncthreads();

    for (int i = tid; i < cnt; i += 256) {
        int s = src[base + i];
        int d = dst[base + i];
        float w = ew[base + i];
        int b = d >> 8;
        int pos = atomicAdd(&curs[b], 1);
        srec[pos] = make_uint2(((unsigned)s << 8) | (unsigned)(d & 255), __float_as_uint(w));
        sbk[pos] = (unsigned short)b;
    }
    __syncthreads();

    for (int b = tid; b < NB; b += 256) {
        int len = hist[b];
        sbase[b] = len ? atomicAdd(&gcur[b], len) : 0;
    }
    __syncthreads();

    for (int i = tid; i < cnt; i += 256) {
        int b = sbk[i];
        int off = sbase[b] + (i - excl[b]);
        if (off < bcap) recs[(size_t)b * bcap + off] = srec[i];
    }
}

// ================= Phase B: in-bucket sort by dst + CSR ptrs + dinv =================

__global__ __launch_bounds__(512) void k_sortb(
        uint2* __restrict__ recs, const int* __restrict__ gcur, int bcap,
        int* __restrict__ pstart, int* __restrict__ pcnt,
        float* __restrict__ dinv, int n) {
    __shared__ uint2 srec[BCAPS];
    __shared__ int hist[BS], excl[BS], curs[BS];
    __shared__ float wsum[BS];

    int b = blockIdx.x, tid = threadIdx.x;
    int cnt = min(gcur[b], bcap);
    uint2* r = recs + (size_t)b * bcap;

    if (tid < BS) { hist[tid] = 0; wsum[tid] = 1.0f; }  // self-loop weight in wsum
    __syncthreads();

    for (int i = tid; i < cnt; i += 512) {
        uint2 u = r[i];
        srec[i] = u;
        int dl = u.x & 255;
        atomicAdd(&hist[dl], 1);
        atomicAdd(&wsum[dl], __uint_as_float(u.y));
    }
    __syncthreads();

    if (tid < 64) {
        int run = 0;
        for (int c = 0; c < BS; c += 64) {
            int idx = c + tid;
            int v = hist[idx];
            int incl = v;
#pragma unroll
            for (int o = 1; o < 64; o <<= 1) {
                int up = __shfl_up(incl, o, 64);
                if (tid >= o) incl += up;
            }
            int e = run + incl - v;
            excl[idx] = e; curs[idx] = e;
            run += __shfl(incl, 63, 64);
        }
    }
    __syncthreads();

    for (int i = tid; i < cnt; i += 512) {
        uint2 u = srec[i];
        int pos = atomicAdd(&curs[u.x & 255], 1);
        r[pos] = u;
    }

    if (tid < BS) {
        int g = b * BS + tid;
        if (g < n) {
            pstart[g] = b * bcap + excl[tid];
            pcnt[g] = hist[tid];
            dinv[g] = rsqrtf(wsum[tid]);
        }
    }
}

// ================= Phase C: precompute norm per record =================

__global__ __launch_bounds__(256) void k_norm(
        uint2* __restrict__ recs, const int* __restrict__ gcur, int bcap,
        const float* __restrict__ dinv) {
    int b = blockIdx.x >> 2, q = blockIdx.x & 3;
    int cnt = min(gcur[b], bcap);
    int lo = (cnt * q) >> 2, hi = (cnt * (q + 1)) >> 2;
    uint2* r = recs + (size_t)b * bcap;
    for (int i = lo + threadIdx.x; i < hi; i += 256) {
        uint2 u = r[i];
        int s = u.x >> 8;
        int g = b * BS + (int)(u.x & 255);
        float w = __uint_as_float(u.y);
        u.y = __float_as_uint(w * dinv[s] * dinv[g]);
        r[i] = u;
    }
}

// ================= dense feature transforms (fp16 out) =================

__global__ void k_xw1_h(const float* __restrict__ x, const float* __restrict__ W,
                        __half* __restrict__ out, int n) {
    int idx = blockIdx.x * blockDim.x + threadIdx.x;
    if (idx >= n * HF) return;
    int nn = idx >> 5, f = idx & 31;
    const float4 xr = *(const float4*)(x + (size_t)nn * 4);
    float acc = xr.x * W[f] + xr.y * W[32 + f] + xr.z * W[64 + f] + xr.w * W[96 + f];
    out[idx] = __float2half(acc);
}

__global__ void k_xw2_h(const float* __restrict__ Hin, const float* __restrict__ W,
                        __half* __restrict__ out, int n) {
    __shared__ float sW[32 * 32];
    __shared__ float sH[8][32];
    int tid = threadIdx.x;
    for (int i = tid; i < 1024; i += 256) sW[i] = W[i];
    int r = tid >> 5, f = tid & 31;
    int nn = blockIdx.x * 8 + r;
    if (nn < n) sH[r][f] = Hin[(size_t)nn * HF + f];
    __syncthreads();
    if (nn >= n) return;
    float acc = 0.0f;
#pragma unroll
    for (int k = 0; k < 32; ++k) acc += sH[r][k] * sW[k * 32 + f];
    out[(size_t)nn * HF + f] = __float2half(acc);
}

// ================= gather: per-node CSR aggregation + fused epilogue =================

__global__ __launch_bounds__(256) void k_gather(
        const uint2* __restrict__ recs, const int* __restrict__ pstart,
        const int* __restrict__ pcnt, const float* __restrict__ dinv,
        const __half* __restrict__ A,
        const float* __restrict__ bias, const float* __restrict__ gamma,
        const float* __restrict__ beta, const float* __restrict__ mean,
        const float* __restrict__ var,
        float* __restrict__ Hout, int n) {
    int g = blockIdx.x * 64 + (threadIdx.x >> 2);
    int lane = threadIdx.x & 3;
    if (g >= n) return;

    float dig = dinv[g];
    float sl = dig * dig;
    uint4 srow = ((const uint4*)(A + ((size_t)g << 5)))[lane];
    float acc[8];
    {
        const __half2* h = (const __half2*)&srow;
#pragma unroll
        for (int k = 0; k < 4; ++k) {
            float2 f = __half22float2(h[k]);
            acc[2 * k] = sl * f.x; acc[2 * k + 1] = sl * f.y;
        }
    }

    int cn = pcnt[g];
    const uint2* r = recs + pstart[g];
    int e = 0;
    for (; e + 2 <= cn; e += 2) {
        uint2 r0 = r[e], r1 = r[e + 1];
        uint4 row0 = ((const uint4*)(A + ((size_t)(r0.x >> 8) << 5)))[lane];
        uint4 row1 = ((const uint4*)(A + ((size_t)(r1.x >> 8) << 5)))[lane];
        float n0 = __uint_as_float(r0.y), n1 = __uint_as_float(r1.y);
        const __half2* h0 = (const __half2*)&row0;
        const __half2* h1 = (const __half2*)&row1;
#pragma unroll
        for (int k = 0; k < 4; ++k) {
            float2 f0 = __half22float2(h0[k]);
            float2 f1 = __half22float2(h1[k]);
            acc[2 * k]     += n0 * f0.x + n1 * f1.x;
            acc[2 * k + 1] += n0 * f0.y + n1 * f1.y;
        }
    }
    if (e < cn) {
        uint2 r0 = r[e];
        uint4 row0 = ((const uint4*)(A + ((size_t)(r0.x >> 8) << 5)))[lane];
        float n0 = __uint_as_float(r0.y);
        const __half2* h0 = (const __half2*)&row0;
#pragma unroll
        for (int k = 0; k < 4; ++k) {
            float2 f0 = __half22float2(h0[k]);
            acc[2 * k]     += n0 * f0.x;
            acc[2 * k + 1] += n0 * f0.y;
        }
    }

    int fq = lane * 8;
    float o[8];
#pragma unroll
    for (int k = 0; k < 8; ++k) {
        float v = fmaxf(acc[k] + bias[fq + k], 0.0f);
        o[k] = (v - mean[fq + k]) * gamma[fq + k] * rsqrtf(var[fq + k] + BN_EPS) + beta[fq + k];
    }
    float* dst = Hout + ((size_t)g << 5) + fq;
    *(float4*)dst = make_float4(o[0], o[1], o[2], o[3]);
    *(float4*)(dst + 4) = make_float4(o[4], o[5], o[6], o[7]);
}

// ================= fused head: LSTM1 + LSTM2 + linear =================
// One thread per node. Skip vector held in 16 EXPLICIT float4 registers (no
// indexable array -> cannot be demoted to scratch). H1 via private LDS slot.
// j-loops kept rolled (unroll 1) for I-cache. launch_bounds(256,2) lifts the
// VGPR cap to 256 so the ~130-reg live set fits without spilling.

#define DOT4(acc, wv, sv) acc += (wv).x*(sv).x + (wv).y*(sv).y + (wv).z*(sv).z + (wv).w*(sv).w
#define ACC16(acc, W) { DOT4(acc,(W)[0],sk0); DOT4(acc,(W)[1],sk1); DOT4(acc,(W)[2],sk2); DOT4(acc,(W)[3],sk3); \
                        DOT4(acc,(W)[4],sk4); DOT4(acc,(W)[5],sk5); DOT4(acc,(W)[6],sk6); DOT4(acc,(W)[7],sk7); \
                        DOT4(acc,(W)[8],sk8); DOT4(acc,(W)[9],sk9); DOT4(acc,(W)[10],sk10); DOT4(acc,(W)[11],sk11); \
                        DOT4(acc,(W)[12],sk12); DOT4(acc,(W)[13],sk13); DOT4(acc,(W)[14],sk14); DOT4(acc,(W)[15],sk15); }
#define ACC8(acc, W)  { DOT4(acc,(W)[0],hh0); DOT4(acc,(W)[1],hh1); DOT4(acc,(W)[2],hh2); DOT4(acc,(W)[3],hh3); \
                        DOT4(acc,(W)[4],hh4); DOT4(acc,(W)[5],hh5); DOT4(acc,(W)[6],hh6); DOT4(acc,(W)[7],hh7); }

__global__ __launch_bounds__(256, 2) void k_head(
        const float* __restrict__ h1, const float* __restrict__ h2,
        const float* __restrict__ x,
        const float* __restrict__ wih1, const float* __restrict__ bih1, const float* __restrict__ bhh1,
        const float* __restrict__ wih2, const float* __restrict__ bih2, const float* __restrict__ bhh2,
        const float* __restrict__ lw, const float* __restrict__ lb,
        float* __restrict__ out, int n) {
    __shared__ float sH1[32 * 256];
    int tid = threadIdx.x;
    int nn = blockIdx.x * 256 + tid;
    if (nn >= n) return;  // no barriers below; safe divergence

    const float4* a = (const float4*)(h1 + (size_t)nn * HF);
    const float4* b = (const float4*)(h2 + (size_t)nn * HF);
    float4 sk0 = a[0], sk1 = a[1], sk2 = a[2], sk3 = a[3];
    float4 sk4 = a[4], sk5 = a[5], sk6 = a[6], sk7 = a[7];
    float4 sk8 = b[0], sk9 = b[1], sk10 = b[2], sk11 = b[3];
    float4 sk12 = b[4], sk13 = b[5], sk14 = b[6], sk15 = b[7];

    float oa = lb[0];

    // LSTM1 (torch gate rows: i=0..31, g=64..95, o=96..127)
#pragma unroll 1
    for (int j = 0; j < 32; ++j) {
        const float4* wi = (const float4*)(wih1 + (size_t)j * 64);
        const float4* wg = (const float4*)(wih1 + (size_t)(64 + j) * 64);
        const float4* wo = (const float4*)(wih1 + (size_t)(96 + j) * 64);
        float gi = bih1[j] + bhh1[j];
        float gg = bih1[64 + j] + bhh1[64 + j];
        float go = bih1[96 + j] + bhh1[96 + j];
        ACC16(gi, wi);
        ACC16(gg, wg);
        ACC16(go, wo);
        float cc = fsig(gi) * ftanh(gg);
        float hh = fsig(go) * ftanh(cc);
        sH1[j * 256 + tid] = hh;
        oa += fmaxf(hh, 0.0f) * lw[j];
    }

    // H1 read-back into explicit registers (static LDS offsets)
    float4 hh0 = make_float4(sH1[0*256+tid],  sH1[1*256+tid],  sH1[2*256+tid],  sH1[3*256+tid]);
    float4 hh1 = make_float4(sH1[4*256+tid],  sH1[5*256+tid],  sH1[6*256+tid],  sH1[7*256+tid]);
    float4 hh2 = make_float4(sH1[8*256+tid],  sH1[9*256+tid],  sH1[10*256+tid], sH1[11*256+tid]);
    float4 hh3 = make_float4(sH1[12*256+tid], sH1[13*256+tid], sH1[14*256+tid], sH1[15*256+tid]);
    float4 hh4 = make_float4(sH1[16*256+tid], sH1[17*256+tid], sH1[18*256+tid], sH1[19*256+tid]);
    float4 hh5 = make_float4(sH1[20*256+tid], sH1[21*256+tid], sH1[22*256+tid], sH1[23*256+tid]);
    float4 hh6 = make_float4(sH1[24*256+tid], sH1[25*256+tid], sH1[26*256+tid], sH1[27*256+tid]);
    float4 hh7 = make_float4(sH1[28*256+tid], sH1[29*256+tid], sH1[30*256+tid], sH1[31*256+tid]);

    // LSTM2 over H1 (32-wide), head dot accumulated on the fly
#pragma unroll 1
    for (int j = 0; j < 32; ++j) {
        const float4* wi = (const float4*)(wih2 + (size_t)j * 32);
        const float4* wg = (const float4*)(wih2 + (size_t)(64 + j) * 32);
        const float4* wo = (const float4*)(wih2 + (size_t)(96 + j) * 32);
        float gi = bih2[j] + bhh2[j];
        float gg = bih2[64 + j] + bhh2[64 + j];
        float go = bih2[96 + j] + bhh2[96 + j];
        ACC8(gi, wi);
        ACC8(gg, wg);
        ACC8(go, wo);
        float cc = fsig(gi) * ftanh(gg);
        float hh = fsig(go) * ftanh(cc);
        oa += fmaxf(hh, 0.0f) * lw[32 + j];
    }

    const float4 xv = *(const float4*)(x + (size_t)nn * 4);
    oa += fmaxf(xv.x, 0.0f) * lw[64] + fmaxf(xv.y, 0.0f) * lw[65] +
          fmaxf(xv.z, 0.0f) * lw[66] + fmaxf(xv.w, 0.0f) * lw[67];
    out[nn] = oa;
}

// ================= fallback (atomic scatter, fp32) =================

__global__ void k_initdeg(float* __restrict__ deg, int n) {
    int i = blockIdx.x * blockDim.x + threadIdx.x;
    if (i < n) deg[i] = 1.0f;
}

__global__ void k_deg_only(const int* __restrict__ dst, const float* __restrict__ ew,
                           float* __restrict__ deg, int E) {
    int e = blockIdx.x * blockDim.x + threadIdx.x;
    if (e < E) atomicAdd(&deg[dst[e]], ew[e]);
}

__global__ void k_dinv_f(float* __restrict__ deg, int n) {
    int i = blockIdx.x * blockDim.x + threadIdx.x;
    if (i < n) {
        float d = deg[i];
        deg[i] = d > 0.0f ? rsqrtf(d) : 0.0f;
    }
}

__global__ void k_xw1_f(const float* __restrict__ x, const float* __restrict__ W,
                        float* __restrict__ out, int n) {
    int idx = blockIdx.x * blockDim.x + threadIdx.x;
    if (idx >= n * HF) return;
    int nn = idx >> 5, f = idx & 31;
    const float4 xr = *(const float4*)(x + (size_t)nn * 4);
    out[idx] = xr.x * W[f] + xr.y * W[32 + f] + xr.z * W[64 + f] + xr.w * W[96 + f];
}

__global__ void k_xw2_f(const float* __restrict__ Hin, const float* __restrict__ W,
                        float* __restrict__ out, int n) {
    __shared__ float sW[32 * 32];
    __shared__ float sH[8][32];
    int tid = threadIdx.x;
    for (int i = tid; i < 1024; i += 256) sW[i] = W[i];
    int r = tid >> 5, f = tid & 31;
    int nn = blockIdx.x * 8 + r;
    if (nn < n) sH[r][f] = Hin[(size_t)nn * HF + f];
    __syncthreads();
    if (nn >= n) return;
    float acc = 0.0f;
#pragma unroll
    for (int k = 0; k < 32; ++k) acc += sH[r][k] * sW[k * 32 + f];
    out[(size_t)nn * HF + f] = acc;
}

__global__ void k_selfloop(const float* __restrict__ A, const float* __restrict__ dinv,
                           float* __restrict__ B, int n) {
    int idx = blockIdx.x * blockDim.x + threadIdx.x;
    if (idx >= n * HF) return;
    int nn = idx >> 5;
    float di = dinv[nn];
    B[idx] = di * di * A[idx];
}

__global__ void k_scatter(const int* __restrict__ src, const int* __restrict__ dst,
                          const float* __restrict__ ew, const float* __restrict__ dinv,
                          const float* __restrict__ A, float* __restrict__ B, int total) {
    int idx = blockIdx.x * blockDim.x + threadIdx.x;
    if (idx >= total) return;
    int e = idx >> 5, f = idx & 31;
    int s = src[e], d = dst[e];
    float norm = dinv[s] * ew[e] * dinv[d];
    atomicAdd(&B[d * HF + f], norm * A[s * HF + f]);
}

__global__ void k_post(const float* __restrict__ B, const float* __restrict__ bias,
                       const float* __restrict__ gamma, const float* __restrict__ beta,
                       const float* __restrict__ mean, const float* __restrict__ var,
                       float* __restrict__ Hout, int n) {
    int idx = blockIdx.x * blockDim.x + threadIdx.x;
    if (idx >= n * HF) return;
    int f = idx & 31;
    float v = fmaxf(B[idx] + bias[f], 0.0f);
    float sc = gamma[f] * rsqrtf(var[f] + BN_EPS);
    Hout[idx] = (v - mean[f]) * sc + beta[f];
}

// ================= launch =================

extern "C" void kernel_launch(void* const* d_in, const int* in_sizes, int n_in,
                              void* d_out, int out_size, void* d_ws, size_t ws_size,
                              hipStream_t stream) {
    const float* x   = (const float*)d_in[0];
    const int*   ei  = (const int*)d_in[1];
    const float* ew  = (const float*)d_in[2];
    const float* g1w = (const float*)d_in[3];
    const float* g1b = (const float*)d_in[4];
    const float* g2w = (const float*)d_in[5];
    const float* g2b = (const float*)d_in[6];
    const float* bn1g = (const float*)d_in[7];
    const float* bn1b = (const float*)d_in[8];
    const float* bn1m = (const float*)d_in[9];
    const float* bn1v = (const float*)d_in[10];
    const float* bn2g = (const float*)d_in[11];
    const float* bn2b = (const float*)d_in[12];
    const float* bn2m = (const float*)d_in[13];
    const float* bn2v = (const float*)d_in[14];
    const float* w1ih = (const float*)d_in[15];
    const float* b1ih = (const float*)d_in[17];
    const float* b1hh = (const float*)d_in[18];
    const float* w2ih = (const float*)d_in[19];
    const float* b2ih = (const float*)d_in[21];
    const float* b2hh = (const float*)d_in[22];
    const float* lw   = (const float*)d_in[23];
    const float* lb   = (const float*)d_in[24];
    float* out = (float*)d_out;

    const int N = in_sizes[0] / 4;
    const int E = in_sizes[2];
    const int* src = ei;
    const int* dst = ei + E;

    const int T = 256;
    const int NB = (N + BS - 1) / BS;
    long long meanb = ((long long)BS * E) / (N > 0 ? N : 1);
    int bcap = (int)(meanb + meanb / 4 + 128);

    // workspace layout (256B-aligned regions)
    char* p = (char*)d_ws;
    auto alloc = [&](size_t bytes) { char* q = p; p += (bytes + 255) & ~(size_t)255; return q; };
    int*      gcur   = (int*)alloc(sizeof(int) * NB);
    uint2*    recs   = (uint2*)alloc(sizeof(uint2) * (size_t)NB * bcap);
    float*    dinv   = (float*)alloc(sizeof(float) * N);
    int*      pstart = (int*)alloc(sizeof(int) * N);
    int*      pcnt   = (int*)alloc(sizeof(int) * N);
    __half*   A      = (__half*)alloc(sizeof(__half) * (size_t)N * HF);
    float*    C      = (float*)alloc(sizeof(float) * (size_t)N * HF);   // h1
    float*    B2     = (float*)alloc(sizeof(float) * (size_t)N * HF);   // h2
    size_t need = (size_t)(p - (char*)d_ws);

    int bN  = (N + T - 1) / T;
    int bE  = (E + T - 1) / T;
    int bNF = (N * HF + T - 1) / T;
    int bN8 = (N + 7) / 8;
    int bG  = (N + 63) / 64;
    int bH  = (N + 255) / 256;
    int bBin = (E + KEDGE - 1) / KEDGE;

    if (ws_size >= need && NB <= MAXNB && bcap <= BCAPS && N <= (1 << 24)) {
        // ---- build ----
        k_zero<<<(NB + T - 1) / T, T, 0, stream>>>(gcur, NB);
        k_binsort<<<bBin, T, 0, stream>>>(src, dst, ew, E, NB, bcap, gcur, recs);
        k_sortb<<<NB, 512, 0, stream>>>(recs, gcur, bcap, pstart, pcnt, dinv, N);
        k_norm<<<NB * 4, T, 0, stream>>>(recs, gcur, bcap, dinv);

        // ---- layer 1 ----
        k_xw1_h<<<bNF, T, 0, stream>>>(x, g1w, A, N);
        k_gather<<<bG, T, 0, stream>>>(recs, pstart, pcnt, dinv, A,
                                       g1b, bn1g, bn1b, bn1m, bn1v, C, N);
        // ---- layer 2 ----
        k_xw2_h<<<bN8, T, 0, stream>>>(C, g2w, A, N);
        k_gather<<<bG, T, 0, stream>>>(recs, pstart, pcnt, dinv, A,
                                       g2b, bn2g, bn2b, bn2m, bn2v, B2, N);
        // ---- head ----
        k_head<<<bH, T, 0, stream>>>(C, B2, x, w1ih, b1ih, b1hh, w2ih, b2ih, b2hh,
                                     lw, lb, out, N);
    } else {
        // ---- fallback: atomic scatter, fp32 ----
        size_t Npad = ((size_t)N + 255) & ~(size_t)255;
        float* fdinv = (float*)d_ws;
        float* fA = fdinv + Npad;
        float* fB = fA + (size_t)N * HF;
        float* fC = fB + (size_t)N * HF;
        int bEF = (int)(((long long)E * HF + T - 1) / T);

        k_initdeg<<<bN, T, 0, stream>>>(fdinv, N);
        k_deg_only<<<bE, T, 0, stream>>>(dst, ew, fdinv, E);
        k_dinv_f<<<bN, T, 0, stream>>>(fdinv, N);

        k_xw1_f<<<bNF, T, 0, stream>>>(x, g1w, fA, N);
        k_selfloop<<<bNF, T, 0, stream>>>(fA, fdinv, fB, N);
        k_scatter<<<bEF, T, 0, stream>>>(src, dst, ew, fdinv, fA, fB, E * HF);
        k_post<<<bNF, T, 0, stream>>>(fB, g1b, bn1g, bn1b, bn1m, bn1v, fC, N);

        k_xw2_f<<<bN8, T, 0, stream>>>(fC, g2w, fA, N);
        k_selfloop<<<bNF, T, 0, stream>>>(fA, fdinv, fB, N);
        k_scatter<<<bEF, T, 0, stream>>>(src, dst, ew, fdinv, fA, fB, E * HF);
        k_post<<<bNF, T, 0, stream>>>(fB, g2b, bn2g, bn2b, bn2m, bn2v, fB, N);

        k_head<<<bH, T, 0, stream>>>(fC, fB, x, w1ih, b1ih, b1hh, w2ih, b2ih, b2hh,
                                     lw, lb, out, N);
    }
}

// Round 9
// 436.629 us; speedup vs baseline: 1.7964x; 1.1856x over previous
//
#include <hip/hip_runtime.h>
#include <hip/hip_fp16.h>
#include <math.h>

#define BN_EPS 1e-5f
#define HF 32          // hidden features
#define BS 256         // nodes per bucket (8-bit dloc)
#define KEDGE 4096     // edges per binsort block
#define MAXNB 1024     // max buckets supported by binsort LDS
#define BCAPS 5632     // max records per bucket held in k_sortb LDS

typedef _Float16 half8 __attribute__((ext_vector_type(8)));
typedef float f32x4 __attribute__((ext_vector_type(4)));

// fast transcendentals (trans pipe; error ~1e-7 rel, fine vs 2.2e-2 threshold)
__device__ __forceinline__ float fsig(float x) {
    return __builtin_amdgcn_rcpf(1.0f + __expf(-x));
}
__device__ __forceinline__ float ftanh(float x) {
    return 1.0f - 2.0f * __builtin_amdgcn_rcpf(1.0f + __expf(2.0f * x));
}

// ================= tiny utils =================

__global__ void k_zero(int* __restrict__ p, int n) {
    int i = blockIdx.x * blockDim.x + threadIdx.x;
    if (i < n) p[i] = 0;
}

// ================= Phase A: block-local counting sort into buckets =================

__global__ __launch_bounds__(256) void k_binsort(
        const int* __restrict__ src, const int* __restrict__ dst,
        const float* __restrict__ ew, int E, int NB, int bcap,
        int* __restrict__ gcur, uint2* __restrict__ recs) {
    __shared__ uint2 srec[KEDGE];
    __shared__ unsigned short sbk[KEDGE];
    __shared__ int hist[MAXNB], excl[MAXNB], curs[MAXNB], sbase[MAXNB];

    int tid = threadIdx.x;
    int base = blockIdx.x * KEDGE;
    int cnt = min(KEDGE, E - base);

    for (int i = tid; i < NB; i += 256) hist[i] = 0;
    __syncthreads();

    for (int i = tid; i < cnt; i += 256)
        atomicAdd(&hist[dst[base + i] >> 8], 1);
    __syncthreads();

    if (tid < 64) {
        int run = 0;
        for (int c = 0; c < NB; c += 64) {
            int idx = c + tid;
            int v = (idx < NB) ? hist[idx] : 0;
            int incl = v;
#pragma unroll
            for (int o = 1; o < 64; o <<= 1) {
                int up = __shfl_up(incl, o, 64);
                if (tid >= o) incl += up;
            }
            if (idx < NB) { int e = run + incl - v; excl[idx] = e; curs[idx] = e; }
            run += __shfl(incl, 63, 64);
        }
    }
    __syncthreads();

    for (int i = tid; i < cnt; i += 256) {
        int s = src[base + i];
        int d = dst[base + i];
        float w = ew[base + i];
        int b = d >> 8;
        int pos = atomicAdd(&curs[b], 1);
        srec[pos] = make_uint2(((unsigned)s << 8) | (unsigned)(d & 255), __float_as_uint(w));
        sbk[pos] = (unsigned short)b;
    }
    __syncthreads();

    for (int b = tid; b < NB; b += 256) {
        int len = hist[b];
        sbase[b] = len ? atomicAdd(&gcur[b], len) : 0;
    }
    __syncthreads();

    for (int i = tid; i < cnt; i += 256) {
        int b = sbk[i];
        int off = sbase[b] + (i - excl[b]);
        if (off < bcap) recs[(size_t)b * bcap + off] = srec[i];
    }
}

// ================= Phase B: in-bucket sort by dst + CSR ptrs + dinv =================

__global__ __launch_bounds__(512) void k_sortb(
        uint2* __restrict__ recs, const int* __restrict__ gcur, int bcap,
        int* __restrict__ pstart, int* __restrict__ pcnt,
        float* __restrict__ dinv, int n) {
    __shared__ uint2 srec[BCAPS];
    __shared__ int hist[BS], excl[BS], curs[BS];
    __shared__ float wsum[BS];

    int b = blockIdx.x, tid = threadIdx.x;
    int cnt = min(gcur[b], bcap);
    uint2* r = recs + (size_t)b * bcap;

    if (tid < BS) { hist[tid] = 0; wsum[tid] = 1.0f; }  // self-loop weight in wsum
    __syncthreads();

    for (int i = tid; i < cnt; i += 512) {
        uint2 u = r[i];
        srec[i] = u;
        int dl = u.x & 255;
        atomicAdd(&hist[dl], 1);
        atomicAdd(&wsum[dl], __uint_as_float(u.y));
    }
    __syncthreads();

    if (tid < 64) {
        int run = 0;
        for (int c = 0; c < BS; c += 64) {
            int idx = c + tid;
            int v = hist[idx];
            int incl = v;
#pragma unroll
            for (int o = 1; o < 64; o <<= 1) {
                int up = __shfl_up(incl, o, 64);
                if (tid >= o) incl += up;
            }
            int e = run + incl - v;
            excl[idx] = e; curs[idx] = e;
            run += __shfl(incl, 63, 64);
        }
    }
    __syncthreads();

    for (int i = tid; i < cnt; i += 512) {
        uint2 u = srec[i];
        int pos = atomicAdd(&curs[u.x & 255], 1);
        r[pos] = u;
    }

    if (tid < BS) {
        int g = b * BS + tid;
        if (g < n) {
            pstart[g] = b * bcap + excl[tid];
            pcnt[g] = hist[tid];
            dinv[g] = rsqrtf(wsum[tid]);
        }
    }
}

// ================= Phase C: precompute norm per record =================

__global__ __launch_bounds__(256) void k_norm(
        uint2* __restrict__ recs, const int* __restrict__ gcur, int bcap,
        const float* __restrict__ dinv) {
    int b = blockIdx.x >> 2, q = blockIdx.x & 3;
    int cnt = min(gcur[b], bcap);
    int lo = (cnt * q) >> 2, hi = (cnt * (q + 1)) >> 2;
    uint2* r = recs + (size_t)b * bcap;
    for (int i = lo + threadIdx.x; i < hi; i += 256) {
        uint2 u = r[i];
        int s = u.x >> 8;
        int g = b * BS + (int)(u.x & 255);
        float w = __uint_as_float(u.y);
        u.y = __float_as_uint(w * dinv[s] * dinv[g]);
        r[i] = u;
    }
}

// ================= weight pack for MFMA head (runs once) =================
// wp1: B-fragments of wih1^T (f16) for tiles t in {i0,i1,g0,g1,o0,o1}, kc in {0,1}
//   layout: ((t*2+kc)*64 + lane)*8 + j  <->  B[kc*32 + (lane>>4)*8 + j][tg[t] + (lane&15)]
// wp2: same for wih2 (K=32, single kc).  bsum = bih + bhh.

__global__ void k_pack(const float* __restrict__ wih1, const float* __restrict__ bih1,
                       const float* __restrict__ bhh1, const float* __restrict__ wih2,
                       const float* __restrict__ bih2, const float* __restrict__ bhh2,
                       __half* __restrict__ wp1, __half* __restrict__ wp2,
                       float* __restrict__ bsum1, float* __restrict__ bsum2) {
    const int tg[6] = {0, 16, 64, 80, 96, 112};
    int idx = blockIdx.x * blockDim.x + threadIdx.x;
    if (idx < 6144) {
        int t = idx >> 10, rem = idx & 1023;
        int kc = rem >> 9, rem2 = rem & 511;
        int lane = rem2 >> 3, j = rem2 & 7;
        int g = tg[t] + (lane & 15);
        int k = kc * 32 + (lane >> 4) * 8 + j;
        wp1[idx] = __float2half(wih1[g * 64 + k]);
    } else if (idx < 9216) {
        int i2 = idx - 6144;
        int t = i2 >> 9, rem2 = i2 & 511;
        int lane = rem2 >> 3, j = rem2 & 7;
        int g = tg[t] + (lane & 15);
        int k = (lane >> 4) * 8 + j;
        wp2[i2] = __float2half(wih2[g * 32 + k]);
    } else if (idx < 9344) {
        int i = idx - 9216;
        bsum1[i] = bih1[i] + bhh1[i];
    } else if (idx < 9472) {
        int i = idx - 9344;
        bsum2[i] = bih2[i] + bhh2[i];
    }
}

// ================= dense feature transforms (fp16 out) =================

__global__ void k_xw1_h(const float* __restrict__ x, const float* __restrict__ W,
                        __half* __restrict__ out, int n) {
    int idx = blockIdx.x * blockDim.x + threadIdx.x;
    if (idx >= n * HF) return;
    int nn = idx >> 5, f = idx & 31;
    const float4 xr = *(const float4*)(x + (size_t)nn * 4);
    float acc = xr.x * W[f] + xr.y * W[32 + f] + xr.z * W[64 + f] + xr.w * W[96 + f];
    out[idx] = __float2half(acc);
}

__global__ void k_xw2_h(const float* __restrict__ Hin, const float* __restrict__ W,
                        __half* __restrict__ out, int n) {
    __shared__ float sW[32 * 32];
    __shared__ float sH[8][32];
    int tid = threadIdx.x;
    for (int i = tid; i < 1024; i += 256) sW[i] = W[i];
    int r = tid >> 5, f = tid & 31;
    int nn = blockIdx.x * 8 + r;
    if (nn < n) sH[r][f] = Hin[(size_t)nn * HF + f];
    __syncthreads();
    if (nn >= n) return;
    float acc = 0.0f;
#pragma unroll
    for (int k = 0; k < 32; ++k) acc += sH[r][k] * sW[k * 32 + f];
    out[(size_t)nn * HF + f] = __float2half(acc);
}

// ================= gather: per-node CSR aggregation + fused epilogue =================
// Also emits the fp16 skip slice (uoff 0 for h1, 32 for h2) for the MFMA head.

__global__ __launch_bounds__(256) void k_gather(
        const uint2* __restrict__ recs, const int* __restrict__ pstart,
        const int* __restrict__ pcnt, const float* __restrict__ dinv,
        const __half* __restrict__ A,
        const float* __restrict__ bias, const float* __restrict__ gamma,
        const float* __restrict__ beta, const float* __restrict__ mean,
        const float* __restrict__ var,
        float* __restrict__ Hout, __half* __restrict__ skiph, int uoff, int n) {
    int g = blockIdx.x * 64 + (threadIdx.x >> 2);
    int lane = threadIdx.x & 3;
    if (g >= n) return;

    float dig = dinv[g];
    float sl = dig * dig;
    uint4 srow = ((const uint4*)(A + ((size_t)g << 5)))[lane];
    float acc[8];
    {
        const __half2* h = (const __half2*)&srow;
#pragma unroll
        for (int k = 0; k < 4; ++k) {
            float2 f = __half22float2(h[k]);
            acc[2 * k] = sl * f.x; acc[2 * k + 1] = sl * f.y;
        }
    }

    int cn = pcnt[g];
    const uint2* r = recs + pstart[g];
    int e = 0;
    for (; e + 2 <= cn; e += 2) {
        uint2 r0 = r[e], r1 = r[e + 1];
        uint4 row0 = ((const uint4*)(A + ((size_t)(r0.x >> 8) << 5)))[lane];
        uint4 row1 = ((const uint4*)(A + ((size_t)(r1.x >> 8) << 5)))[lane];
        float n0 = __uint_as_float(r0.y), n1 = __uint_as_float(r1.y);
        const __half2* h0 = (const __half2*)&row0;
        const __half2* h1 = (const __half2*)&row1;
#pragma unroll
        for (int k = 0; k < 4; ++k) {
            float2 f0 = __half22float2(h0[k]);
            float2 f1 = __half22float2(h1[k]);
            acc[2 * k]     += n0 * f0.x + n1 * f1.x;
            acc[2 * k + 1] += n0 * f0.y + n1 * f1.y;
        }
    }
    if (e < cn) {
        uint2 r0 = r[e];
        uint4 row0 = ((const uint4*)(A + ((size_t)(r0.x >> 8) << 5)))[lane];
        float n0 = __uint_as_float(r0.y);
        const __half2* h0 = (const __half2*)&row0;
#pragma unroll
        for (int k = 0; k < 4; ++k) {
            float2 f0 = __half22float2(h0[k]);
            acc[2 * k]     += n0 * f0.x;
            acc[2 * k + 1] += n0 * f0.y;
        }
    }

    int fq = lane * 8;
    float o[8];
#pragma unroll
    for (int k = 0; k < 8; ++k) {
        float v = fmaxf(acc[k] + bias[fq + k], 0.0f);
        o[k] = (v - mean[fq + k]) * gamma[fq + k] * rsqrtf(var[fq + k] + BN_EPS) + beta[fq + k];
    }
    float* dst = Hout + ((size_t)g << 5) + fq;
    *(float4*)dst = make_float4(o[0], o[1], o[2], o[3]);
    *(float4*)(dst + 4) = make_float4(o[4], o[5], o[6], o[7]);

    // fp16 skip slice for MFMA head
    union { __half h[8]; uint4 q; } hv;
#pragma unroll
    for (int k = 0; k < 8; ++k) hv.h[k] = __float2half(o[k]);
    *(uint4*)(skiph + (size_t)g * 64 + uoff + fq) = hv.q;
}

// ================= MFMA fused head: LSTM1 + LSTM2 + linear =================
// Wave = 16 nodes. gates = skip @ W^T via mfma_f32_16x16x32_f16 (f-gate
// dropped: c0=0). C/D layout: col=lane&15 (gate), row=quad*4+reg (node).
// H1 redistributes D-layout -> A-layout through LDS (80B row stride).

__global__ __launch_bounds__(256) void k_headm(
        const __half* __restrict__ skiph, const float* __restrict__ x,
        const __half* __restrict__ wp1, const __half* __restrict__ wp2,
        const float* __restrict__ bsum1, const float* __restrict__ bsum2,
        const float* __restrict__ lw, const float* __restrict__ lb,
        float* __restrict__ out, int n) {
    __shared__ __align__(16) __half H1lds[4 * 16 * 40];
    int tid = threadIdx.x;
    int w = tid >> 6, l = tid & 63;
    int quad = l >> 4, c = l & 15;
    int node_base = blockIdx.x * 64 + w * 16;

    // A-frags: lane holds skip[l&15][quad*8+j] (+32 for second k-chunk)
    int arow = node_base + c; if (arow > n - 1) arow = n - 1;
    const half8* ap = (const half8*)(skiph + (size_t)arow * 64);
    half8 a0 = ap[quad];
    half8 a1 = ap[4 + quad];

    const half8* b1 = (const half8*)wp1;
    f32x4 d[6];
#pragma unroll
    for (int t = 0; t < 6; ++t) {
        f32x4 acc = {0.0f, 0.0f, 0.0f, 0.0f};
        acc = __builtin_amdgcn_mfma_f32_16x16x32_f16(a0, b1[(t * 2 + 0) * 64 + l], acc, 0, 0, 0);
        acc = __builtin_amdgcn_mfma_f32_16x16x32_f16(a1, b1[(t * 2 + 1) * 64 + l], acc, 0, 0, 0);
        d[t] = acc;
    }

    float bi0 = bsum1[c],      bi1 = bsum1[16 + c];
    float bg0 = bsum1[64 + c], bg1 = bsum1[80 + c];
    float bo0 = bsum1[96 + c], bo1 = bsum1[112 + c];
    float lwc0 = lw[c], lwc1 = lw[c + 16];

    float pa[4];
#pragma unroll
    for (int r = 0; r < 4; ++r) {
        float cc0 = fsig(d[0][r] + bi0) * ftanh(d[2][r] + bg0);
        float h0 = fsig(d[4][r] + bo0) * ftanh(cc0);
        float cc1 = fsig(d[1][r] + bi1) * ftanh(d[3][r] + bg1);
        float h1 = fsig(d[5][r] + bo1) * ftanh(cc1);
        pa[r] = fmaxf(h0, 0.0f) * lwc0 + fmaxf(h1, 0.0f) * lwc1;
        __half* hp = H1lds + (w * 16 + quad * 4 + r) * 40;
        hp[c] = __float2half(h0);
        hp[c + 16] = __float2half(h1);
    }
    __syncthreads();

    // A-frag for LSTM2: lane holds H1[l&15][quad*8+j], K=32 exactly
    half8 a2 = *(const half8*)(H1lds + (w * 16 + c) * 40 + quad * 8);

    const half8* b2 = (const half8*)wp2;
    f32x4 e[6];
#pragma unroll
    for (int t = 0; t < 6; ++t) {
        f32x4 acc = {0.0f, 0.0f, 0.0f, 0.0f};
        e[t] = __builtin_amdgcn_mfma_f32_16x16x32_f16(a2, b2[t * 64 + l], acc, 0, 0, 0);
    }

    float ci0 = bsum2[c],      ci1 = bsum2[16 + c];
    float cg0 = bsum2[64 + c], cg1 = bsum2[80 + c];
    float co0 = bsum2[96 + c], co1 = bsum2[112 + c];
    float lw2c0 = lw[32 + c], lw2c1 = lw[48 + c];
#pragma unroll
    for (int r = 0; r < 4; ++r) {
        float cc0 = fsig(e[0][r] + ci0) * ftanh(e[2][r] + cg0);
        float h0 = fsig(e[4][r] + co0) * ftanh(cc0);
        float cc1 = fsig(e[1][r] + ci1) * ftanh(e[3][r] + cg1);
        float h1 = fsig(e[5][r] + co1) * ftanh(cc1);
        pa[r] += fmaxf(h0, 0.0f) * lw2c0 + fmaxf(h1, 0.0f) * lw2c1;
    }

    // sum across the 16 lanes of each quad group
#pragma unroll
    for (int m = 1; m < 16; m <<= 1) {
#pragma unroll
        for (int r = 0; r < 4; ++r) pa[r] += __shfl_xor(pa[r], m, 64);
    }

    if (c < 4) {
        int node = node_base + quad * 4 + c;
        if (node < n) {
            const float4 xv = *(const float4*)(x + (size_t)node * 4);
            out[node] = pa[c] + lb[0]
                + fmaxf(xv.x, 0.0f) * lw[64] + fmaxf(xv.y, 0.0f) * lw[65]
                + fmaxf(xv.z, 0.0f) * lw[66] + fmaxf(xv.w, 0.0f) * lw[67];
        }
    }
}

// ================= fallback (atomic scatter, fp32) =================

__global__ void k_initdeg(float* __restrict__ deg, int n) {
    int i = blockIdx.x * blockDim.x + threadIdx.x;
    if (i < n) deg[i] = 1.0f;
}

__global__ void k_deg_only(const int* __restrict__ dst, const float* __restrict__ ew,
                           float* __restrict__ deg, int E) {
    int e = blockIdx.x * blockDim.x + threadIdx.x;
    if (e < E) atomicAdd(&deg[dst[e]], ew[e]);
}

__global__ void k_dinv_f(float* __restrict__ deg, int n) {
    int i = blockIdx.x * blockDim.x + threadIdx.x;
    if (i < n) {
        float d = deg[i];
        deg[i] = d > 0.0f ? rsqrtf(d) : 0.0f;
    }
}

__global__ void k_xw1_f(const float* __restrict__ x, const float* __restrict__ W,
                        float* __restrict__ out, int n) {
    int idx = blockIdx.x * blockDim.x + threadIdx.x;
    if (idx >= n * HF) return;
    int nn = idx >> 5, f = idx & 31;
    const float4 xr = *(const float4*)(x + (size_t)nn * 4);
    out[idx] = xr.x * W[f] + xr.y * W[32 + f] + xr.z * W[64 + f] + xr.w * W[96 + f];
}

__global__ void k_xw2_f(const float* __restrict__ Hin, const float* __restrict__ W,
                        float* __restrict__ out, int n) {
    __shared__ float sW[32 * 32];
    __shared__ float sH[8][32];
    int tid = threadIdx.x;
    for (int i = tid; i < 1024; i += 256) sW[i] = W[i];
    int r = tid >> 5, f = tid & 31;
    int nn = blockIdx.x * 8 + r;
    if (nn < n) sH[r][f] = Hin[(size_t)nn * HF + f];
    __syncthreads();
    if (nn >= n) return;
    float acc = 0.0f;
#pragma unroll
    for (int k = 0; k < 32; ++k) acc += sH[r][k] * sW[k * 32 + f];
    out[(size_t)nn * HF + f] = acc;
}

__global__ void k_selfloop(const float* __restrict__ A, const float* __restrict__ dinv,
                           float* __restrict__ B, int n) {
    int idx = blockIdx.x * blockDim.x + threadIdx.x;
    if (idx >= n * HF) return;
    int nn = idx >> 5;
    float di = dinv[nn];
    B[idx] = di * di * A[idx];
}

__global__ void k_scatter(const int* __restrict__ src, const int* __restrict__ dst,
                          const float* __restrict__ ew, const float* __restrict__ dinv,
                          const float* __restrict__ A, float* __restrict__ B, int total) {
    int idx = blockIdx.x * blockDim.x + threadIdx.x;
    if (idx >= total) return;
    int e = idx >> 5, f = idx & 31;
    int s = src[e], d = dst[e];
    float norm = dinv[s] * ew[e] * dinv[d];
    atomicAdd(&B[d * HF + f], norm * A[s * HF + f]);
}

__global__ void k_post(const float* __restrict__ B, const float* __restrict__ bias,
                       const float* __restrict__ gamma, const float* __restrict__ beta,
                       const float* __restrict__ mean, const float* __restrict__ var,
                       float* __restrict__ Hout, int n) {
    int idx = blockIdx.x * blockDim.x + threadIdx.x;
    if (idx >= n * HF) return;
    int f = idx & 31;
    float v = fmaxf(B[idx] + bias[f], 0.0f);
    float sc = gamma[f] * rsqrtf(var[f] + BN_EPS);
    Hout[idx] = (v - mean[f]) * sc + beta[f];
}

// fallback head (round-8 structure, fp32 inputs)
__global__ __launch_bounds__(256) void k_head(
        const float* __restrict__ h1, const float* __restrict__ h2,
        const float* __restrict__ x,
        const float* __restrict__ wih1, const float* __restrict__ bih1, const float* __restrict__ bhh1,
        const float* __restrict__ wih2, const float* __restrict__ bih2, const float* __restrict__ bhh2,
        const float* __restrict__ lw, const float* __restrict__ lb,
        float* __restrict__ out, int n) {
    __shared__ float sH1[32 * 256];
    int tid = threadIdx.x;
    int nn = blockIdx.x * 256 + tid;
    if (nn >= n) return;

    const float4* a = (const float4*)(h1 + (size_t)nn * HF);
    const float4* b = (const float4*)(h2 + (size_t)nn * HF);
    float skip[64];
#pragma unroll
    for (int q = 0; q < 8; ++q) {
        float4 v = a[q];
        skip[4 * q] = v.x; skip[4 * q + 1] = v.y; skip[4 * q + 2] = v.z; skip[4 * q + 3] = v.w;
        float4 u = b[q];
        skip[32 + 4 * q] = u.x; skip[33 + 4 * q] = u.y; skip[34 + 4 * q] = u.z; skip[35 + 4 * q] = u.w;
    }

    float oa = lb[0];
#pragma unroll 1
    for (int j = 0; j < 32; ++j) {
        const float4* wi = (const float4*)(wih1 + (size_t)j * 64);
        const float4* wg = (const float4*)(wih1 + (size_t)(64 + j) * 64);
        const float4* wo = (const float4*)(wih1 + (size_t)(96 + j) * 64);
        float gi = bih1[j] + bhh1[j];
        float gg = bih1[64 + j] + bhh1[64 + j];
        float go = bih1[96 + j] + bhh1[96 + j];
#pragma unroll
        for (int q = 0; q < 16; ++q) {
            float4 aa = wi[q], bb = wg[q], cc4 = wo[q];
            float s0 = skip[4 * q], s1 = skip[4 * q + 1], s2 = skip[4 * q + 2], s3 = skip[4 * q + 3];
            gi += aa.x * s0 + aa.y * s1 + aa.z * s2 + aa.w * s3;
            gg += bb.x * s0 + bb.y * s1 + bb.z * s2 + bb.w * s3;
            go += cc4.x * s0 + cc4.y * s1 + cc4.z * s2 + cc4.w * s3;
        }
        float cc = fsig(gi) * ftanh(gg);
        float hh = fsig(go) * ftanh(cc);
        sH1[j * 256 + tid] = hh;
        oa += fmaxf(hh, 0.0f) * lw[j];
    }

#pragma unroll 1
    for (int j = 0; j < 32; ++j) {
        const float4* wi = (const float4*)(wih2 + (size_t)j * 32);
        const float4* wg = (const float4*)(wih2 + (size_t)(64 + j) * 32);
        const float4* wo = (const float4*)(wih2 + (size_t)(96 + j) * 32);
        float gi = bih2[j] + bhh2[j];
        float gg = bih2[64 + j] + bhh2[64 + j];
        float go = bih2[96 + j] + bhh2[96 + j];
#pragma unroll
        for (int q = 0; q < 8; ++q) {
            float4 aa = wi[q], bb = wg[q], cc4 = wo[q];
            float s0 = sH1[(4 * q) * 256 + tid], s1 = sH1[(4 * q + 1) * 256 + tid];
            float s2 = sH1[(4 * q + 2) * 256 + tid], s3 = sH1[(4 * q + 3) * 256 + tid];
            gi += aa.x * s0 + aa.y * s1 + aa.z * s2 + aa.w * s3;
            gg += bb.x * s0 + bb.y * s1 + bb.z * s2 + bb.w * s3;
            go += cc4.x * s0 + cc4.y * s1 + cc4.z * s2 + cc4.w * s3;
        }
        float cc = fsig(gi) * ftanh(gg);
        float hh = fsig(go) * ftanh(cc);
        oa += fmaxf(hh, 0.0f) * lw[32 + j];
    }

    const float4 xv = *(const float4*)(x + (size_t)nn * 4);
    oa += fmaxf(xv.x, 0.0f) * lw[64] + fmaxf(xv.y, 0.0f) * lw[65] +
          fmaxf(xv.z, 0.0f) * lw[66] + fmaxf(xv.w, 0.0f) * lw[67];
    out[nn] = oa;
}

// ================= launch =================

extern "C" void kernel_launch(void* const* d_in, const int* in_sizes, int n_in,
                              void* d_out, int out_size, void* d_ws, size_t ws_size,
                              hipStream_t stream) {
    const float* x   = (const float*)d_in[0];
    const int*   ei  = (const int*)d_in[1];
    const float* ew  = (const float*)d_in[2];
    const float* g1w = (const float*)d_in[3];
    const float* g1b = (const float*)d_in[4];
    const float* g2w = (const float*)d_in[5];
    const float* g2b = (const float*)d_in[6];
    const float* bn1g = (const float*)d_in[7];
    const float* bn1b = (const float*)d_in[8];
    const float* bn1m = (const float*)d_in[9];
    const float* bn1v = (const float*)d_in[10];
    const float* bn2g = (const float*)d_in[11];
    const float* bn2b = (const float*)d_in[12];
    const float* bn2m = (const float*)d_in[13];
    const float* bn2v = (const float*)d_in[14];
    const float* w1ih = (const float*)d_in[15];
    const float* b1ih = (const float*)d_in[17];
    const float* b1hh = (const float*)d_in[18];
    const float* w2ih = (const float*)d_in[19];
    const float* b2ih = (const float*)d_in[21];
    const float* b2hh = (const float*)d_in[22];
    const float* lw   = (const float*)d_in[23];
    const float* lb   = (const float*)d_in[24];
    float* out = (float*)d_out;

    const int N = in_sizes[0] / 4;
    const int E = in_sizes[2];
    const int* src = ei;
    const int* dst = ei + E;

    const int T = 256;
    const int NB = (N + BS - 1) / BS;
    long long meanb = ((long long)BS * E) / (N > 0 ? N : 1);
    int bcap = (int)(meanb + meanb / 4 + 128);

    // workspace layout (256B-aligned regions)
    char* p = (char*)d_ws;
    auto alloc = [&](size_t bytes) { char* q = p; p += (bytes + 255) & ~(size_t)255; return q; };
    int*      gcur   = (int*)alloc(sizeof(int) * NB);
    uint2*    recs   = (uint2*)alloc(sizeof(uint2) * (size_t)NB * bcap);
    float*    dinv   = (float*)alloc(sizeof(float) * N);
    int*      pstart = (int*)alloc(sizeof(int) * N);
    int*      pcnt   = (int*)alloc(sizeof(int) * N);
    __half*   A      = (__half*)alloc(sizeof(__half) * (size_t)N * HF);
    float*    C      = (float*)alloc(sizeof(float) * (size_t)N * HF);   // h1 f32 (xw2 input)
    __half*   skiph  = (__half*)alloc(sizeof(__half) * (size_t)N * 64); // h1|h2 f16 for head
    __half*   wp1    = (__half*)alloc(sizeof(__half) * 6144);
    __half*   wp2    = (__half*)alloc(sizeof(__half) * 3072);
    float*    bsum1  = (float*)alloc(sizeof(float) * 128);
    float*    bsum2  = (float*)alloc(sizeof(float) * 128);
    size_t need = (size_t)(p - (char*)d_ws);

    int bN  = (N + T - 1) / T;
    int bE  = (E + T - 1) / T;
    int bNF = (N * HF + T - 1) / T;
    int bN8 = (N + 7) / 8;
    int bG  = (N + 63) / 64;
    int bHM = (N + 63) / 64;
    int bBin = (E + KEDGE - 1) / KEDGE;

    if (ws_size >= need && NB <= MAXNB && bcap <= BCAPS && N <= (1 << 24)) {
        // ---- build ----
        k_zero<<<(NB + T - 1) / T, T, 0, stream>>>(gcur, NB);
        k_binsort<<<bBin, T, 0, stream>>>(src, dst, ew, E, NB, bcap, gcur, recs);
        k_sortb<<<NB, 512, 0, stream>>>(recs, gcur, bcap, pstart, pcnt, dinv, N);
        k_norm<<<NB * 4, T, 0, stream>>>(recs, gcur, bcap, dinv);
        k_pack<<<37, 256, 0, stream>>>(w1ih, b1ih, b1hh, w2ih, b2ih, b2hh,
                                       wp1, wp2, bsum1, bsum2);

        // ---- layer 1: h1 -> C (f32) + skiph[0:32] ----
        k_xw1_h<<<bNF, T, 0, stream>>>(x, g1w, A, N);
        k_gather<<<bG, T, 0, stream>>>(recs, pstart, pcnt, dinv, A,
                                       g1b, bn1g, bn1b, bn1m, bn1v, C, skiph, 0, N);
        // ---- layer 2: h2 -> C (dead after xw2) + skiph[32:64] ----
        k_xw2_h<<<bN8, T, 0, stream>>>(C, g2w, A, N);
        k_gather<<<bG, T, 0, stream>>>(recs, pstart, pcnt, dinv, A,
                                       g2b, bn2g, bn2b, bn2m, bn2v, C, skiph, 32, N);
        // ---- MFMA head ----
        k_headm<<<bHM, T, 0, stream>>>(skiph, x, wp1, wp2, bsum1, bsum2,
                                       lw, lb, out, N);
    } else {
        // ---- fallback: atomic scatter, fp32 ----
        size_t Npad = ((size_t)N + 255) & ~(size_t)255;
        float* fdinv = (float*)d_ws;
        float* fA = fdinv + Npad;
        float* fB = fA + (size_t)N * HF;
        float* fC = fB + (size_t)N * HF;
        int bEF = (int)(((long long)E * HF + T - 1) / T);
        int bH = (N + 255) / 256;

        k_initdeg<<<bN, T, 0, stream>>>(fdinv, N);
        k_deg_only<<<bE, T, 0, stream>>>(dst, ew, fdinv, E);
        k_dinv_f<<<bN, T, 0, stream>>>(fdinv, N);

        k_xw1_f<<<bNF, T, 0, stream>>>(x, g1w, fA, N);
        k_selfloop<<<bNF, T, 0, stream>>>(fA, fdinv, fB, N);
        k_scatter<<<bEF, T, 0, stream>>>(src, dst, ew, fdinv, fA, fB, E * HF);
        k_post<<<bNF, T, 0, stream>>>(fB, g1b, bn1g, bn1b, bn1m, bn1v, fC, N);

        k_xw2_f<<<bN8, T, 0, stream>>>(fC, g2w, fA, N);
        k_selfloop<<<bNF, T, 0, stream>>>(fA, fdinv, fB, N);
        k_scatter<<<bEF, T, 0, stream>>>(src, dst, ew, fdinv, fA, fB, E * HF);
        k_post<<<bNF, T, 0, stream>>>(fB, g2b, bn2g, bn2b, bn2m, bn2v, fB, N);

        k_head<<<bH, T, 0, stream>>>(fC, fB, x, w1ih, b1ih, b1hh, w2ih, b2ih, b2hh,
                                     lw, lb, out, N);
    }
}

// Round 10
// 397.459 us; speedup vs baseline: 1.9735x; 1.0985x over previous
//
#include <hip/hip_runtime.h>
#include <hip/hip_fp16.h>
#include <math.h>

#define BN_EPS 1e-5f
#define HF 32          // hidden features
#define BS 256         // nodes per bucket (8-bit dloc)
#define KEDGE 4096     // edges per binsort block
#define MAXNB 1024     // max buckets supported by binsort LDS
#define BCAPS 5632     // max records per bucket held in k_sortb LDS
#define WQ14 16383.0f  // 14-bit norm quantization

typedef _Float16 half8 __attribute__((ext_vector_type(8)));
typedef float f32x4 __attribute__((ext_vector_type(4)));

// fast transcendentals (trans pipe; error ~1e-7 rel, fine vs 2.2e-2 threshold)
__device__ __forceinline__ float fsig(float x) {
    return __builtin_amdgcn_rcpf(1.0f + __expf(-x));
}
__device__ __forceinline__ float ftanh(float x) {
    return 1.0f - 2.0f * __builtin_amdgcn_rcpf(1.0f + __expf(2.0f * x));
}

// ================= tiny utils =================

__global__ void k_zero(int* __restrict__ p, int n) {
    int i = blockIdx.x * blockDim.x + threadIdx.x;
    if (i < n) p[i] = 0;
}

// ================= Phase A: block-local counting sort into buckets =================

__global__ __launch_bounds__(256) void k_binsort(
        const int* __restrict__ src, const int* __restrict__ dst,
        const float* __restrict__ ew, int E, int NB, int bcap,
        int* __restrict__ gcur, uint2* __restrict__ recs) {
    __shared__ uint2 srec[KEDGE];
    __shared__ unsigned short sbk[KEDGE];
    __shared__ int hist[MAXNB], excl[MAXNB], curs[MAXNB], sbase[MAXNB];

    int tid = threadIdx.x;
    int base = blockIdx.x * KEDGE;
    int cnt = min(KEDGE, E - base);

    for (int i = tid; i < NB; i += 256) hist[i] = 0;
    __syncthreads();

    for (int i = tid; i < cnt; i += 256)
        atomicAdd(&hist[dst[base + i] >> 8], 1);
    __syncthreads();

    if (tid < 64) {
        int run = 0;
        for (int c = 0; c < NB; c += 64) {
            int idx = c + tid;
            int v = (idx < NB) ? hist[idx] : 0;
            int incl = v;
#pragma unroll
            for (int o = 1; o < 64; o <<= 1) {
                int up = __shfl_up(incl, o, 64);
                if (tid >= o) incl += up;
            }
            if (idx < NB) { int e = run + incl - v; excl[idx] = e; curs[idx] = e; }
            run += __shfl(incl, 63, 64);
        }
    }
    __syncthreads();

    for (int i = tid; i < cnt; i += 256) {
        int s = src[base + i];
        int d = dst[base + i];
        float w = ew[base + i];
        int b = d >> 8;
        int pos = atomicAdd(&curs[b], 1);
        srec[pos] = make_uint2(((unsigned)s << 8) | (unsigned)(d & 255), __float_as_uint(w));
        sbk[pos] = (unsigned short)b;
    }
    __syncthreads();

    for (int b = tid; b < NB; b += 256) {
        int len = hist[b];
        sbase[b] = len ? atomicAdd(&gcur[b], len) : 0;
    }
    __syncthreads();

    for (int i = tid; i < cnt; i += 256) {
        int b = sbk[i];
        int off = sbase[b] + (i - excl[b]);
        if (off < bcap) recs[(size_t)b * bcap + off] = srec[i];
    }
}

// ================= Phase B: in-bucket sort + 4B records + dinv (norm fused) =================
// Stages the whole bucket run in LDS, then writes back SORTED 4-byte records
// src(18b)|q14(w*dinv[dst]) in place (dinv[src] applied later in the gather).
// Emits per-node pstart (uint index), pcnt, dinv. No separate k_norm pass.

__global__ __launch_bounds__(512) void k_sortb(
        uint2* __restrict__ recs, const int* __restrict__ gcur, int bcap,
        int* __restrict__ pstart, int* __restrict__ pcnt,
        float* __restrict__ dinv, int n) {
    __shared__ uint2 srec[BCAPS];
    __shared__ int hist[BS], excl[BS], curs[BS];
    __shared__ float wsum[BS];

    int b = blockIdx.x, tid = threadIdx.x;
    int cnt = min(gcur[b], bcap);
    uint2* r = recs + (size_t)b * bcap;

    if (tid < BS) { hist[tid] = 0; wsum[tid] = 1.0f; }  // self-loop weight in wsum
    __syncthreads();

    for (int i = tid; i < cnt; i += 512) {
        uint2 u = r[i];
        srec[i] = u;
        int dl = u.x & 255;
        atomicAdd(&hist[dl], 1);
        atomicAdd(&wsum[dl], __uint_as_float(u.y));
    }
    __syncthreads();

    if (tid < BS) wsum[tid] = rsqrtf(wsum[tid]);  // wsum -> dinv_d (complete)

    if (tid < 64) {
        int run = 0;
        for (int c = 0; c < BS; c += 64) {
            int idx = c + tid;
            int v = hist[idx];
            int incl = v;
#pragma unroll
            for (int o = 1; o < 64; o <<= 1) {
                int up = __shfl_up(incl, o, 64);
                if (tid >= o) incl += up;
            }
            int e = run + incl - v;
            excl[idx] = e; curs[idx] = e;
            run += __shfl(incl, 63, 64);
        }
    }
    __syncthreads();

    // write back sorted 4B records (all source data is in LDS -> in-place safe)
    unsigned* r4 = (unsigned*)r;
    for (int i = tid; i < cnt; i += 512) {
        uint2 u = srec[i];
        int dl = u.x & 255;
        int pos = atomicAdd(&curs[dl], 1);
        float qn = __uint_as_float(u.y) * wsum[dl];       // w * dinv_d  in [0,1)
        unsigned q = (unsigned)(qn * WQ14 + 0.5f);
        if (q > 16383u) q = 16383u;
        r4[pos] = ((u.x >> 8) << 14) | q;
    }

    if (tid < BS) {
        int g = b * BS + tid;
        if (g < n) {
            pstart[g] = 2 * b * bcap + excl[tid];   // uint32 index into recs
            pcnt[g] = hist[tid];
            dinv[g] = wsum[tid];
        }
    }
}

// ================= weight pack for MFMA head (runs once) =================

__global__ void k_pack(const float* __restrict__ wih1, const float* __restrict__ bih1,
                       const float* __restrict__ bhh1, const float* __restrict__ wih2,
                       const float* __restrict__ bih2, const float* __restrict__ bhh2,
                       __half* __restrict__ wp1, __half* __restrict__ wp2,
                       float* __restrict__ bsum1, float* __restrict__ bsum2) {
    const int tg[6] = {0, 16, 64, 80, 96, 112};
    int idx = blockIdx.x * blockDim.x + threadIdx.x;
    if (idx < 6144) {
        int t = idx >> 10, rem = idx & 1023;
        int kc = rem >> 9, rem2 = rem & 511;
        int lane = rem2 >> 3, j = rem2 & 7;
        int g = tg[t] + (lane & 15);
        int k = kc * 32 + (lane >> 4) * 8 + j;
        wp1[idx] = __float2half(wih1[g * 64 + k]);
    } else if (idx < 9216) {
        int i2 = idx - 6144;
        int t = i2 >> 9, rem2 = i2 & 511;
        int lane = rem2 >> 3, j = rem2 & 7;
        int g = tg[t] + (lane & 15);
        int k = (lane >> 4) * 8 + j;
        wp2[i2] = __float2half(wih2[g * 32 + k]);
    } else if (idx < 9344) {
        int i = idx - 9216;
        bsum1[i] = bih1[i] + bhh1[i];
    } else if (idx < 9472) {
        int i = idx - 9344;
        bsum2[i] = bih2[i] + bhh2[i];
    }
}

// ================= dense feature transforms (fp16 out) =================

__global__ void k_xw1_h(const float* __restrict__ x, const float* __restrict__ W,
                        __half* __restrict__ out, int n) {
    int idx = blockIdx.x * blockDim.x + threadIdx.x;
    if (idx >= n * HF) return;
    int nn = idx >> 5, f = idx & 31;
    const float4 xr = *(const float4*)(x + (size_t)nn * 4);
    float acc = xr.x * W[f] + xr.y * W[32 + f] + xr.z * W[64 + f] + xr.w * W[96 + f];
    out[idx] = __float2half(acc);
}

__global__ void k_xw2_h(const float* __restrict__ Hin, const float* __restrict__ W,
                        __half* __restrict__ out, int n) {
    __shared__ float sW[32 * 32];
    __shared__ float sH[8][32];
    int tid = threadIdx.x;
    for (int i = tid; i < 1024; i += 256) sW[i] = W[i];
    int r = tid >> 5, f = tid & 31;
    int nn = blockIdx.x * 8 + r;
    if (nn < n) sH[r][f] = Hin[(size_t)nn * HF + f];
    __syncthreads();
    if (nn >= n) return;
    float acc = 0.0f;
#pragma unroll
    for (int k = 0; k < 32; ++k) acc += sH[r][k] * sW[k * 32 + f];
    out[(size_t)nn * HF + f] = __float2half(acc);
}

// ================= gather: per-node aggregation (4B recs) + fused epilogue =================
// 4 lanes per node, 16B fp16 row loads. nrm = q14 * dinv[src] (dinv L2-hot).
// Unroll 4 -> 4 independent row loads in flight per thread.

__global__ __launch_bounds__(256) void k_gather(
        const unsigned* __restrict__ recs4, const int* __restrict__ pstart,
        const int* __restrict__ pcnt, const float* __restrict__ dinv,
        const __half* __restrict__ A,
        const float* __restrict__ bias, const float* __restrict__ gamma,
        const float* __restrict__ beta, const float* __restrict__ mean,
        const float* __restrict__ var,
        float* __restrict__ Hout, __half* __restrict__ skiph, int uoff, int n) {
    int g = blockIdx.x * 64 + (threadIdx.x >> 2);
    int lane = threadIdx.x & 3;
    if (g >= n) return;

    float dig = dinv[g];
    float sl = dig * dig;
    uint4 srow = ((const uint4*)(A + ((size_t)g << 5)))[lane];
    float acc[8];
    {
        const __half2* h = (const __half2*)&srow;
#pragma unroll
        for (int k = 0; k < 4; ++k) {
            float2 f = __half22float2(h[k]);
            acc[2 * k] = sl * f.x; acc[2 * k + 1] = sl * f.y;
        }
    }

    const float qs = 1.0f / WQ14;
    int cn = pcnt[g];
    const unsigned* r = recs4 + pstart[g];
    int e = 0;
    for (; e + 4 <= cn; e += 4) {
        unsigned u0 = r[e], u1 = r[e + 1], u2 = r[e + 2], u3 = r[e + 3];
        uint4 row0 = ((const uint4*)(A + ((size_t)(u0 >> 14) << 5)))[lane];
        uint4 row1 = ((const uint4*)(A + ((size_t)(u1 >> 14) << 5)))[lane];
        uint4 row2 = ((const uint4*)(A + ((size_t)(u2 >> 14) << 5)))[lane];
        uint4 row3 = ((const uint4*)(A + ((size_t)(u3 >> 14) << 5)))[lane];
        float n0 = (float)(u0 & 16383u) * qs * dinv[u0 >> 14];
        float n1 = (float)(u1 & 16383u) * qs * dinv[u1 >> 14];
        float n2 = (float)(u2 & 16383u) * qs * dinv[u2 >> 14];
        float n3 = (float)(u3 & 16383u) * qs * dinv[u3 >> 14];
        const __half2* h0 = (const __half2*)&row0;
        const __half2* h1 = (const __half2*)&row1;
        const __half2* h2 = (const __half2*)&row2;
        const __half2* h3 = (const __half2*)&row3;
#pragma unroll
        for (int k = 0; k < 4; ++k) {
            float2 f0 = __half22float2(h0[k]);
            float2 f1 = __half22float2(h1[k]);
            float2 f2 = __half22float2(h2[k]);
            float2 f3 = __half22float2(h3[k]);
            acc[2 * k]     += n0 * f0.x + n1 * f1.x + n2 * f2.x + n3 * f3.x;
            acc[2 * k + 1] += n0 * f0.y + n1 * f1.y + n2 * f2.y + n3 * f3.y;
        }
    }
    for (; e < cn; ++e) {
        unsigned u0 = r[e];
        uint4 row0 = ((const uint4*)(A + ((size_t)(u0 >> 14) << 5)))[lane];
        float n0 = (float)(u0 & 16383u) * qs * dinv[u0 >> 14];
        const __half2* h0 = (const __half2*)&row0;
#pragma unroll
        for (int k = 0; k < 4; ++k) {
            float2 f0 = __half22float2(h0[k]);
            acc[2 * k]     += n0 * f0.x;
            acc[2 * k + 1] += n0 * f0.y;
        }
    }

    int fq = lane * 8;
    float o[8];
#pragma unroll
    for (int k = 0; k < 8; ++k) {
        float v = fmaxf(acc[k] + bias[fq + k], 0.0f);
        o[k] = (v - mean[fq + k]) * gamma[fq + k] * rsqrtf(var[fq + k] + BN_EPS) + beta[fq + k];
    }
    float* dst = Hout + ((size_t)g << 5) + fq;
    *(float4*)dst = make_float4(o[0], o[1], o[2], o[3]);
    *(float4*)(dst + 4) = make_float4(o[4], o[5], o[6], o[7]);

    union { __half h[8]; uint4 q; } hv;
#pragma unroll
    for (int k = 0; k < 8; ++k) hv.h[k] = __float2half(o[k]);
    *(uint4*)(skiph + (size_t)g * 64 + uoff + fq) = hv.q;
}

// ================= MFMA fused head: LSTM1 + LSTM2 + linear =================

__global__ __launch_bounds__(256) void k_headm(
        const __half* __restrict__ skiph, const float* __restrict__ x,
        const __half* __restrict__ wp1, const __half* __restrict__ wp2,
        const float* __restrict__ bsum1, const float* __restrict__ bsum2,
        const float* __restrict__ lw, const float* __restrict__ lb,
        float* __restrict__ out, int n) {
    __shared__ __align__(16) __half H1lds[4 * 16 * 40];
    int tid = threadIdx.x;
    int w = tid >> 6, l = tid & 63;
    int quad = l >> 4, c = l & 15;
    int node_base = blockIdx.x * 64 + w * 16;

    int arow = node_base + c; if (arow > n - 1) arow = n - 1;
    const half8* ap = (const half8*)(skiph + (size_t)arow * 64);
    half8 a0 = ap[quad];
    half8 a1 = ap[4 + quad];

    const half8* b1 = (const half8*)wp1;
    f32x4 d[6];
#pragma unroll
    for (int t = 0; t < 6; ++t) {
        f32x4 acc = {0.0f, 0.0f, 0.0f, 0.0f};
        acc = __builtin_amdgcn_mfma_f32_16x16x32_f16(a0, b1[(t * 2 + 0) * 64 + l], acc, 0, 0, 0);
        acc = __builtin_amdgcn_mfma_f32_16x16x32_f16(a1, b1[(t * 2 + 1) * 64 + l], acc, 0, 0, 0);
        d[t] = acc;
    }

    float bi0 = bsum1[c],      bi1 = bsum1[16 + c];
    float bg0 = bsum1[64 + c], bg1 = bsum1[80 + c];
    float bo0 = bsum1[96 + c], bo1 = bsum1[112 + c];
    float lwc0 = lw[c], lwc1 = lw[c + 16];

    float pa[4];
#pragma unroll
    for (int r = 0; r < 4; ++r) {
        float cc0 = fsig(d[0][r] + bi0) * ftanh(d[2][r] + bg0);
        float h0 = fsig(d[4][r] + bo0) * ftanh(cc0);
        float cc1 = fsig(d[1][r] + bi1) * ftanh(d[3][r] + bg1);
        float h1 = fsig(d[5][r] + bo1) * ftanh(cc1);
        pa[r] = fmaxf(h0, 0.0f) * lwc0 + fmaxf(h1, 0.0f) * lwc1;
        __half* hp = H1lds + (w * 16 + quad * 4 + r) * 40;
        hp[c] = __float2half(h0);
        hp[c + 16] = __float2half(h1);
    }
    __syncthreads();

    half8 a2 = *(const half8*)(H1lds + (w * 16 + c) * 40 + quad * 8);

    const half8* b2 = (const half8*)wp2;
    f32x4 e[6];
#pragma unroll
    for (int t = 0; t < 6; ++t) {
        f32x4 acc = {0.0f, 0.0f, 0.0f, 0.0f};
        e[t] = __builtin_amdgcn_mfma_f32_16x16x32_f16(a2, b2[t * 64 + l], acc, 0, 0, 0);
    }

    float ci0 = bsum2[c],      ci1 = bsum2[16 + c];
    float cg0 = bsum2[64 + c], cg1 = bsum2[80 + c];
    float co0 = bsum2[96 + c], co1 = bsum2[112 + c];
    float lw2c0 = lw[32 + c], lw2c1 = lw[48 + c];
#pragma unroll
    for (int r = 0; r < 4; ++r) {
        float cc0 = fsig(e[0][r] + ci0) * ftanh(e[2][r] + cg0);
        float h0 = fsig(e[4][r] + co0) * ftanh(cc0);
        float cc1 = fsig(e[1][r] + ci1) * ftanh(e[3][r] + cg1);
        float h1 = fsig(e[5][r] + co1) * ftanh(cc1);
        pa[r] += fmaxf(h0, 0.0f) * lw2c0 + fmaxf(h1, 0.0f) * lw2c1;
    }

#pragma unroll
    for (int m = 1; m < 16; m <<= 1) {
#pragma unroll
        for (int r = 0; r < 4; ++r) pa[r] += __shfl_xor(pa[r], m, 64);
    }

    if (c < 4) {
        int node = node_base + quad * 4 + c;
        if (node < n) {
            const float4 xv = *(const float4*)(x + (size_t)node * 4);
            out[node] = pa[c] + lb[0]
                + fmaxf(xv.x, 0.0f) * lw[64] + fmaxf(xv.y, 0.0f) * lw[65]
                + fmaxf(xv.z, 0.0f) * lw[66] + fmaxf(xv.w, 0.0f) * lw[67];
        }
    }
}

// ================= fallback (atomic scatter, fp32) =================

__global__ void k_initdeg(float* __restrict__ deg, int n) {
    int i = blockIdx.x * blockDim.x + threadIdx.x;
    if (i < n) deg[i] = 1.0f;
}

__global__ void k_deg_only(const int* __restrict__ dst, const float* __restrict__ ew,
                           float* __restrict__ deg, int E) {
    int e = blockIdx.x * blockDim.x + threadIdx.x;
    if (e < E) atomicAdd(&deg[dst[e]], ew[e]);
}

__global__ void k_dinv_f(float* __restrict__ deg, int n) {
    int i = blockIdx.x * blockDim.x + threadIdx.x;
    if (i < n) {
        float d = deg[i];
        deg[i] = d > 0.0f ? rsqrtf(d) : 0.0f;
    }
}

__global__ void k_xw1_f(const float* __restrict__ x, const float* __restrict__ W,
                        float* __restrict__ out, int n) {
    int idx = blockIdx.x * blockDim.x + threadIdx.x;
    if (idx >= n * HF) return;
    int nn = idx >> 5, f = idx & 31;
    const float4 xr = *(const float4*)(x + (size_t)nn * 4);
    out[idx] = xr.x * W[f] + xr.y * W[32 + f] + xr.z * W[64 + f] + xr.w * W[96 + f];
}

__global__ void k_xw2_f(const float* __restrict__ Hin, const float* __restrict__ W,
                        float* __restrict__ out, int n) {
    __shared__ float sW[32 * 32];
    __shared__ float sH[8][32];
    int tid = threadIdx.x;
    for (int i = tid; i < 1024; i += 256) sW[i] = W[i];
    int r = tid >> 5, f = tid & 31;
    int nn = blockIdx.x * 8 + r;
    if (nn < n) sH[r][f] = Hin[(size_t)nn * HF + f];
    __syncthreads();
    if (nn >= n) return;
    float acc = 0.0f;
#pragma unroll
    for (int k = 0; k < 32; ++k) acc += sH[r][k] * sW[k * 32 + f];
    out[(size_t)nn * HF + f] = acc;
}

__global__ void k_selfloop(const float* __restrict__ A, const float* __restrict__ dinv,
                           float* __restrict__ B, int n) {
    int idx = blockIdx.x * blockDim.x + threadIdx.x;
    if (idx >= n * HF) return;
    int nn = idx >> 5;
    float di = dinv[nn];
    B[idx] = di * di * A[idx];
}

__global__ void k_scatter(const int* __restrict__ src, const int* __restrict__ dst,
                          const float* __restrict__ ew, const float* __restrict__ dinv,
                          const float* __restrict__ A, float* __restrict__ B, int total) {
    int idx = blockIdx.x * blockDim.x + threadIdx.x;
    if (idx >= total) return;
    int e = idx >> 5, f = idx & 31;
    int s = src[e], d = dst[e];
    float norm = dinv[s] * ew[e] * dinv[d];
    atomicAdd(&B[d * HF + f], norm * A[s * HF + f]);
}

__global__ void k_post(const float* __restrict__ B, const float* __restrict__ bias,
                       const float* __restrict__ gamma, const float* __restrict__ beta,
                       const float* __restrict__ mean, const float* __restrict__ var,
                       float* __restrict__ Hout, int n) {
    int idx = blockIdx.x * blockDim.x + threadIdx.x;
    if (idx >= n * HF) return;
    int f = idx & 31;
    float v = fmaxf(B[idx] + bias[f], 0.0f);
    float sc = gamma[f] * rsqrtf(var[f] + BN_EPS);
    Hout[idx] = (v - mean[f]) * sc + beta[f];
}

__global__ __launch_bounds__(256) void k_head(
        const float* __restrict__ h1, const float* __restrict__ h2,
        const float* __restrict__ x,
        const float* __restrict__ wih1, const float* __restrict__ bih1, const float* __restrict__ bhh1,
        const float* __restrict__ wih2, const float* __restrict__ bih2, const float* __restrict__ bhh2,
        const float* __restrict__ lw, const float* __restrict__ lb,
        float* __restrict__ out, int n) {
    __shared__ float sH1[32 * 256];
    int tid = threadIdx.x;
    int nn = blockIdx.x * 256 + tid;
    if (nn >= n) return;

    const float4* a = (const float4*)(h1 + (size_t)nn * HF);
    const float4* b = (const float4*)(h2 + (size_t)nn * HF);
    float skip[64];
#pragma unroll
    for (int q = 0; q < 8; ++q) {
        float4 v = a[q];
        skip[4 * q] = v.x; skip[4 * q + 1] = v.y; skip[4 * q + 2] = v.z; skip[4 * q + 3] = v.w;
        float4 u = b[q];
        skip[32 + 4 * q] = u.x; skip[33 + 4 * q] = u.y; skip[34 + 4 * q] = u.z; skip[35 + 4 * q] = u.w;
    }

    float oa = lb[0];
#pragma unroll 1
    for (int j = 0; j < 32; ++j) {
        const float4* wi = (const float4*)(wih1 + (size_t)j * 64);
        const float4* wg = (const float4*)(wih1 + (size_t)(64 + j) * 64);
        const float4* wo = (const float4*)(wih1 + (size_t)(96 + j) * 64);
        float gi = bih1[j] + bhh1[j];
        float gg = bih1[64 + j] + bhh1[64 + j];
        float go = bih1[96 + j] + bhh1[96 + j];
#pragma unroll
        for (int q = 0; q < 16; ++q) {
            float4 aa = wi[q], bb = wg[q], cc4 = wo[q];
            float s0 = skip[4 * q], s1 = skip[4 * q + 1], s2 = skip[4 * q + 2], s3 = skip[4 * q + 3];
            gi += aa.x * s0 + aa.y * s1 + aa.z * s2 + aa.w * s3;
            gg += bb.x * s0 + bb.y * s1 + bb.z * s2 + bb.w * s3;
            go += cc4.x * s0 + cc4.y * s1 + cc4.z * s2 + cc4.w * s3;
        }
        float cc = fsig(gi) * ftanh(gg);
        float hh = fsig(go) * ftanh(cc);
        sH1[j * 256 + tid] = hh;
        oa += fmaxf(hh, 0.0f) * lw[j];
    }

#pragma unroll 1
    for (int j = 0; j < 32; ++j) {
        const float4* wi = (const float4*)(wih2 + (size_t)j * 32);
        const float4* wg = (const float4*)(wih2 + (size_t)(64 + j) * 32);
        const float4* wo = (const float4*)(wih2 + (size_t)(96 + j) * 32);
        float gi = bih2[j] + bhh2[j];
        float gg = bih2[64 + j] + bhh2[64 + j];
        float go = bih2[96 + j] + bhh2[96 + j];
#pragma unroll
        for (int q = 0; q < 8; ++q) {
            float4 aa = wi[q], bb = wg[q], cc4 = wo[q];
            float s0 = sH1[(4 * q) * 256 + tid], s1 = sH1[(4 * q + 1) * 256 + tid];
            float s2 = sH1[(4 * q + 2) * 256 + tid], s3 = sH1[(4 * q + 3) * 256 + tid];
            gi += aa.x * s0 + aa.y * s1 + aa.z * s2 + aa.w * s3;
            gg += bb.x * s0 + bb.y * s1 + bb.z * s2 + bb.w * s3;
            go += cc4.x * s0 + cc4.y * s1 + cc4.z * s2 + cc4.w * s3;
        }
        float cc = fsig(gi) * ftanh(gg);
        float hh = fsig(go) * ftanh(cc);
        oa += fmaxf(hh, 0.0f) * lw[32 + j];
    }

    const float4 xv = *(const float4*)(x + (size_t)nn * 4);
    oa += fmaxf(xv.x, 0.0f) * lw[64] + fmaxf(xv.y, 0.0f) * lw[65] +
          fmaxf(xv.z, 0.0f) * lw[66] + fmaxf(xv.w, 0.0f) * lw[67];
    out[nn] = oa;
}

// ================= launch =================

extern "C" void kernel_launch(void* const* d_in, const int* in_sizes, int n_in,
                              void* d_out, int out_size, void* d_ws, size_t ws_size,
                              hipStream_t stream) {
    const float* x   = (const float*)d_in[0];
    const int*   ei  = (const int*)d_in[1];
    const float* ew  = (const float*)d_in[2];
    const float* g1w = (const float*)d_in[3];
    const float* g1b = (const float*)d_in[4];
    const float* g2w = (const float*)d_in[5];
    const float* g2b = (const float*)d_in[6];
    const float* bn1g = (const float*)d_in[7];
    const float* bn1b = (const float*)d_in[8];
    const float* bn1m = (const float*)d_in[9];
    const float* bn1v = (const float*)d_in[10];
    const float* bn2g = (const float*)d_in[11];
    const float* bn2b = (const float*)d_in[12];
    const float* bn2m = (const float*)d_in[13];
    const float* bn2v = (const float*)d_in[14];
    const float* w1ih = (const float*)d_in[15];
    const float* b1ih = (const float*)d_in[17];
    const float* b1hh = (const float*)d_in[18];
    const float* w2ih = (const float*)d_in[19];
    const float* b2ih = (const float*)d_in[21];
    const float* b2hh = (const float*)d_in[22];
    const float* lw   = (const float*)d_in[23];
    const float* lb   = (const float*)d_in[24];
    float* out = (float*)d_out;

    const int N = in_sizes[0] / 4;
    const int E = in_sizes[2];
    const int* src = ei;
    const int* dst = ei + E;

    const int T = 256;
    const int NB = (N + BS - 1) / BS;
    long long meanb = ((long long)BS * E) / (N > 0 ? N : 1);
    int bcap = (int)(meanb + meanb / 4 + 128);

    // workspace layout (256B-aligned regions)
    char* p = (char*)d_ws;
    auto alloc = [&](size_t bytes) { char* q = p; p += (bytes + 255) & ~(size_t)255; return q; };
    int*      gcur   = (int*)alloc(sizeof(int) * NB);
    uint2*    recs   = (uint2*)alloc(sizeof(uint2) * (size_t)NB * bcap);
    float*    dinv   = (float*)alloc(sizeof(float) * N);
    int*      pstart = (int*)alloc(sizeof(int) * N);
    int*      pcnt   = (int*)alloc(sizeof(int) * N);
    __half*   A      = (__half*)alloc(sizeof(__half) * (size_t)N * HF);
    float*    C      = (float*)alloc(sizeof(float) * (size_t)N * HF);   // h1 f32 (xw2 input)
    __half*   skiph  = (__half*)alloc(sizeof(__half) * (size_t)N * 64); // h1|h2 f16 for head
    __half*   wp1    = (__half*)alloc(sizeof(__half) * 6144);
    __half*   wp2    = (__half*)alloc(sizeof(__half) * 3072);
    float*    bsum1  = (float*)alloc(sizeof(float) * 128);
    float*    bsum2  = (float*)alloc(sizeof(float) * 128);
    size_t need = (size_t)(p - (char*)d_ws);

    int bN  = (N + T - 1) / T;
    int bE  = (E + T - 1) / T;
    int bNF = (N * HF + T - 1) / T;
    int bN8 = (N + 7) / 8;
    int bG  = (N + 63) / 64;
    int bHM = (N + 63) / 64;
    int bBin = (E + KEDGE - 1) / KEDGE;

    if (ws_size >= need && NB <= MAXNB && bcap <= BCAPS && N <= (1 << 18)) {
        // ---- build ----
        k_zero<<<(NB + T - 1) / T, T, 0, stream>>>(gcur, NB);
        k_binsort<<<bBin, T, 0, stream>>>(src, dst, ew, E, NB, bcap, gcur, recs);
        k_sortb<<<NB, 512, 0, stream>>>(recs, gcur, bcap, pstart, pcnt, dinv, N);
        k_pack<<<37, 256, 0, stream>>>(w1ih, b1ih, b1hh, w2ih, b2ih, b2hh,
                                       wp1, wp2, bsum1, bsum2);

        // ---- layer 1: h1 -> C (f32) + skiph[0:32] ----
        k_xw1_h<<<bNF, T, 0, stream>>>(x, g1w, A, N);
        k_gather<<<bG, T, 0, stream>>>((const unsigned*)recs, pstart, pcnt, dinv, A,
                                       g1b, bn1g, bn1b, bn1m, bn1v, C, skiph, 0, N);
        // ---- layer 2: h2 -> skiph[32:64] ----
        k_xw2_h<<<bN8, T, 0, stream>>>(C, g2w, A, N);
        k_gather<<<bG, T, 0, stream>>>((const unsigned*)recs, pstart, pcnt, dinv, A,
                                       g2b, bn2g, bn2b, bn2m, bn2v, C, skiph, 32, N);
        // ---- MFMA head ----
        k_headm<<<bHM, T, 0, stream>>>(skiph, x, wp1, wp2, bsum1, bsum2,
                                       lw, lb, out, N);
    } else {
        // ---- fallback: atomic scatter, fp32 ----
        size_t Npad = ((size_t)N + 255) & ~(size_t)255;
        float* fdinv = (float*)d_ws;
        float* fA = fdinv + Npad;
        float* fB = fA + (size_t)N * HF;
        float* fC = fB + (size_t)N * HF;
        int bEF = (int)(((long long)E * HF + T - 1) / T);
        int bH = (N + 255) / 256;

        k_initdeg<<<bN, T, 0, stream>>>(fdinv, N);
        k_deg_only<<<bE, T, 0, stream>>>(dst, ew, fdinv, E);
        k_dinv_f<<<bN, T, 0, stream>>>(fdinv, N);

        k_xw1_f<<<bNF, T, 0, stream>>>(x, g1w, fA, N);
        k_selfloop<<<bNF, T, 0, stream>>>(fA, fdinv, fB, N);
        k_scatter<<<bEF, T, 0, stream>>>(src, dst, ew, fdinv, fA, fB, E * HF);
        k_post<<<bNF, T, 0, stream>>>(fB, g1b, bn1g, bn1b, bn1m, bn1v, fC, N);

        k_xw2_f<<<bN8, T, 0, stream>>>(fC, g2w, fA, N);
        k_selfloop<<<bNF, T, 0, stream>>>(fA, fdinv, fB, N);
        k_scatter<<<bEF, T, 0, stream>>>(src, dst, ew, fdinv, fA, fB, E * HF);
        k_post<<<bNF, T, 0, stream>>>(fB, g2b, bn2g, bn2b, bn2m, bn2v, fB, N);

        k_head<<<bH, T, 0, stream>>>(fC, fB, x, w1ih, b1ih, b1hh, w2ih, b2ih, b2hh,
                                     lw, lb, out, N);
    }
}

// Round 11
// 368.397 us; speedup vs baseline: 2.1292x; 1.0789x over previous
//
#include <hip/hip_runtime.h>
#include <hip/hip_fp16.h>
#include <math.h>

#define BN_EPS 1e-5f
#define HF 32          // hidden features
#define BS 256         // nodes per bucket (8-bit dloc)
#define KEDGE 4096     // edges per binsort block
#define MAXNB 1024     // max buckets supported by binsort LDS
#define BCAPS 5632     // max records per bucket held in k_sortb LDS
#define WQ14 16383.0f  // 14-bit norm quantization

typedef _Float16 half8 __attribute__((ext_vector_type(8)));
typedef float f32x4 __attribute__((ext_vector_type(4)));

// fast transcendentals (trans pipe; error ~1e-7 rel, fine vs 2.2e-2 threshold)
__device__ __forceinline__ float fsig(float x) {
    return __builtin_amdgcn_rcpf(1.0f + __expf(-x));
}
__device__ __forceinline__ float ftanh(float x) {
    return 1.0f - 2.0f * __builtin_amdgcn_rcpf(1.0f + __expf(2.0f * x));
}

// ================= tiny utils =================

__global__ void k_zero(int* __restrict__ p, int n) {
    int i = blockIdx.x * blockDim.x + threadIdx.x;
    if (i < n) p[i] = 0;
}

// ================= Phase A: block-local counting sort into buckets =================

__global__ __launch_bounds__(256) void k_binsort(
        const int* __restrict__ src, const int* __restrict__ dst,
        const float* __restrict__ ew, int E, int NB, int bcap,
        int* __restrict__ gcur, uint2* __restrict__ recs) {
    __shared__ uint2 srec[KEDGE];
    __shared__ unsigned short sbk[KEDGE];
    __shared__ int hist[MAXNB], excl[MAXNB], curs[MAXNB], sbase[MAXNB];

    int tid = threadIdx.x;
    int base = blockIdx.x * KEDGE;
    int cnt = min(KEDGE, E - base);

    for (int i = tid; i < NB; i += 256) hist[i] = 0;
    __syncthreads();

    for (int i = tid; i < cnt; i += 256)
        atomicAdd(&hist[dst[base + i] >> 8], 1);
    __syncthreads();

    if (tid < 64) {
        int run = 0;
        for (int c = 0; c < NB; c += 64) {
            int idx = c + tid;
            int v = (idx < NB) ? hist[idx] : 0;
            int incl = v;
#pragma unroll
            for (int o = 1; o < 64; o <<= 1) {
                int up = __shfl_up(incl, o, 64);
                if (tid >= o) incl += up;
            }
            if (idx < NB) { int e = run + incl - v; excl[idx] = e; curs[idx] = e; }
            run += __shfl(incl, 63, 64);
        }
    }
    __syncthreads();

    for (int i = tid; i < cnt; i += 256) {
        int s = src[base + i];
        int d = dst[base + i];
        float w = ew[base + i];
        int b = d >> 8;
        int pos = atomicAdd(&curs[b], 1);
        srec[pos] = make_uint2(((unsigned)s << 8) | (unsigned)(d & 255), __float_as_uint(w));
        sbk[pos] = (unsigned short)b;
    }
    __syncthreads();

    for (int b = tid; b < NB; b += 256) {
        int len = hist[b];
        sbase[b] = len ? atomicAdd(&gcur[b], len) : 0;
    }
    __syncthreads();

    for (int i = tid; i < cnt; i += 256) {
        int b = sbk[i];
        int off = sbase[b] + (i - excl[b]);
        if (off < bcap) recs[(size_t)b * bcap + off] = srec[i];
    }
}

// ================= Phase B: in-bucket sort + 4B records + dinv (norm fused) =================

__global__ __launch_bounds__(512) void k_sortb(
        uint2* __restrict__ recs, const int* __restrict__ gcur, int bcap,
        int* __restrict__ pstart, int* __restrict__ pcnt,
        float* __restrict__ dinv, int n) {
    __shared__ uint2 srec[BCAPS];
    __shared__ int hist[BS], excl[BS], curs[BS];
    __shared__ float wsum[BS];

    int b = blockIdx.x, tid = threadIdx.x;
    int cnt = min(gcur[b], bcap);
    uint2* r = recs + (size_t)b * bcap;

    if (tid < BS) { hist[tid] = 0; wsum[tid] = 1.0f; }  // self-loop weight in wsum
    __syncthreads();

    for (int i = tid; i < cnt; i += 512) {
        uint2 u = r[i];
        srec[i] = u;
        int dl = u.x & 255;
        atomicAdd(&hist[dl], 1);
        atomicAdd(&wsum[dl], __uint_as_float(u.y));
    }
    __syncthreads();

    if (tid < BS) wsum[tid] = rsqrtf(wsum[tid]);  // wsum -> dinv_d (complete)

    if (tid < 64) {
        int run = 0;
        for (int c = 0; c < BS; c += 64) {
            int idx = c + tid;
            int v = hist[idx];
            int incl = v;
#pragma unroll
            for (int o = 1; o < 64; o <<= 1) {
                int up = __shfl_up(incl, o, 64);
                if (tid >= o) incl += up;
            }
            int e = run + incl - v;
            excl[idx] = e; curs[idx] = e;
            run += __shfl(incl, 63, 64);
        }
    }
    __syncthreads();

    // write back sorted 4B records (all source data is in LDS -> in-place safe)
    unsigned* r4 = (unsigned*)r;
    for (int i = tid; i < cnt; i += 512) {
        uint2 u = srec[i];
        int dl = u.x & 255;
        int pos = atomicAdd(&curs[dl], 1);
        float qn = __uint_as_float(u.y) * wsum[dl];       // w * dinv_d  in [0,1)
        unsigned q = (unsigned)(qn * WQ14 + 0.5f);
        if (q > 16383u) q = 16383u;
        r4[pos] = ((u.x >> 8) << 14) | q;
    }

    if (tid < BS) {
        int g = b * BS + tid;
        if (g < n) {
            pstart[g] = 2 * b * bcap + excl[tid];   // uint32 index into recs
            pcnt[g] = hist[tid];
            dinv[g] = wsum[tid];
        }
    }
}

// ================= weight pack for MFMA head (runs once) =================

__global__ void k_pack(const float* __restrict__ wih1, const float* __restrict__ bih1,
                       const float* __restrict__ bhh1, const float* __restrict__ wih2,
                       const float* __restrict__ bih2, const float* __restrict__ bhh2,
                       __half* __restrict__ wp1, __half* __restrict__ wp2,
                       float* __restrict__ bsum1, float* __restrict__ bsum2) {
    const int tg[6] = {0, 16, 64, 80, 96, 112};
    int idx = blockIdx.x * blockDim.x + threadIdx.x;
    if (idx < 6144) {
        int t = idx >> 10, rem = idx & 1023;
        int kc = rem >> 9, rem2 = rem & 511;
        int lane = rem2 >> 3, j = rem2 & 7;
        int g = tg[t] + (lane & 15);
        int k = kc * 32 + (lane >> 4) * 8 + j;
        wp1[idx] = __float2half(wih1[g * 64 + k]);
    } else if (idx < 9216) {
        int i2 = idx - 6144;
        int t = i2 >> 9, rem2 = i2 & 511;
        int lane = rem2 >> 3, j = rem2 & 7;
        int g = tg[t] + (lane & 15);
        int k = (lane >> 4) * 8 + j;
        wp2[i2] = __float2half(wih2[g * 32 + k]);
    } else if (idx < 9344) {
        int i = idx - 9216;
        bsum1[i] = bih1[i] + bhh1[i];
    } else if (idx < 9472) {
        int i = idx - 9344;
        bsum2[i] = bih2[i] + bhh2[i];
    }
}

// ================= gather layer 1: xw1 FUSED (x is L2-resident, 3.2 MB) =================
// Per edge: load x[src] (16B, lane-broadcast), project to 8 features in-register.
// No A matrix for layer 1 at all. Writes fp16 h1 into skiph[0:32].

__global__ __launch_bounds__(256) void k_gather_x1(
        const unsigned* __restrict__ recs4, const int* __restrict__ pstart,
        const int* __restrict__ pcnt, const float* __restrict__ dinv,
        const float* __restrict__ x, const float* __restrict__ W1,
        const float* __restrict__ bias, const float* __restrict__ gamma,
        const float* __restrict__ beta, const float* __restrict__ mean,
        const float* __restrict__ var,
        __half* __restrict__ skiph, int n) {
    __shared__ float sW[128];
    int tid = threadIdx.x;
    if (tid < 128) sW[tid] = W1[tid];
    __syncthreads();

    int g = blockIdx.x * 64 + (tid >> 2);
    int lane = tid & 3;
    if (g >= n) return;
    int fq = lane * 8;

    float w[4][8];
#pragma unroll
    for (int r = 0; r < 4; ++r)
#pragma unroll
        for (int k = 0; k < 8; ++k) w[r][k] = sW[r * 32 + fq + k];

    float dig = dinv[g];
    float sl = dig * dig;
    float4 xg = *(const float4*)(x + (size_t)g * 4);
    float acc[8];
#pragma unroll
    for (int k = 0; k < 8; ++k)
        acc[k] = sl * (xg.x * w[0][k] + xg.y * w[1][k] + xg.z * w[2][k] + xg.w * w[3][k]);

    const float qs = 1.0f / WQ14;
    int cn = pcnt[g];
    const unsigned* r = recs4 + pstart[g];
    int e = 0;
    for (; e + 4 <= cn; e += 4) {
        unsigned u0 = r[e], u1 = r[e + 1], u2 = r[e + 2], u3 = r[e + 3];
        float4 x0 = *(const float4*)(x + (size_t)(u0 >> 14) * 4);
        float4 x1 = *(const float4*)(x + (size_t)(u1 >> 14) * 4);
        float4 x2 = *(const float4*)(x + (size_t)(u2 >> 14) * 4);
        float4 x3 = *(const float4*)(x + (size_t)(u3 >> 14) * 4);
        float n0 = (float)(u0 & 16383u) * qs * dinv[u0 >> 14];
        float n1 = (float)(u1 & 16383u) * qs * dinv[u1 >> 14];
        float n2 = (float)(u2 & 16383u) * qs * dinv[u2 >> 14];
        float n3 = (float)(u3 & 16383u) * qs * dinv[u3 >> 14];
#pragma unroll
        for (int k = 0; k < 8; ++k) {
            acc[k] += n0 * (x0.x * w[0][k] + x0.y * w[1][k] + x0.z * w[2][k] + x0.w * w[3][k]);
            acc[k] += n1 * (x1.x * w[0][k] + x1.y * w[1][k] + x1.z * w[2][k] + x1.w * w[3][k]);
            acc[k] += n2 * (x2.x * w[0][k] + x2.y * w[1][k] + x2.z * w[2][k] + x2.w * w[3][k]);
            acc[k] += n3 * (x3.x * w[0][k] + x3.y * w[1][k] + x3.z * w[2][k] + x3.w * w[3][k]);
        }
    }
    for (; e < cn; ++e) {
        unsigned u0 = r[e];
        float4 x0 = *(const float4*)(x + (size_t)(u0 >> 14) * 4);
        float n0 = (float)(u0 & 16383u) * qs * dinv[u0 >> 14];
#pragma unroll
        for (int k = 0; k < 8; ++k)
            acc[k] += n0 * (x0.x * w[0][k] + x0.y * w[1][k] + x0.z * w[2][k] + x0.w * w[3][k]);
    }

    union { __half h[8]; uint4 q; } hv;
#pragma unroll
    for (int k = 0; k < 8; ++k) {
        float v = fmaxf(acc[k] + bias[fq + k], 0.0f);
        hv.h[k] = __float2half((v - mean[fq + k]) * gamma[fq + k] * rsqrtf(var[fq + k] + BN_EPS) + beta[fq + k]);
    }
    *(uint4*)(skiph + (size_t)g * 64 + fq) = hv.q;
}

// ================= xw2: h1(fp16, from skiph) @ W2 -> A fp16 =================

__global__ void k_xw2_h(const __half* __restrict__ skiph, const float* __restrict__ W,
                        __half* __restrict__ out, int n) {
    __shared__ float sW[32 * 32];
    __shared__ float sH[8][32];
    int tid = threadIdx.x;
    for (int i = tid; i < 1024; i += 256) sW[i] = W[i];
    int r = tid >> 5, f = tid & 31;
    int nn = blockIdx.x * 8 + r;
    if (nn < n) sH[r][f] = __half2float(skiph[(size_t)nn * 64 + f]);
    __syncthreads();
    if (nn >= n) return;
    float acc = 0.0f;
#pragma unroll
    for (int k = 0; k < 32; ++k) acc += sH[r][k] * sW[k * 32 + f];
    out[(size_t)nn * HF + f] = __float2half(acc);
}

// ================= gather layer 2: A-based (4B recs) + fused epilogue =================

__global__ __launch_bounds__(256) void k_gather(
        const unsigned* __restrict__ recs4, const int* __restrict__ pstart,
        const int* __restrict__ pcnt, const float* __restrict__ dinv,
        const __half* __restrict__ A,
        const float* __restrict__ bias, const float* __restrict__ gamma,
        const float* __restrict__ beta, const float* __restrict__ mean,
        const float* __restrict__ var,
        float* __restrict__ Hout, __half* __restrict__ skiph, int uoff, int n) {
    int g = blockIdx.x * 64 + (threadIdx.x >> 2);
    int lane = threadIdx.x & 3;
    if (g >= n) return;

    float dig = dinv[g];
    float sl = dig * dig;
    uint4 srow = ((const uint4*)(A + ((size_t)g << 5)))[lane];
    float acc[8];
    {
        const __half2* h = (const __half2*)&srow;
#pragma unroll
        for (int k = 0; k < 4; ++k) {
            float2 f = __half22float2(h[k]);
            acc[2 * k] = sl * f.x; acc[2 * k + 1] = sl * f.y;
        }
    }

    const float qs = 1.0f / WQ14;
    int cn = pcnt[g];
    const unsigned* r = recs4 + pstart[g];
    int e = 0;
    for (; e + 4 <= cn; e += 4) {
        unsigned u0 = r[e], u1 = r[e + 1], u2 = r[e + 2], u3 = r[e + 3];
        uint4 row0 = ((const uint4*)(A + ((size_t)(u0 >> 14) << 5)))[lane];
        uint4 row1 = ((const uint4*)(A + ((size_t)(u1 >> 14) << 5)))[lane];
        uint4 row2 = ((const uint4*)(A + ((size_t)(u2 >> 14) << 5)))[lane];
        uint4 row3 = ((const uint4*)(A + ((size_t)(u3 >> 14) << 5)))[lane];
        float n0 = (float)(u0 & 16383u) * qs * dinv[u0 >> 14];
        float n1 = (float)(u1 & 16383u) * qs * dinv[u1 >> 14];
        float n2 = (float)(u2 & 16383u) * qs * dinv[u2 >> 14];
        float n3 = (float)(u3 & 16383u) * qs * dinv[u3 >> 14];
        const __half2* h0 = (const __half2*)&row0;
        const __half2* h1 = (const __half2*)&row1;
        const __half2* h2 = (const __half2*)&row2;
        const __half2* h3 = (const __half2*)&row3;
#pragma unroll
        for (int k = 0; k < 4; ++k) {
            float2 f0 = __half22float2(h0[k]);
            float2 f1 = __half22float2(h1[k]);
            float2 f2 = __half22float2(h2[k]);
            float2 f3 = __half22float2(h3[k]);
            acc[2 * k]     += n0 * f0.x + n1 * f1.x + n2 * f2.x + n3 * f3.x;
            acc[2 * k + 1] += n0 * f0.y + n1 * f1.y + n2 * f2.y + n3 * f3.y;
        }
    }
    for (; e < cn; ++e) {
        unsigned u0 = r[e];
        uint4 row0 = ((const uint4*)(A + ((size_t)(u0 >> 14) << 5)))[lane];
        float n0 = (float)(u0 & 16383u) * qs * dinv[u0 >> 14];
        const __half2* h0 = (const __half2*)&row0;
#pragma unroll
        for (int k = 0; k < 4; ++k) {
            float2 f0 = __half22float2(h0[k]);
            acc[2 * k]     += n0 * f0.x;
            acc[2 * k + 1] += n0 * f0.y;
        }
    }

    int fq = lane * 8;
    float o[8];
#pragma unroll
    for (int k = 0; k < 8; ++k) {
        float v = fmaxf(acc[k] + bias[fq + k], 0.0f);
        o[k] = (v - mean[fq + k]) * gamma[fq + k] * rsqrtf(var[fq + k] + BN_EPS) + beta[fq + k];
    }
    if (Hout) {
        float* dst = Hout + ((size_t)g << 5) + fq;
        *(float4*)dst = make_float4(o[0], o[1], o[2], o[3]);
        *(float4*)(dst + 4) = make_float4(o[4], o[5], o[6], o[7]);
    }

    union { __half h[8]; uint4 q; } hv;
#pragma unroll
    for (int k = 0; k < 8; ++k) hv.h[k] = __float2half(o[k]);
    *(uint4*)(skiph + (size_t)g * 64 + uoff + fq) = hv.q;
}

// ================= MFMA fused head: LSTM1 + LSTM2 + linear =================

__global__ __launch_bounds__(256) void k_headm(
        const __half* __restrict__ skiph, const float* __restrict__ x,
        const __half* __restrict__ wp1, const __half* __restrict__ wp2,
        const float* __restrict__ bsum1, const float* __restrict__ bsum2,
        const float* __restrict__ lw, const float* __restrict__ lb,
        float* __restrict__ out, int n) {
    __shared__ __align__(16) __half H1lds[4 * 16 * 40];
    int tid = threadIdx.x;
    int w = tid >> 6, l = tid & 63;
    int quad = l >> 4, c = l & 15;
    int node_base = blockIdx.x * 64 + w * 16;

    int arow = node_base + c; if (arow > n - 1) arow = n - 1;
    const half8* ap = (const half8*)(skiph + (size_t)arow * 64);
    half8 a0 = ap[quad];
    half8 a1 = ap[4 + quad];

    const half8* b1 = (const half8*)wp1;
    f32x4 d[6];
#pragma unroll
    for (int t = 0; t < 6; ++t) {
        f32x4 acc = {0.0f, 0.0f, 0.0f, 0.0f};
        acc = __builtin_amdgcn_mfma_f32_16x16x32_f16(a0, b1[(t * 2 + 0) * 64 + l], acc, 0, 0, 0);
        acc = __builtin_amdgcn_mfma_f32_16x16x32_f16(a1, b1[(t * 2 + 1) * 64 + l], acc, 0, 0, 0);
        d[t] = acc;
    }

    float bi0 = bsum1[c],      bi1 = bsum1[16 + c];
    float bg0 = bsum1[64 + c], bg1 = bsum1[80 + c];
    float bo0 = bsum1[96 + c], bo1 = bsum1[112 + c];
    float lwc0 = lw[c], lwc1 = lw[c + 16];

    float pa[4];
#pragma unroll
    for (int r = 0; r < 4; ++r) {
        float cc0 = fsig(d[0][r] + bi0) * ftanh(d[2][r] + bg0);
        float h0 = fsig(d[4][r] + bo0) * ftanh(cc0);
        float cc1 = fsig(d[1][r] + bi1) * ftanh(d[3][r] + bg1);
        float h1 = fsig(d[5][r] + bo1) * ftanh(cc1);
        pa[r] = fmaxf(h0, 0.0f) * lwc0 + fmaxf(h1, 0.0f) * lwc1;
        __half* hp = H1lds + (w * 16 + quad * 4 + r) * 40;
        hp[c] = __float2half(h0);
        hp[c + 16] = __float2half(h1);
    }
    __syncthreads();

    half8 a2 = *(const half8*)(H1lds + (w * 16 + c) * 40 + quad * 8);

    const half8* b2 = (const half8*)wp2;
    f32x4 e[6];
#pragma unroll
    for (int t = 0; t < 6; ++t) {
        f32x4 acc = {0.0f, 0.0f, 0.0f, 0.0f};
        e[t] = __builtin_amdgcn_mfma_f32_16x16x32_f16(a2, b2[t * 64 + l], acc, 0, 0, 0);
    }

    float ci0 = bsum2[c],      ci1 = bsum2[16 + c];
    float cg0 = bsum2[64 + c], cg1 = bsum2[80 + c];
    float co0 = bsum2[96 + c], co1 = bsum2[112 + c];
    float lw2c0 = lw[32 + c], lw2c1 = lw[48 + c];
#pragma unroll
    for (int r = 0; r < 4; ++r) {
        float cc0 = fsig(e[0][r] + ci0) * ftanh(e[2][r] + cg0);
        float h0 = fsig(e[4][r] + co0) * ftanh(cc0);
        float cc1 = fsig(e[1][r] + ci1) * ftanh(e[3][r] + cg1);
        float h1 = fsig(e[5][r] + co1) * ftanh(cc1);
        pa[r] += fmaxf(h0, 0.0f) * lw2c0 + fmaxf(h1, 0.0f) * lw2c1;
    }

#pragma unroll
    for (int m = 1; m < 16; m <<= 1) {
#pragma unroll
        for (int r = 0; r < 4; ++r) pa[r] += __shfl_xor(pa[r], m, 64);
    }

    if (c < 4) {
        int node = node_base + quad * 4 + c;
        if (node < n) {
            const float4 xv = *(const float4*)(x + (size_t)node * 4);
            out[node] = pa[c] + lb[0]
                + fmaxf(xv.x, 0.0f) * lw[64] + fmaxf(xv.y, 0.0f) * lw[65]
                + fmaxf(xv.z, 0.0f) * lw[66] + fmaxf(xv.w, 0.0f) * lw[67];
        }
    }
}

// ================= fallback (atomic scatter, fp32) =================

__global__ void k_initdeg(float* __restrict__ deg, int n) {
    int i = blockIdx.x * blockDim.x + threadIdx.x;
    if (i < n) deg[i] = 1.0f;
}

__global__ void k_deg_only(const int* __restrict__ dst, const float* __restrict__ ew,
                           float* __restrict__ deg, int E) {
    int e = blockIdx.x * blockDim.x + threadIdx.x;
    if (e < E) atomicAdd(&deg[dst[e]], ew[e]);
}

__global__ void k_dinv_f(float* __restrict__ deg, int n) {
    int i = blockIdx.x * blockDim.x + threadIdx.x;
    if (i < n) {
        float d = deg[i];
        deg[i] = d > 0.0f ? rsqrtf(d) : 0.0f;
    }
}

__global__ void k_xw1_f(const float* __restrict__ x, const float* __restrict__ W,
                        float* __restrict__ out, int n) {
    int idx = blockIdx.x * blockDim.x + threadIdx.x;
    if (idx >= n * HF) return;
    int nn = idx >> 5, f = idx & 31;
    const float4 xr = *(const float4*)(x + (size_t)nn * 4);
    out[idx] = xr.x * W[f] + xr.y * W[32 + f] + xr.z * W[64 + f] + xr.w * W[96 + f];
}

__global__ void k_xw2_f(const float* __restrict__ Hin, const float* __restrict__ W,
                        float* __restrict__ out, int n) {
    __shared__ float sW[32 * 32];
    __shared__ float sH[8][32];
    int tid = threadIdx.x;
    for (int i = tid; i < 1024; i += 256) sW[i] = W[i];
    int r = tid >> 5, f = tid & 31;
    int nn = blockIdx.x * 8 + r;
    if (nn < n) sH[r][f] = Hin[(size_t)nn * HF + f];
    __syncthreads();
    if (nn >= n) return;
    float acc = 0.0f;
#pragma unroll
    for (int k = 0; k < 32; ++k) acc += sH[r][k] * sW[k * 32 + f];
    out[(size_t)nn * HF + f] = acc;
}

__global__ void k_selfloop(const float* __restrict__ A, const float* __restrict__ dinv,
                           float* __restrict__ B, int n) {
    int idx = blockIdx.x * blockDim.x + threadIdx.x;
    if (idx >= n * HF) return;
    int nn = idx >> 5;
    float di = dinv[nn];
    B[idx] = di * di * A[idx];
}

__global__ void k_scatter(const int* __restrict__ src, const int* __restrict__ dst,
                          const float* __restrict__ ew, const float* __restrict__ dinv,
                          const float* __restrict__ A, float* __restrict__ B, int total) {
    int idx = blockIdx.x * blockDim.x + threadIdx.x;
    if (idx >= total) return;
    int e = idx >> 5, f = idx & 31;
    int s = src[e], d = dst[e];
    float norm = dinv[s] * ew[e] * dinv[d];
    atomicAdd(&B[d * HF + f], norm * A[s * HF + f]);
}

__global__ void k_post(const float* __restrict__ B, const float* __restrict__ bias,
                       const float* __restrict__ gamma, const float* __restrict__ beta,
                       const float* __restrict__ mean, const float* __restrict__ var,
                       float* __restrict__ Hout, int n) {
    int idx = blockIdx.x * blockDim.x + threadIdx.x;
    if (idx >= n * HF) return;
    int f = idx & 31;
    float v = fmaxf(B[idx] + bias[f], 0.0f);
    float sc = gamma[f] * rsqrtf(var[f] + BN_EPS);
    Hout[idx] = (v - mean[f]) * sc + beta[f];
}

__global__ __launch_bounds__(256) void k_head(
        const float* __restrict__ h1, const float* __restrict__ h2,
        const float* __restrict__ x,
        const float* __restrict__ wih1, const float* __restrict__ bih1, const float* __restrict__ bhh1,
        const float* __restrict__ wih2, const float* __restrict__ bih2, const float* __restrict__ bhh2,
        const float* __restrict__ lw, const float* __restrict__ lb,
        float* __restrict__ out, int n) {
    __shared__ float sH1[32 * 256];
    int tid = threadIdx.x;
    int nn = blockIdx.x * 256 + tid;
    if (nn >= n) return;

    const float4* a = (const float4*)(h1 + (size_t)nn * HF);
    const float4* b = (const float4*)(h2 + (size_t)nn * HF);
    float skip[64];
#pragma unroll
    for (int q = 0; q < 8; ++q) {
        float4 v = a[q];
        skip[4 * q] = v.x; skip[4 * q + 1] = v.y; skip[4 * q + 2] = v.z; skip[4 * q + 3] = v.w;
        float4 u = b[q];
        skip[32 + 4 * q] = u.x; skip[33 + 4 * q] = u.y; skip[34 + 4 * q] = u.z; skip[35 + 4 * q] = u.w;
    }

    float oa = lb[0];
#pragma unroll 1
    for (int j = 0; j < 32; ++j) {
        const float4* wi = (const float4*)(wih1 + (size_t)j * 64);
        const float4* wg = (const float4*)(wih1 + (size_t)(64 + j) * 64);
        const float4* wo = (const float4*)(wih1 + (size_t)(96 + j) * 64);
        float gi = bih1[j] + bhh1[j];
        float gg = bih1[64 + j] + bhh1[64 + j];
        float go = bih1[96 + j] + bhh1[96 + j];
#pragma unroll
        for (int q = 0; q < 16; ++q) {
            float4 aa = wi[q], bb = wg[q], cc4 = wo[q];
            float s0 = skip[4 * q], s1 = skip[4 * q + 1], s2 = skip[4 * q + 2], s3 = skip[4 * q + 3];
            gi += aa.x * s0 + aa.y * s1 + aa.z * s2 + aa.w * s3;
            gg += bb.x * s0 + bb.y * s1 + bb.z * s2 + bb.w * s3;
            go += cc4.x * s0 + cc4.y * s1 + cc4.z * s2 + cc4.w * s3;
        }
        float cc = fsig(gi) * ftanh(gg);
        float hh = fsig(go) * ftanh(cc);
        sH1[j * 256 + tid] = hh;
        oa += fmaxf(hh, 0.0f) * lw[j];
    }

#pragma unroll 1
    for (int j = 0; j < 32; ++j) {
        const float4* wi = (const float4*)(wih2 + (size_t)j * 32);
        const float4* wg = (const float4*)(wih2 + (size_t)(64 + j) * 32);
        const float4* wo = (const float4*)(wih2 + (size_t)(96 + j) * 32);
        float gi = bih2[j] + bhh2[j];
        float gg = bih2[64 + j] + bhh2[64 + j];
        float go = bih2[96 + j] + bhh2[96 + j];
#pragma unroll
        for (int q = 0; q < 8; ++q) {
            float4 aa = wi[q], bb = wg[q], cc4 = wo[q];
            float s0 = sH1[(4 * q) * 256 + tid], s1 = sH1[(4 * q + 1) * 256 + tid];
            float s2 = sH1[(4 * q + 2) * 256 + tid], s3 = sH1[(4 * q + 3) * 256 + tid];
            gi += aa.x * s0 + aa.y * s1 + aa.z * s2 + aa.w * s3;
            gg += bb.x * s0 + bb.y * s1 + bb.z * s2 + bb.w * s3;
            go += cc4.x * s0 + cc4.y * s1 + cc4.z * s2 + cc4.w * s3;
        }
        float cc = fsig(gi) * ftanh(gg);
        float hh = fsig(go) * ftanh(cc);
        oa += fmaxf(hh, 0.0f) * lw[32 + j];
    }

    const float4 xv = *(const float4*)(x + (size_t)nn * 4);
    oa += fmaxf(xv.x, 0.0f) * lw[64] + fmaxf(xv.y, 0.0f) * lw[65] +
          fmaxf(xv.z, 0.0f) * lw[66] + fmaxf(xv.w, 0.0f) * lw[67];
    out[nn] = oa;
}

// ================= launch =================

extern "C" void kernel_launch(void* const* d_in, const int* in_sizes, int n_in,
                              void* d_out, int out_size, void* d_ws, size_t ws_size,
                              hipStream_t stream) {
    const float* x   = (const float*)d_in[0];
    const int*   ei  = (const int*)d_in[1];
    const float* ew  = (const float*)d_in[2];
    const float* g1w = (const float*)d_in[3];
    const float* g1b = (const float*)d_in[4];
    const float* g2w = (const float*)d_in[5];
    const float* g2b = (const float*)d_in[6];
    const float* bn1g = (const float*)d_in[7];
    const float* bn1b = (const float*)d_in[8];
    const float* bn1m = (const float*)d_in[9];
    const float* bn1v = (const float*)d_in[10];
    const float* bn2g = (const float*)d_in[11];
    const float* bn2b = (const float*)d_in[12];
    const float* bn2m = (const float*)d_in[13];
    const float* bn2v = (const float*)d_in[14];
    const float* w1ih = (const float*)d_in[15];
    const float* b1ih = (const float*)d_in[17];
    const float* b1hh = (const float*)d_in[18];
    const float* w2ih = (const float*)d_in[19];
    const float* b2ih = (const float*)d_in[21];
    const float* b2hh = (const float*)d_in[22];
    const float* lw   = (const float*)d_in[23];
    const float* lb   = (const float*)d_in[24];
    float* out = (float*)d_out;

    const int N = in_sizes[0] / 4;
    const int E = in_sizes[2];
    const int* src = ei;
    const int* dst = ei + E;

    const int T = 256;
    const int NB = (N + BS - 1) / BS;
    long long meanb = ((long long)BS * E) / (N > 0 ? N : 1);
    int bcap = (int)(meanb + meanb / 4 + 128);

    // workspace layout (256B-aligned regions)
    char* p = (char*)d_ws;
    auto alloc = [&](size_t bytes) { char* q = p; p += (bytes + 255) & ~(size_t)255; return q; };
    int*      gcur   = (int*)alloc(sizeof(int) * NB);
    uint2*    recs   = (uint2*)alloc(sizeof(uint2) * (size_t)NB * bcap);
    float*    dinv   = (float*)alloc(sizeof(float) * N);
    int*      pstart = (int*)alloc(sizeof(int) * N);
    int*      pcnt   = (int*)alloc(sizeof(int) * N);
    __half*   A      = (__half*)alloc(sizeof(__half) * (size_t)N * HF);  // xw2 output
    __half*   skiph  = (__half*)alloc(sizeof(__half) * (size_t)N * 64); // h1|h2 f16
    __half*   wp1    = (__half*)alloc(sizeof(__half) * 6144);
    __half*   wp2    = (__half*)alloc(sizeof(__half) * 3072);
    float*    bsum1  = (float*)alloc(sizeof(float) * 128);
    float*    bsum2  = (float*)alloc(sizeof(float) * 128);
    size_t need = (size_t)(p - (char*)d_ws);

    int bN  = (N + T - 1) / T;
    int bE  = (E + T - 1) / T;
    int bNF = (N * HF + T - 1) / T;
    int bN8 = (N + 7) / 8;
    int bG  = (N + 63) / 64;
    int bHM = (N + 63) / 64;
    int bBin = (E + KEDGE - 1) / KEDGE;

    if (ws_size >= need && NB <= MAXNB && bcap <= BCAPS && N <= (1 << 18)) {
        // ---- build ----
        k_zero<<<(NB + T - 1) / T, T, 0, stream>>>(gcur, NB);
        k_binsort<<<bBin, T, 0, stream>>>(src, dst, ew, E, NB, bcap, gcur, recs);
        k_sortb<<<NB, 512, 0, stream>>>(recs, gcur, bcap, pstart, pcnt, dinv, N);
        k_pack<<<37, 256, 0, stream>>>(w1ih, b1ih, b1hh, w2ih, b2ih, b2hh,
                                       wp1, wp2, bsum1, bsum2);

        // ---- layer 1: fused xw1+gather -> skiph[0:32] ----
        k_gather_x1<<<bG, T, 0, stream>>>((const unsigned*)recs, pstart, pcnt, dinv,
                                          x, g1w, g1b, bn1g, bn1b, bn1m, bn1v,
                                          skiph, N);
        // ---- layer 2: xw2(h1 fp16) -> A; gather -> skiph[32:64] ----
        k_xw2_h<<<bN8, T, 0, stream>>>(skiph, g2w, A, N);
        k_gather<<<bG, T, 0, stream>>>((const unsigned*)recs, pstart, pcnt, dinv, A,
                                       g2b, bn2g, bn2b, bn2m, bn2v,
                                       (float*)nullptr, skiph, 32, N);
        // ---- MFMA head ----
        k_headm<<<bHM, T, 0, stream>>>(skiph, x, wp1, wp2, bsum1, bsum2,
                                       lw, lb, out, N);
    } else {
        // ---- fallback: atomic scatter, fp32 ----
        size_t Npad = ((size_t)N + 255) & ~(size_t)255;
        float* fdinv = (float*)d_ws;
        float* fA = fdinv + Npad;
        float* fB = fA + (size_t)N * HF;
        float* fC = fB + (size_t)N * HF;
        int bEF = (int)(((long long)E * HF + T - 1) / T);
        int bH = (N + 255) / 256;

        k_initdeg<<<bN, T, 0, stream>>>(fdinv, N);
        k_deg_only<<<bE, T, 0, stream>>>(dst, ew, fdinv, E);
        k_dinv_f<<<bN, T, 0, stream>>>(fdinv, N);

        k_xw1_f<<<bNF, T, 0, stream>>>(x, g1w, fA, N);
        k_selfloop<<<bNF, T, 0, stream>>>(fA, fdinv, fB, N);
        k_scatter<<<bEF, T, 0, stream>>>(src, dst, ew, fdinv, fA, fB, E * HF);
        k_post<<<bNF, T, 0, stream>>>(fB, g1b, bn1g, bn1b, bn1m, bn1v, fC, N);

        k_xw2_f<<<bN8, T, 0, stream>>>(fC, g2w, fA, N);
        k_selfloop<<<bNF, T, 0, stream>>>(fA, fdinv, fB, N);
        k_scatter<<<bEF, T, 0, stream>>>(src, dst, ew, fdinv, fA, fB, E * HF);
        k_post<<<bNF, T, 0, stream>>>(fB, g2b, bn2g, bn2b, bn2m, bn2v, fB, N);

        k_head<<<bH, T, 0, stream>>>(fC, fB, x, w1ih, b1ih, b1hh, w2ih, b2ih, b2hh,
                                     lw, lb, out, N);
    }
}

// Round 12
// 367.548 us; speedup vs baseline: 2.1341x; 1.0023x over previous
//
#include <hip/hip_runtime.h>
#include <hip/hip_fp16.h>
#include <math.h>

#define BN_EPS 1e-5f
#define HF 32          // hidden features
#define BS 256         // nodes per bucket (8-bit dloc)
#define KEDGE 4096     // edges per binsort block
#define MAXNB 800      // max buckets (NB=782 for N=200k)
#define WQ14 16383.0f  // 14-bit norm quantization
#define WQ22 4194303.0f // 22-bit raw-weight quantization (binsort staging)

typedef _Float16 half8 __attribute__((ext_vector_type(8)));
typedef float f32x4 __attribute__((ext_vector_type(4)));

// fast transcendentals (trans pipe)
__device__ __forceinline__ float fsig(float x) {
    return __builtin_amdgcn_rcpf(1.0f + __expf(-x));
}
__device__ __forceinline__ float ftanh(float x) {
    return 1.0f - 2.0f * __builtin_amdgcn_rcpf(1.0f + __expf(2.0f * x));
}

// ================= tiny utils =================

__global__ void k_zero(int* __restrict__ p, int n) {
    int i = blockIdx.x * blockDim.x + threadIdx.x;
    if (i < n) p[i] = 0;
}

// ================= Phase A: block-local counting sort into buckets =================
// LDS diet: bucket id packed into y (b<<22 | q22w) -> no sbk array. 512 threads.

__global__ __launch_bounds__(512) void k_binsort(
        const int* __restrict__ src, const int* __restrict__ dst,
        const float* __restrict__ ew, int E, int NB, int bcap,
        int* __restrict__ gcur, uint2* __restrict__ recs) {
    __shared__ uint2 srec[KEDGE];
    __shared__ int hist[MAXNB], excl[MAXNB], curs[MAXNB], sbase[MAXNB];

    int tid = threadIdx.x;
    int base = blockIdx.x * KEDGE;
    int cnt = min(KEDGE, E - base);

    for (int i = tid; i < NB; i += 512) hist[i] = 0;
    __syncthreads();

    for (int i = tid; i < cnt; i += 512)
        atomicAdd(&hist[dst[base + i] >> 8], 1);
    __syncthreads();

    if (tid < 64) {
        int run = 0;
        for (int c = 0; c < NB; c += 64) {
            int idx = c + tid;
            int v = (idx < NB) ? hist[idx] : 0;
            int incl = v;
#pragma unroll
            for (int o = 1; o < 64; o <<= 1) {
                int up = __shfl_up(incl, o, 64);
                if (tid >= o) incl += up;
            }
            if (idx < NB) { int e = run + incl - v; excl[idx] = e; curs[idx] = e; }
            run += __shfl(incl, 63, 64);
        }
    }
    __syncthreads();

    for (int i = tid; i < cnt; i += 512) {
        int s = src[base + i];
        int d = dst[base + i];
        float w = ew[base + i];
        unsigned q = (unsigned)(w * WQ22 + 0.5f);
        if (q > 4194303u) q = 4194303u;
        int b = d >> 8;
        int pos = atomicAdd(&curs[b], 1);
        srec[pos] = make_uint2(((unsigned)s << 8) | (unsigned)(d & 255),
                               ((unsigned)b << 22) | q);
    }
    __syncthreads();

    for (int b = tid; b < NB; b += 512) {
        int len = hist[b];
        sbase[b] = len ? atomicAdd(&gcur[b], len) : 0;
    }
    __syncthreads();

    for (int i = tid; i < cnt; i += 512) {
        uint2 u = srec[i];
        int b = u.y >> 22;
        int off = sbase[b] + (i - excl[b]);
        if (off < bcap) recs[(size_t)b * bcap + off] = u;
    }
}

// ================= Phase B: per-bucket 4B records + CSR + dinv (4 KB LDS) =================
// Two coalesced passes over the bucket run; 4B records go to a SEPARATE recs4
// buffer (no in-place hazard). LDS only histogram/scan/wsum -> high occupancy.

__global__ __launch_bounds__(512) void k_sortb(
        const uint2* __restrict__ recs, const int* __restrict__ gcur, int bcap,
        unsigned* __restrict__ recs4, int* __restrict__ pstart,
        int* __restrict__ pcnt, float* __restrict__ dinv, int n) {
    __shared__ int hist[BS], excl[BS], curs[BS];
    __shared__ float wsum[BS];

    int b = blockIdx.x, tid = threadIdx.x;
    int cnt = min(gcur[b], bcap);
    const uint2* r = recs + (size_t)b * bcap;
    const float dq = 1.0f / WQ22;

    if (tid < BS) { hist[tid] = 0; wsum[tid] = 1.0f; }  // self-loop weight
    __syncthreads();

    // pass 1: histogram + weighted degree (coalesced read)
    for (int i = tid; i < cnt; i += 512) {
        uint2 u = r[i];
        int dl = u.x & 255;
        atomicAdd(&hist[dl], 1);
        atomicAdd(&wsum[dl], (float)(u.y & 4194303u) * dq);
    }
    __syncthreads();

    if (tid < BS) wsum[tid] = rsqrtf(wsum[tid]);  // -> dinv_d
    if (tid >= 64 && tid < 128) {
        // second wave idles; wave 0 does the scan below
    }
    if (tid < 64) {
        int run = 0;
        for (int c = 0; c < BS; c += 64) {
            int idx = c + tid;
            int v = hist[idx];
            int incl = v;
#pragma unroll
            for (int o = 1; o < 64; o <<= 1) {
                int up = __shfl_up(incl, o, 64);
                if (tid >= o) incl += up;
            }
            int e = run + incl - v;
            excl[idx] = e; curs[idx] = e;
            run += __shfl(incl, 63, 64);
        }
    }
    __syncthreads();

    // pass 2: re-read (L2-hot), emit 4B records into bucket window of recs4
    unsigned* out4 = recs4 + (size_t)b * bcap;
    for (int i = tid; i < cnt; i += 512) {
        uint2 u = r[i];
        int dl = u.x & 255;
        int pos = atomicAdd(&curs[dl], 1);
        float qn = (float)(u.y & 4194303u) * dq * wsum[dl];  // w * dinv_d
        unsigned q = (unsigned)(qn * WQ14 + 0.5f);
        if (q > 16383u) q = 16383u;
        out4[pos] = ((u.x >> 8) << 14) | q;
    }

    if (tid < BS) {
        int g = b * BS + tid;
        if (g < n) {
            pstart[g] = b * bcap + excl[tid];   // index into recs4
            pcnt[g] = hist[tid];
            dinv[g] = wsum[tid];
        }
    }
}

// ================= weight pack for MFMA head (runs once) =================

__global__ void k_pack(const float* __restrict__ wih1, const float* __restrict__ bih1,
                       const float* __restrict__ bhh1, const float* __restrict__ wih2,
                       const float* __restrict__ bih2, const float* __restrict__ bhh2,
                       __half* __restrict__ wp1, __half* __restrict__ wp2,
                       float* __restrict__ bsum1, float* __restrict__ bsum2) {
    const int tg[6] = {0, 16, 64, 80, 96, 112};
    int idx = blockIdx.x * blockDim.x + threadIdx.x;
    if (idx < 6144) {
        int t = idx >> 10, rem = idx & 1023;
        int kc = rem >> 9, rem2 = rem & 511;
        int lane = rem2 >> 3, j = rem2 & 7;
        int g = tg[t] + (lane & 15);
        int k = kc * 32 + (lane >> 4) * 8 + j;
        wp1[idx] = __float2half(wih1[g * 64 + k]);
    } else if (idx < 9216) {
        int i2 = idx - 6144;
        int t = i2 >> 9, rem2 = i2 & 511;
        int lane = rem2 >> 3, j = rem2 & 7;
        int g = tg[t] + (lane & 15);
        int k = (lane >> 4) * 8 + j;
        wp2[i2] = __float2half(wih2[g * 32 + k]);
    } else if (idx < 9344) {
        int i = idx - 9216;
        bsum1[i] = bih1[i] + bhh1[i];
    } else if (idx < 9472) {
        int i = idx - 9344;
        bsum2[i] = bih2[i] + bhh2[i];
    }
}

// ================= gather layer 1: xw1 FUSED (x is L2-resident) =================

__global__ __launch_bounds__(256) void k_gather_x1(
        const unsigned* __restrict__ recs4, const int* __restrict__ pstart,
        const int* __restrict__ pcnt, const float* __restrict__ dinv,
        const float* __restrict__ x, const float* __restrict__ W1,
        const float* __restrict__ bias, const float* __restrict__ gamma,
        const float* __restrict__ beta, const float* __restrict__ mean,
        const float* __restrict__ var,
        __half* __restrict__ skiph, int n) {
    __shared__ float sW[128];
    int tid = threadIdx.x;
    if (tid < 128) sW[tid] = W1[tid];
    __syncthreads();

    int g = blockIdx.x * 64 + (tid >> 2);
    int lane = tid & 3;
    if (g >= n) return;
    int fq = lane * 8;

    float w[4][8];
#pragma unroll
    for (int r = 0; r < 4; ++r)
#pragma unroll
        for (int k = 0; k < 8; ++k) w[r][k] = sW[r * 32 + fq + k];

    float dig = dinv[g];
    float sl = dig * dig;
    float4 xg = *(const float4*)(x + (size_t)g * 4);
    float acc[8];
#pragma unroll
    for (int k = 0; k < 8; ++k)
        acc[k] = sl * (xg.x * w[0][k] + xg.y * w[1][k] + xg.z * w[2][k] + xg.w * w[3][k]);

    const float qs = 1.0f / WQ14;
    int cn = pcnt[g];
    const unsigned* r = recs4 + pstart[g];
    int e = 0;
    for (; e + 4 <= cn; e += 4) {
        unsigned u0 = r[e], u1 = r[e + 1], u2 = r[e + 2], u3 = r[e + 3];
        float4 x0 = *(const float4*)(x + (size_t)(u0 >> 14) * 4);
        float4 x1 = *(const float4*)(x + (size_t)(u1 >> 14) * 4);
        float4 x2 = *(const float4*)(x + (size_t)(u2 >> 14) * 4);
        float4 x3 = *(const float4*)(x + (size_t)(u3 >> 14) * 4);
        float n0 = (float)(u0 & 16383u) * qs * dinv[u0 >> 14];
        float n1 = (float)(u1 & 16383u) * qs * dinv[u1 >> 14];
        float n2 = (float)(u2 & 16383u) * qs * dinv[u2 >> 14];
        float n3 = (float)(u3 & 16383u) * qs * dinv[u3 >> 14];
#pragma unroll
        for (int k = 0; k < 8; ++k) {
            acc[k] += n0 * (x0.x * w[0][k] + x0.y * w[1][k] + x0.z * w[2][k] + x0.w * w[3][k]);
            acc[k] += n1 * (x1.x * w[0][k] + x1.y * w[1][k] + x1.z * w[2][k] + x1.w * w[3][k]);
            acc[k] += n2 * (x2.x * w[0][k] + x2.y * w[1][k] + x2.z * w[2][k] + x2.w * w[3][k]);
            acc[k] += n3 * (x3.x * w[0][k] + x3.y * w[1][k] + x3.z * w[2][k] + x3.w * w[3][k]);
        }
    }
    for (; e < cn; ++e) {
        unsigned u0 = r[e];
        float4 x0 = *(const float4*)(x + (size_t)(u0 >> 14) * 4);
        float n0 = (float)(u0 & 16383u) * qs * dinv[u0 >> 14];
#pragma unroll
        for (int k = 0; k < 8; ++k)
            acc[k] += n0 * (x0.x * w[0][k] + x0.y * w[1][k] + x0.z * w[2][k] + x0.w * w[3][k]);
    }

    union { __half h[8]; uint4 q; } hv;
#pragma unroll
    for (int k = 0; k < 8; ++k) {
        float v = fmaxf(acc[k] + bias[fq + k], 0.0f);
        hv.h[k] = __float2half((v - mean[fq + k]) * gamma[fq + k] * rsqrtf(var[fq + k] + BN_EPS) + beta[fq + k]);
    }
    *(uint4*)(skiph + (size_t)g * 64 + fq) = hv.q;
}

// ================= xw2: h1(fp16, from skiph) @ W2 -> A fp16 =================

__global__ void k_xw2_h(const __half* __restrict__ skiph, const float* __restrict__ W,
                        __half* __restrict__ out, int n) {
    __shared__ float sW[32 * 32];
    __shared__ float sH[8][32];
    int tid = threadIdx.x;
    for (int i = tid; i < 1024; i += 256) sW[i] = W[i];
    int r = tid >> 5, f = tid & 31;
    int nn = blockIdx.x * 8 + r;
    if (nn < n) sH[r][f] = __half2float(skiph[(size_t)nn * 64 + f]);
    __syncthreads();
    if (nn >= n) return;
    float acc = 0.0f;
#pragma unroll
    for (int k = 0; k < 32; ++k) acc += sH[r][k] * sW[k * 32 + f];
    out[(size_t)nn * HF + f] = __float2half(acc);
}

// ================= gather layer 2: A-based + fused epilogue =================

__global__ __launch_bounds__(256) void k_gather(
        const unsigned* __restrict__ recs4, const int* __restrict__ pstart,
        const int* __restrict__ pcnt, const float* __restrict__ dinv,
        const __half* __restrict__ A,
        const float* __restrict__ bias, const float* __restrict__ gamma,
        const float* __restrict__ beta, const float* __restrict__ mean,
        const float* __restrict__ var,
        __half* __restrict__ skiph, int uoff, int n) {
    int g = blockIdx.x * 64 + (threadIdx.x >> 2);
    int lane = threadIdx.x & 3;
    if (g >= n) return;

    float dig = dinv[g];
    float sl = dig * dig;
    uint4 srow = ((const uint4*)(A + ((size_t)g << 5)))[lane];
    float acc[8];
    {
        const __half2* h = (const __half2*)&srow;
#pragma unroll
        for (int k = 0; k < 4; ++k) {
            float2 f = __half22float2(h[k]);
            acc[2 * k] = sl * f.x; acc[2 * k + 1] = sl * f.y;
        }
    }

    const float qs = 1.0f / WQ14;
    int cn = pcnt[g];
    const unsigned* r = recs4 + pstart[g];
    int e = 0;
    for (; e + 4 <= cn; e += 4) {
        unsigned u0 = r[e], u1 = r[e + 1], u2 = r[e + 2], u3 = r[e + 3];
        uint4 row0 = ((const uint4*)(A + ((size_t)(u0 >> 14) << 5)))[lane];
        uint4 row1 = ((const uint4*)(A + ((size_t)(u1 >> 14) << 5)))[lane];
        uint4 row2 = ((const uint4*)(A + ((size_t)(u2 >> 14) << 5)))[lane];
        uint4 row3 = ((const uint4*)(A + ((size_t)(u3 >> 14) << 5)))[lane];
        float n0 = (float)(u0 & 16383u) * qs * dinv[u0 >> 14];
        float n1 = (float)(u1 & 16383u) * qs * dinv[u1 >> 14];
        float n2 = (float)(u2 & 16383u) * qs * dinv[u2 >> 14];
        float n3 = (float)(u3 & 16383u) * qs * dinv[u3 >> 14];
        const __half2* h0 = (const __half2*)&row0;
        const __half2* h1 = (const __half2*)&row1;
        const __half2* h2 = (const __half2*)&row2;
        const __half2* h3 = (const __half2*)&row3;
#pragma unroll
        for (int k = 0; k < 4; ++k) {
            float2 f0 = __half22float2(h0[k]);
            float2 f1 = __half22float2(h1[k]);
            float2 f2 = __half22float2(h2[k]);
            float2 f3 = __half22float2(h3[k]);
            acc[2 * k]     += n0 * f0.x + n1 * f1.x + n2 * f2.x + n3 * f3.x;
            acc[2 * k + 1] += n0 * f0.y + n1 * f1.y + n2 * f2.y + n3 * f3.y;
        }
    }
    for (; e < cn; ++e) {
        unsigned u0 = r[e];
        uint4 row0 = ((const uint4*)(A + ((size_t)(u0 >> 14) << 5)))[lane];
        float n0 = (float)(u0 & 16383u) * qs * dinv[u0 >> 14];
        const __half2* h0 = (const __half2*)&row0;
#pragma unroll
        for (int k = 0; k < 4; ++k) {
            float2 f0 = __half22float2(h0[k]);
            acc[2 * k]     += n0 * f0.x;
            acc[2 * k + 1] += n0 * f0.y;
        }
    }

    int fq = lane * 8;
    union { __half h[8]; uint4 q; } hv;
#pragma unroll
    for (int k = 0; k < 8; ++k) {
        float v = fmaxf(acc[k] + bias[fq + k], 0.0f);
        hv.h[k] = __float2half((v - mean[fq + k]) * gamma[fq + k] * rsqrtf(var[fq + k] + BN_EPS) + beta[fq + k]);
    }
    *(uint4*)(skiph + (size_t)g * 64 + uoff + fq) = hv.q;
}

// ================= MFMA fused head: LSTM1 + LSTM2 + linear =================

__global__ __launch_bounds__(256) void k_headm(
        const __half* __restrict__ skiph, const float* __restrict__ x,
        const __half* __restrict__ wp1, const __half* __restrict__ wp2,
        const float* __restrict__ bsum1, const float* __restrict__ bsum2,
        const float* __restrict__ lw, const float* __restrict__ lb,
        float* __restrict__ out, int n) {
    __shared__ __align__(16) __half H1lds[4 * 16 * 40];
    int tid = threadIdx.x;
    int w = tid >> 6, l = tid & 63;
    int quad = l >> 4, c = l & 15;
    int node_base = blockIdx.x * 64 + w * 16;

    int arow = node_base + c; if (arow > n - 1) arow = n - 1;
    const half8* ap = (const half8*)(skiph + (size_t)arow * 64);
    half8 a0 = ap[quad];
    half8 a1 = ap[4 + quad];

    const half8* b1 = (const half8*)wp1;
    f32x4 d[6];
#pragma unroll
    for (int t = 0; t < 6; ++t) {
        f32x4 acc = {0.0f, 0.0f, 0.0f, 0.0f};
        acc = __builtin_amdgcn_mfma_f32_16x16x32_f16(a0, b1[(t * 2 + 0) * 64 + l], acc, 0, 0, 0);
        acc = __builtin_amdgcn_mfma_f32_16x16x32_f16(a1, b1[(t * 2 + 1) * 64 + l], acc, 0, 0, 0);
        d[t] = acc;
    }

    float bi0 = bsum1[c],      bi1 = bsum1[16 + c];
    float bg0 = bsum1[64 + c], bg1 = bsum1[80 + c];
    float bo0 = bsum1[96 + c], bo1 = bsum1[112 + c];
    float lwc0 = lw[c], lwc1 = lw[c + 16];

    float pa[4];
#pragma unroll
    for (int r = 0; r < 4; ++r) {
        float cc0 = fsig(d[0][r] + bi0) * ftanh(d[2][r] + bg0);
        float h0 = fsig(d[4][r] + bo0) * ftanh(cc0);
        float cc1 = fsig(d[1][r] + bi1) * ftanh(d[3][r] + bg1);
        float h1 = fsig(d[5][r] + bo1) * ftanh(cc1);
        pa[r] = fmaxf(h0, 0.0f) * lwc0 + fmaxf(h1, 0.0f) * lwc1;
        __half* hp = H1lds + (w * 16 + quad * 4 + r) * 40;
        hp[c] = __float2half(h0);
        hp[c + 16] = __float2half(h1);
    }
    __syncthreads();

    half8 a2 = *(const half8*)(H1lds + (w * 16 + c) * 40 + quad * 8);

    const half8* b2 = (const half8*)wp2;
    f32x4 e[6];
#pragma unroll
    for (int t = 0; t < 6; ++t) {
        f32x4 acc = {0.0f, 0.0f, 0.0f, 0.0f};
        e[t] = __builtin_amdgcn_mfma_f32_16x16x32_f16(a2, b2[t * 64 + l], acc, 0, 0, 0);
    }

    float ci0 = bsum2[c],      ci1 = bsum2[16 + c];
    float cg0 = bsum2[64 + c], cg1 = bsum2[80 + c];
    float co0 = bsum2[96 + c], co1 = bsum2[112 + c];
    float lw2c0 = lw[32 + c], lw2c1 = lw[48 + c];
#pragma unroll
    for (int r = 0; r < 4; ++r) {
        float cc0 = fsig(e[0][r] + ci0) * ftanh(e[2][r] + cg0);
        float h0 = fsig(e[4][r] + co0) * ftanh(cc0);
        float cc1 = fsig(e[1][r] + ci1) * ftanh(e[3][r] + cg1);
        float h1 = fsig(e[5][r] + co1) * ftanh(cc1);
        pa[r] += fmaxf(h0, 0.0f) * lw2c0 + fmaxf(h1, 0.0f) * lw2c1;
    }

#pragma unroll
    for (int m = 1; m < 16; m <<= 1) {
#pragma unroll
        for (int r = 0; r < 4; ++r) pa[r] += __shfl_xor(pa[r], m, 64);
    }

    if (c < 4) {
        int node = node_base + quad * 4 + c;
        if (node < n) {
            const float4 xv = *(const float4*)(x + (size_t)node * 4);
            out[node] = pa[c] + lb[0]
                + fmaxf(xv.x, 0.0f) * lw[64] + fmaxf(xv.y, 0.0f) * lw[65]
                + fmaxf(xv.z, 0.0f) * lw[66] + fmaxf(xv.w, 0.0f) * lw[67];
        }
    }
}

// ================= fallback (atomic scatter, fp32) =================

__global__ void k_initdeg(float* __restrict__ deg, int n) {
    int i = blockIdx.x * blockDim.x + threadIdx.x;
    if (i < n) deg[i] = 1.0f;
}

__global__ void k_deg_only(const int* __restrict__ dst, const float* __restrict__ ew,
                           float* __restrict__ deg, int E) {
    int e = blockIdx.x * blockDim.x + threadIdx.x;
    if (e < E) atomicAdd(&deg[dst[e]], ew[e]);
}

__global__ void k_dinv_f(float* __restrict__ deg, int n) {
    int i = blockIdx.x * blockDim.x + threadIdx.x;
    if (i < n) {
        float d = deg[i];
        deg[i] = d > 0.0f ? rsqrtf(d) : 0.0f;
    }
}

__global__ void k_xw1_f(const float* __restrict__ x, const float* __restrict__ W,
                        float* __restrict__ out, int n) {
    int idx = blockIdx.x * blockDim.x + threadIdx.x;
    if (idx >= n * HF) return;
    int nn = idx >> 5, f = idx & 31;
    const float4 xr = *(const float4*)(x + (size_t)nn * 4);
    out[idx] = xr.x * W[f] + xr.y * W[32 + f] + xr.z * W[64 + f] + xr.w * W[96 + f];
}

__global__ void k_xw2_f(const float* __restrict__ Hin, const float* __restrict__ W,
                        float* __restrict__ out, int n) {
    __shared__ float sW[32 * 32];
    __shared__ float sH[8][32];
    int tid = threadIdx.x;
    for (int i = tid; i < 1024; i += 256) sW[i] = W[i];
    int r = tid >> 5, f = tid & 31;
    int nn = blockIdx.x * 8 + r;
    if (nn < n) sH[r][f] = Hin[(size_t)nn * HF + f];
    __syncthreads();
    if (nn >= n) return;
    float acc = 0.0f;
#pragma unroll
    for (int k = 0; k < 32; ++k) acc += sH[r][k] * sW[k * 32 + f];
    out[(size_t)nn * HF + f] = acc;
}

__global__ void k_selfloop(const float* __restrict__ A, const float* __restrict__ dinv,
                           float* __restrict__ B, int n) {
    int idx = blockIdx.x * blockDim.x + threadIdx.x;
    if (idx >= n * HF) return;
    int nn = idx >> 5;
    float di = dinv[nn];
    B[idx] = di * di * A[idx];
}

__global__ void k_scatter(const int* __restrict__ src, const int* __restrict__ dst,
                          const float* __restrict__ ew, const float* __restrict__ dinv,
                          const float* __restrict__ A, float* __restrict__ B, int total) {
    int idx = blockIdx.x * blockDim.x + threadIdx.x;
    if (idx >= total) return;
    int e = idx >> 5, f = idx & 31;
    int s = src[e], d = dst[e];
    float norm = dinv[s] * ew[e] * dinv[d];
    atomicAdd(&B[d * HF + f], norm * A[s * HF + f]);
}

__global__ void k_post(const float* __restrict__ B, const float* __restrict__ bias,
                       const float* __restrict__ gamma, const float* __restrict__ beta,
                       const float* __restrict__ mean, const float* __restrict__ var,
                       float* __restrict__ Hout, int n) {
    int idx = blockIdx.x * blockDim.x + threadIdx.x;
    if (idx >= n * HF) return;
    int f = idx & 31;
    float v = fmaxf(B[idx] + bias[f], 0.0f);
    float sc = gamma[f] * rsqrtf(var[f] + BN_EPS);
    Hout[idx] = (v - mean[f]) * sc + beta[f];
}

__global__ __launch_bounds__(256) void k_head(
        const float* __restrict__ h1, const float* __restrict__ h2,
        const float* __restrict__ x,
        const float* __restrict__ wih1, const float* __restrict__ bih1, const float* __restrict__ bhh1,
        const float* __restrict__ wih2, const float* __restrict__ bih2, const float* __restrict__ bhh2,
        const float* __restrict__ lw, const float* __restrict__ lb,
        float* __restrict__ out, int n) {
    __shared__ float sH1[32 * 256];
    int tid = threadIdx.x;
    int nn = blockIdx.x * 256 + tid;
    if (nn >= n) return;

    const float4* a = (const float4*)(h1 + (size_t)nn * HF);
    const float4* b = (const float4*)(h2 + (size_t)nn * HF);
    float skip[64];
#pragma unroll
    for (int q = 0; q < 8; ++q) {
        float4 v = a[q];
        skip[4 * q] = v.x; skip[4 * q + 1] = v.y; skip[4 * q + 2] = v.z; skip[4 * q + 3] = v.w;
        float4 u = b[q];
        skip[32 + 4 * q] = u.x; skip[33 + 4 * q] = u.y; skip[34 + 4 * q] = u.z; skip[35 + 4 * q] = u.w;
    }

    float oa = lb[0];
#pragma unroll 1
    for (int j = 0; j < 32; ++j) {
        const float4* wi = (const float4*)(wih1 + (size_t)j * 64);
        const float4* wg = (const float4*)(wih1 + (size_t)(64 + j) * 64);
        const float4* wo = (const float4*)(wih1 + (size_t)(96 + j) * 64);
        float gi = bih1[j] + bhh1[j];
        float gg = bih1[64 + j] + bhh1[64 + j];
        float go = bih1[96 + j] + bhh1[96 + j];
#pragma unroll
        for (int q = 0; q < 16; ++q) {
            float4 aa = wi[q], bb = wg[q], cc4 = wo[q];
            float s0 = skip[4 * q], s1 = skip[4 * q + 1], s2 = skip[4 * q + 2], s3 = skip[4 * q + 3];
            gi += aa.x * s0 + aa.y * s1 + aa.z * s2 + aa.w * s3;
            gg += bb.x * s0 + bb.y * s1 + bb.z * s2 + bb.w * s3;
            go += cc4.x * s0 + cc4.y * s1 + cc4.z * s2 + cc4.w * s3;
        }
        float cc = fsig(gi) * ftanh(gg);
        float hh = fsig(go) * ftanh(cc);
        sH1[j * 256 + tid] = hh;
        oa += fmaxf(hh, 0.0f) * lw[j];
    }

#pragma unroll 1
    for (int j = 0; j < 32; ++j) {
        const float4* wi = (const float4*)(wih2 + (size_t)j * 32);
        const float4* wg = (const float4*)(wih2 + (size_t)(64 + j) * 32);
        const float4* wo = (const float4*)(wih2 + (size_t)(96 + j) * 32);
        float gi = bih2[j] + bhh2[j];
        float gg = bih2[64 + j] + bhh2[64 + j];
        float go = bih2[96 + j] + bhh2[96 + j];
#pragma unroll
        for (int q = 0; q < 8; ++q) {
            float4 aa = wi[q], bb = wg[q], cc4 = wo[q];
            float s0 = sH1[(4 * q) * 256 + tid], s1 = sH1[(4 * q + 1) * 256 + tid];
            float s2 = sH1[(4 * q + 2) * 256 + tid], s3 = sH1[(4 * q + 3) * 256 + tid];
            gi += aa.x * s0 + aa.y * s1 + aa.z * s2 + aa.w * s3;
            gg += bb.x * s0 + bb.y * s1 + bb.z * s2 + bb.w * s3;
            go += cc4.x * s0 + cc4.y * s1 + cc4.z * s2 + cc4.w * s3;
        }
        float cc = fsig(gi) * ftanh(gg);
        float hh = fsig(go) * ftanh(cc);
        oa += fmaxf(hh, 0.0f) * lw[32 + j];
    }

    const float4 xv = *(const float4*)(x + (size_t)nn * 4);
    oa += fmaxf(xv.x, 0.0f) * lw[64] + fmaxf(xv.y, 0.0f) * lw[65] +
          fmaxf(xv.z, 0.0f) * lw[66] + fmaxf(xv.w, 0.0f) * lw[67];
    out[nn] = oa;
}

// ================= launch =================

extern "C" void kernel_launch(void* const* d_in, const int* in_sizes, int n_in,
                              void* d_out, int out_size, void* d_ws, size_t ws_size,
                              hipStream_t stream) {
    const float* x   = (const float*)d_in[0];
    const int*   ei  = (const int*)d_in[1];
    const float* ew  = (const float*)d_in[2];
    const float* g1w = (const float*)d_in[3];
    const float* g1b = (const float*)d_in[4];
    const float* g2w = (const float*)d_in[5];
    const float* g2b = (const float*)d_in[6];
    const float* bn1g = (const float*)d_in[7];
    const float* bn1b = (const float*)d_in[8];
    const float* bn1m = (const float*)d_in[9];
    const float* bn1v = (const float*)d_in[10];
    const float* bn2g = (const float*)d_in[11];
    const float* bn2b = (const float*)d_in[12];
    const float* bn2m = (const float*)d_in[13];
    const float* bn2v = (const float*)d_in[14];
    const float* w1ih = (const float*)d_in[15];
    const float* b1ih = (const float*)d_in[17];
    const float* b1hh = (const float*)d_in[18];
    const float* w2ih = (const float*)d_in[19];
    const float* b2ih = (const float*)d_in[21];
    const float* b2hh = (const float*)d_in[22];
    const float* lw   = (const float*)d_in[23];
    const float* lb   = (const float*)d_in[24];
    float* out = (float*)d_out;

    const int N = in_sizes[0] / 4;
    const int E = in_sizes[2];
    const int* src = ei;
    const int* dst = ei + E;

    const int T = 256;
    const int NB = (N + BS - 1) / BS;
    long long meanb = ((long long)BS * E) / (N > 0 ? N : 1);
    int bcap = (int)(meanb + meanb / 4 + 128);

    // workspace layout (256B-aligned regions)
    char* p = (char*)d_ws;
    auto alloc = [&](size_t bytes) { char* q = p; p += (bytes + 255) & ~(size_t)255; return q; };
    int*      gcur   = (int*)alloc(sizeof(int) * NB);
    uint2*    recs   = (uint2*)alloc(sizeof(uint2) * (size_t)NB * bcap);
    unsigned* recs4  = (unsigned*)alloc(sizeof(unsigned) * (size_t)NB * bcap);
    float*    dinv   = (float*)alloc(sizeof(float) * N);
    int*      pstart = (int*)alloc(sizeof(int) * N);
    int*      pcnt   = (int*)alloc(sizeof(int) * N);
    __half*   A      = (__half*)alloc(sizeof(__half) * (size_t)N * HF);  // xw2 output
    __half*   skiph  = (__half*)alloc(sizeof(__half) * (size_t)N * 64); // h1|h2 f16
    __half*   wp1    = (__half*)alloc(sizeof(__half) * 6144);
    __half*   wp2    = (__half*)alloc(sizeof(__half) * 3072);
    float*    bsum1  = (float*)alloc(sizeof(float) * 128);
    float*    bsum2  = (float*)alloc(sizeof(float) * 128);
    size_t need = (size_t)(p - (char*)d_ws);

    int bN  = (N + T - 1) / T;
    int bE  = (E + T - 1) / T;
    int bNF = (N * HF + T - 1) / T;
    int bN8 = (N + 7) / 8;
    int bG  = (N + 63) / 64;
    int bHM = (N + 63) / 64;
    int bBin = (E + KEDGE - 1) / KEDGE;

    if (ws_size >= need && NB <= MAXNB && N <= (1 << 18)) {
        // ---- build ----
        k_zero<<<(NB + T - 1) / T, T, 0, stream>>>(gcur, NB);
        k_binsort<<<bBin, 512, 0, stream>>>(src, dst, ew, E, NB, bcap, gcur, recs);
        k_sortb<<<NB, 512, 0, stream>>>(recs, gcur, bcap, recs4, pstart, pcnt, dinv, N);
        k_pack<<<37, 256, 0, stream>>>(w1ih, b1ih, b1hh, w2ih, b2ih, b2hh,
                                       wp1, wp2, bsum1, bsum2);

        // ---- layer 1: fused xw1+gather -> skiph[0:32] ----
        k_gather_x1<<<bG, T, 0, stream>>>(recs4, pstart, pcnt, dinv,
                                          x, g1w, g1b, bn1g, bn1b, bn1m, bn1v,
                                          skiph, N);
        // ---- layer 2: xw2(h1 fp16) -> A; gather -> skiph[32:64] ----
        k_xw2_h<<<bN8, T, 0, stream>>>(skiph, g2w, A, N);
        k_gather<<<bG, T, 0, stream>>>(recs4, pstart, pcnt, dinv, A,
                                       g2b, bn2g, bn2b, bn2m, bn2v,
                                       skiph, 32, N);
        // ---- MFMA head ----
        k_headm<<<bHM, T, 0, stream>>>(skiph, x, wp1, wp2, bsum1, bsum2,
                                       lw, lb, out, N);
    } else {
        // ---- fallback: atomic scatter, fp32 ----
        size_t Npad = ((size_t)N + 255) & ~(size_t)255;
        float* fdinv = (float*)d_ws;
        float* fA = fdinv + Npad;
        float* fB = fA + (size_t)N * HF;
        float* fC = fB + (size_t)N * HF;
        int bEF = (int)(((long long)E * HF + T - 1) / T);
        int bH = (N + 255) / 256;

        k_initdeg<<<bN, T, 0, stream>>>(fdinv, N);
        k_deg_only<<<bE, T, 0, stream>>>(dst, ew, fdinv, E);
        k_dinv_f<<<bN, T, 0, stream>>>(fdinv, N);

        k_xw1_f<<<bNF, T, 0, stream>>>(x, g1w, fA, N);
        k_selfloop<<<bNF, T, 0, stream>>>(fA, fdinv, fB, N);
        k_scatter<<<bEF, T, 0, stream>>>(src, dst, ew, fdinv, fA, fB, E * HF);
        k_post<<<bNF, T, 0, stream>>>(fB, g1b, bn1g, bn1b, bn1m, bn1v, fC, N);

        k_xw2_f<<<bN8, T, 0, stream>>>(fC, g2w, fA, N);
        k_selfloop<<<bNF, T, 0, stream>>>(fA, fdinv, fB, N);
        k_scatter<<<bEF, T, 0, stream>>>(src, dst, ew, fdinv, fA, fB, E * HF);
        k_post<<<bNF, T, 0, stream>>>(fB, g2b, bn2g, bn2b, bn2m, bn2v, fB, N);

        k_head<<<bH, T, 0, stream>>>(fC, fB, x, w1ih, b1ih, b1hh, w2ih, b2ih, b2hh,
                                     lw, lb, out, N);
    }
}

// Round 13
// 336.389 us; speedup vs baseline: 2.3318x; 1.0926x over previous
//
#include <hip/hip_runtime.h>
#include <hip/hip_fp16.h>
#include <math.h>

#define BN_EPS 1e-5f
#define HF 32          // hidden features
#define BS 256         // nodes per bucket (8-bit dloc)
#define KEDGE 4096     // edges per binsort block
#define MAXNB 800      // max buckets (NB=782 for N=200k)
#define WQ14 16383.0f  // 14-bit norm quantization
#define WQ22 4194303.0f // 22-bit raw-weight quantization (binsort staging)

typedef _Float16 half8 __attribute__((ext_vector_type(8)));
typedef float f32x4 __attribute__((ext_vector_type(4)));
typedef float f32x2 __attribute__((ext_vector_type(2)));

// fast transcendentals (trans pipe)
__device__ __forceinline__ float fsig(float x) {
    return __builtin_amdgcn_rcpf(1.0f + __expf(-x));
}
__device__ __forceinline__ float ftanh(float x) {
    return 1.0f - 2.0f * __builtin_amdgcn_rcpf(1.0f + __expf(2.0f * x));
}

// ---------- fp8 e4m3 (OCP) helpers: HW converters with SW fallback ----------

__device__ __forceinline__ float e4m3_to_f32_sw(unsigned v) {
    unsigned s = v & 0x80u, E = (v >> 3) & 0xFu, m = v & 7u;
    float r = E ? ldexpf((float)(8 + m), (int)E - 10) : ldexpf((float)m, -9);
    return s ? -r : r;
}

__device__ __forceinline__ unsigned f32_to_e4m3_sw(float x) {
    float ax = fabsf(x);
    unsigned s = x < 0.0f ? 0x80u : 0u;
    if (!(ax > 0.0f)) return s;
    if (ax >= 448.0f) return s | 0x7Eu;
    int e;
    float m = frexpf(ax, &e);      // ax = m * 2^e, m in [0.5,1)
    int E = e - 1 + 7;
    if (E >= 1) {
        int q = (int)(m * 16.0f + 0.5f);
        if (q == 16) { q = 8; E += 1; if (E > 15) return s | 0x7Eu; }
        return s | (unsigned)(E << 3) | (unsigned)(q - 8);
    }
    int q = (int)(ax * 512.0f + 0.5f);
    if (q > 7) return s | 0x08u;
    return s | (unsigned)q;
}

// decode 8 fp8 bytes (uint2) -> 8 floats
__device__ __forceinline__ void dec8(uint2 r, float* f) {
#if __has_builtin(__builtin_amdgcn_cvt_pk_f32_fp8)
    f32x2 p0 = __builtin_amdgcn_cvt_pk_f32_fp8((int)r.x, false);
    f32x2 p1 = __builtin_amdgcn_cvt_pk_f32_fp8((int)r.x, true);
    f32x2 p2 = __builtin_amdgcn_cvt_pk_f32_fp8((int)r.y, false);
    f32x2 p3 = __builtin_amdgcn_cvt_pk_f32_fp8((int)r.y, true);
    f[0] = p0[0]; f[1] = p0[1]; f[2] = p1[0]; f[3] = p1[1];
    f[4] = p2[0]; f[5] = p2[1]; f[6] = p3[0]; f[7] = p3[1];
#else
#pragma unroll
    for (int k = 0; k < 4; ++k) f[k] = e4m3_to_f32_sw((r.x >> (8 * k)) & 0xFFu);
#pragma unroll
    for (int k = 0; k < 4; ++k) f[4 + k] = e4m3_to_f32_sw((r.y >> (8 * k)) & 0xFFu);
#endif
}

// encode 8 floats -> 8 fp8 bytes (uint2)
__device__ __forceinline__ uint2 enc8(const float* o) {
#if __has_builtin(__builtin_amdgcn_cvt_pk_fp8_f32)
    int w0 = 0, w1 = 0;
    w0 = __builtin_amdgcn_cvt_pk_fp8_f32(o[0], o[1], w0, false);
    w0 = __builtin_amdgcn_cvt_pk_fp8_f32(o[2], o[3], w0, true);
    w1 = __builtin_amdgcn_cvt_pk_fp8_f32(o[4], o[5], w1, false);
    w1 = __builtin_amdgcn_cvt_pk_fp8_f32(o[6], o[7], w1, true);
    return make_uint2((unsigned)w0, (unsigned)w1);
#else
    unsigned a = 0, b = 0;
#pragma unroll
    for (int k = 0; k < 4; ++k) a |= f32_to_e4m3_sw(o[k]) << (8 * k);
#pragma unroll
    for (int k = 0; k < 4; ++k) b |= f32_to_e4m3_sw(o[4 + k]) << (8 * k);
    return make_uint2(a, b);
#endif
}

// ================= Phase A: block-local counting sort into buckets =================

__global__ __launch_bounds__(512) void k_binsort(
        const int* __restrict__ src, const int* __restrict__ dst,
        const float* __restrict__ ew, int E, int NB, int bcap,
        int* __restrict__ gcur, uint2* __restrict__ recs) {
    __shared__ uint2 srec[KEDGE];
    __shared__ int hist[MAXNB], excl[MAXNB], curs[MAXNB], sbase[MAXNB];

    int tid = threadIdx.x;
    int base = blockIdx.x * KEDGE;
    int cnt = min(KEDGE, E - base);

    for (int i = tid; i < NB; i += 512) hist[i] = 0;
    __syncthreads();

    for (int i = tid; i < cnt; i += 512)
        atomicAdd(&hist[dst[base + i] >> 8], 1);
    __syncthreads();

    if (tid < 64) {
        int run = 0;
        for (int c = 0; c < NB; c += 64) {
            int idx = c + tid;
            int v = (idx < NB) ? hist[idx] : 0;
            int incl = v;
#pragma unroll
            for (int o = 1; o < 64; o <<= 1) {
                int up = __shfl_up(incl, o, 64);
                if (tid >= o) incl += up;
            }
            if (idx < NB) { int e = run + incl - v; excl[idx] = e; curs[idx] = e; }
            run += __shfl(incl, 63, 64);
        }
    }
    __syncthreads();

    for (int i = tid; i < cnt; i += 512) {
        int s = src[base + i];
        int d = dst[base + i];
        float w = ew[base + i];
        unsigned q = (unsigned)(w * WQ22 + 0.5f);
        if (q > 4194303u) q = 4194303u;
        int b = d >> 8;
        int pos = atomicAdd(&curs[b], 1);
        srec[pos] = make_uint2(((unsigned)s << 8) | (unsigned)(d & 255),
                               ((unsigned)b << 22) | q);
    }
    __syncthreads();

    for (int b = tid; b < NB; b += 512) {
        int len = hist[b];
        sbase[b] = len ? atomicAdd(&gcur[b], len) : 0;
    }
    __syncthreads();

    for (int i = tid; i < cnt; i += 512) {
        uint2 u = srec[i];
        int b = u.y >> 22;
        int off = sbase[b] + (i - excl[b]);
        if (off < bcap) recs[(size_t)b * bcap + off] = u;
    }
}

// ================= Phase B: per-bucket 4B records + CSR + dinv (4 KB LDS) =================

__global__ __launch_bounds__(512) void k_sortb(
        const uint2* __restrict__ recs, const int* __restrict__ gcur, int bcap,
        unsigned* __restrict__ recs4, int* __restrict__ pstart,
        int* __restrict__ pcnt, float* __restrict__ dinv, int n) {
    __shared__ int hist[BS], excl[BS], curs[BS];
    __shared__ float wsum[BS];

    int b = blockIdx.x, tid = threadIdx.x;
    int cnt = min(gcur[b], bcap);
    const uint2* r = recs + (size_t)b * bcap;
    const float dq = 1.0f / WQ22;

    if (tid < BS) { hist[tid] = 0; wsum[tid] = 1.0f; }  // self-loop weight
    __syncthreads();

    for (int i = tid; i < cnt; i += 512) {
        uint2 u = r[i];
        int dl = u.x & 255;
        atomicAdd(&hist[dl], 1);
        atomicAdd(&wsum[dl], (float)(u.y & 4194303u) * dq);
    }
    __syncthreads();

    if (tid < BS) wsum[tid] = rsqrtf(wsum[tid]);  // -> dinv_d
    if (tid < 64) {
        int run = 0;
        for (int c = 0; c < BS; c += 64) {
            int idx = c + tid;
            int v = hist[idx];
            int incl = v;
#pragma unroll
            for (int o = 1; o < 64; o <<= 1) {
                int up = __shfl_up(incl, o, 64);
                if (tid >= o) incl += up;
            }
            int e = run + incl - v;
            excl[idx] = e; curs[idx] = e;
            run += __shfl(incl, 63, 64);
        }
    }
    __syncthreads();

    unsigned* out4 = recs4 + (size_t)b * bcap;
    for (int i = tid; i < cnt; i += 512) {
        uint2 u = r[i];
        int dl = u.x & 255;
        int pos = atomicAdd(&curs[dl], 1);
        float qn = (float)(u.y & 4194303u) * dq * wsum[dl];  // w * dinv_d
        unsigned q = (unsigned)(qn * WQ14 + 0.5f);
        if (q > 16383u) q = 16383u;
        out4[pos] = ((u.x >> 8) << 14) | q;
    }

    if (tid < BS) {
        int g = b * BS + tid;
        if (g < n) {
            pstart[g] = b * bcap + excl[tid];
            pcnt[g] = hist[tid];
            dinv[g] = wsum[tid];
        }
    }
}

// ================= weight pack for MFMA head + gcur zeroing (runs once) =================

__global__ void k_pack(const float* __restrict__ wih1, const float* __restrict__ bih1,
                       const float* __restrict__ bhh1, const float* __restrict__ wih2,
                       const float* __restrict__ bih2, const float* __restrict__ bhh2,
                       __half* __restrict__ wp1, __half* __restrict__ wp2,
                       float* __restrict__ bsum1, float* __restrict__ bsum2,
                       int* __restrict__ gcur, int NB) {
    const int tg[6] = {0, 16, 64, 80, 96, 112};
    int idx = blockIdx.x * blockDim.x + threadIdx.x;
    if (idx < 6144) {
        int t = idx >> 10, rem = idx & 1023;
        int kc = rem >> 9, rem2 = rem & 511;
        int lane = rem2 >> 3, j = rem2 & 7;
        int g = tg[t] + (lane & 15);
        int k = kc * 32 + (lane >> 4) * 8 + j;
        wp1[idx] = __float2half(wih1[g * 64 + k]);
    } else if (idx < 9216) {
        int i2 = idx - 6144;
        int t = i2 >> 9, rem2 = i2 & 511;
        int lane = rem2 >> 3, j = rem2 & 7;
        int g = tg[t] + (lane & 15);
        int k = (lane >> 4) * 8 + j;
        wp2[i2] = __float2half(wih2[g * 32 + k]);
    } else if (idx < 9344) {
        int i = idx - 9216;
        bsum1[i] = bih1[i] + bhh1[i];
    } else if (idx < 9472) {
        int i = idx - 9344;
        bsum2[i] = bih2[i] + bhh2[i];
    } else if (idx - 9472 < NB) {
        gcur[idx - 9472] = 0;
    }
}

// ================= layer 1 FUSED: gather(x@W1) + BN + xw2 -> A8 (fp8) =================
// Phase 1: per-node aggregation with in-register x-projection (x L2-resident).
// Phase 2: block-local h1 @ W2 -> fp8 A matrix. One kernel, no xw2 pass.

__global__ __launch_bounds__(256) void k_gx1w2(
        const unsigned* __restrict__ recs4, const int* __restrict__ pstart,
        const int* __restrict__ pcnt, const float* __restrict__ dinv,
        const float* __restrict__ x, const float* __restrict__ W1,
        const float* __restrict__ W2,
        const float* __restrict__ bias, const float* __restrict__ gamma,
        const float* __restrict__ beta, const float* __restrict__ mean,
        const float* __restrict__ var,
        __half* __restrict__ skiph, unsigned char* __restrict__ A8, int n) {
    __shared__ float sW[128];
    __shared__ float sW2[1024];
    __shared__ float sh1[64][33];
    int tid = threadIdx.x;
    if (tid < 128) sW[tid] = W1[tid];
    for (int i = tid; i < 1024; i += 256) sW2[i] = W2[i];
    __syncthreads();

    int nl = tid >> 2;
    int g = blockIdx.x * 64 + nl;
    int lane = tid & 3;
    int fq = lane * 8;
    bool act = g < n;

    float w[4][8];
#pragma unroll
    for (int r = 0; r < 4; ++r)
#pragma unroll
        for (int k = 0; k < 8; ++k) w[r][k] = sW[r * 32 + fq + k];

    float acc[8];
#pragma unroll
    for (int k = 0; k < 8; ++k) acc[k] = 0.0f;

    if (act) {
        float dig = dinv[g];
        float sl = dig * dig;
        float4 xg = *(const float4*)(x + (size_t)g * 4);
#pragma unroll
        for (int k = 0; k < 8; ++k)
            acc[k] = sl * (xg.x * w[0][k] + xg.y * w[1][k] + xg.z * w[2][k] + xg.w * w[3][k]);

        const float qs = 1.0f / WQ14;
        int cn = pcnt[g];
        const unsigned* r = recs4 + pstart[g];
        int e = 0;
        for (; e + 4 <= cn; e += 4) {
            unsigned u0 = r[e], u1 = r[e + 1], u2 = r[e + 2], u3 = r[e + 3];
            float4 x0 = *(const float4*)(x + (size_t)(u0 >> 14) * 4);
            float4 x1 = *(const float4*)(x + (size_t)(u1 >> 14) * 4);
            float4 x2 = *(const float4*)(x + (size_t)(u2 >> 14) * 4);
            float4 x3 = *(const float4*)(x + (size_t)(u3 >> 14) * 4);
            float n0 = (float)(u0 & 16383u) * qs * dinv[u0 >> 14];
            float n1 = (float)(u1 & 16383u) * qs * dinv[u1 >> 14];
            float n2 = (float)(u2 & 16383u) * qs * dinv[u2 >> 14];
            float n3 = (float)(u3 & 16383u) * qs * dinv[u3 >> 14];
#pragma unroll
            for (int k = 0; k < 8; ++k) {
                acc[k] += n0 * (x0.x * w[0][k] + x0.y * w[1][k] + x0.z * w[2][k] + x0.w * w[3][k]);
                acc[k] += n1 * (x1.x * w[0][k] + x1.y * w[1][k] + x1.z * w[2][k] + x1.w * w[3][k]);
                acc[k] += n2 * (x2.x * w[0][k] + x2.y * w[1][k] + x2.z * w[2][k] + x2.w * w[3][k]);
                acc[k] += n3 * (x3.x * w[0][k] + x3.y * w[1][k] + x3.z * w[2][k] + x3.w * w[3][k]);
            }
        }
        for (; e < cn; ++e) {
            unsigned u0 = r[e];
            float4 x0 = *(const float4*)(x + (size_t)(u0 >> 14) * 4);
            float n0 = (float)(u0 & 16383u) * qs * dinv[u0 >> 14];
#pragma unroll
            for (int k = 0; k < 8; ++k)
                acc[k] += n0 * (x0.x * w[0][k] + x0.y * w[1][k] + x0.z * w[2][k] + x0.w * w[3][k]);
        }
    }

    // h1 epilogue: bias + relu + BN; stage for xw2; emit fp16 skip slice
    float o[8];
#pragma unroll
    for (int k = 0; k < 8; ++k) {
        float v = fmaxf(acc[k] + bias[fq + k], 0.0f);
        o[k] = (v - mean[fq + k]) * gamma[fq + k] * rsqrtf(var[fq + k] + BN_EPS) + beta[fq + k];
        sh1[nl][fq + k] = o[k];
    }
    if (act) {
        union { __half h[8]; uint4 q; } hv;
#pragma unroll
        for (int k = 0; k < 8; ++k) hv.h[k] = __float2half(o[k]);
        *(uint4*)(skiph + (size_t)g * 64 + fq) = hv.q;
    }
    __syncthreads();

    // phase 2: A[g] = h1[g] @ W2 -> fp8
    if (act) {
        float a2[8];
#pragma unroll
        for (int j = 0; j < 8; ++j) a2[j] = 0.0f;
#pragma unroll 4
        for (int k = 0; k < 32; ++k) {
            float h = sh1[nl][k];
            const float* wr = sW2 + k * 32 + fq;
#pragma unroll
            for (int j = 0; j < 8; ++j) a2[j] += h * wr[j];
        }
        ((uint2*)(A8 + ((size_t)g << 5)))[lane] = enc8(a2);
    }
}

// ================= gather layer 2: fp8 A rows (32B) + fused epilogue =================

__global__ __launch_bounds__(256) void k_gather8(
        const unsigned* __restrict__ recs4, const int* __restrict__ pstart,
        const int* __restrict__ pcnt, const float* __restrict__ dinv,
        const unsigned char* __restrict__ A8,
        const float* __restrict__ bias, const float* __restrict__ gamma,
        const float* __restrict__ beta, const float* __restrict__ mean,
        const float* __restrict__ var,
        __half* __restrict__ skiph, int uoff, int n) {
    int g = blockIdx.x * 64 + (threadIdx.x >> 2);
    int lane = threadIdx.x & 3;
    if (g >= n) return;

    float dig = dinv[g];
    float sl = dig * dig;
    float acc[8];
    {
        uint2 sr = ((const uint2*)(A8 + ((size_t)g << 5)))[lane];
        float f[8];
        dec8(sr, f);
#pragma unroll
        for (int k = 0; k < 8; ++k) acc[k] = sl * f[k];
    }

    const float qs = 1.0f / WQ14;
    int cn = pcnt[g];
    const unsigned* r = recs4 + pstart[g];
    int e = 0;
    for (; e + 4 <= cn; e += 4) {
        unsigned u0 = r[e], u1 = r[e + 1], u2 = r[e + 2], u3 = r[e + 3];
        uint2 r0 = ((const uint2*)(A8 + ((size_t)(u0 >> 14) << 5)))[lane];
        uint2 r1 = ((const uint2*)(A8 + ((size_t)(u1 >> 14) << 5)))[lane];
        uint2 r2 = ((const uint2*)(A8 + ((size_t)(u2 >> 14) << 5)))[lane];
        uint2 r3 = ((const uint2*)(A8 + ((size_t)(u3 >> 14) << 5)))[lane];
        float n0 = (float)(u0 & 16383u) * qs * dinv[u0 >> 14];
        float n1 = (float)(u1 & 16383u) * qs * dinv[u1 >> 14];
        float n2 = (float)(u2 & 16383u) * qs * dinv[u2 >> 14];
        float n3 = (float)(u3 & 16383u) * qs * dinv[u3 >> 14];
        float f0[8], f1[8], f2[8], f3[8];
        dec8(r0, f0); dec8(r1, f1); dec8(r2, f2); dec8(r3, f3);
#pragma unroll
        for (int k = 0; k < 8; ++k)
            acc[k] += n0 * f0[k] + n1 * f1[k] + n2 * f2[k] + n3 * f3[k];
    }
    for (; e < cn; ++e) {
        unsigned u0 = r[e];
        uint2 r0 = ((const uint2*)(A8 + ((size_t)(u0 >> 14) << 5)))[lane];
        float n0 = (float)(u0 & 16383u) * qs * dinv[u0 >> 14];
        float f0[8];
        dec8(r0, f0);
#pragma unroll
        for (int k = 0; k < 8; ++k) acc[k] += n0 * f0[k];
    }

    int fq = lane * 8;
    union { __half h[8]; uint4 q; } hv;
#pragma unroll
    for (int k = 0; k < 8; ++k) {
        float v = fmaxf(acc[k] + bias[fq + k], 0.0f);
        hv.h[k] = __float2half((v - mean[fq + k]) * gamma[fq + k] * rsqrtf(var[fq + k] + BN_EPS) + beta[fq + k]);
    }
    *(uint4*)(skiph + (size_t)g * 64 + uoff + fq) = hv.q;
}

// ================= MFMA fused head: LSTM1 + LSTM2 + linear =================

__global__ __launch_bounds__(256) void k_headm(
        const __half* __restrict__ skiph, const float* __restrict__ x,
        const __half* __restrict__ wp1, const __half* __restrict__ wp2,
        const float* __restrict__ bsum1, const float* __restrict__ bsum2,
        const float* __restrict__ lw, const float* __restrict__ lb,
        float* __restrict__ out, int n) {
    __shared__ __align__(16) __half H1lds[4 * 16 * 40];
    int tid = threadIdx.x;
    int w = tid >> 6, l = tid & 63;
    int quad = l >> 4, c = l & 15;
    int node_base = blockIdx.x * 64 + w * 16;

    int arow = node_base + c; if (arow > n - 1) arow = n - 1;
    const half8* ap = (const half8*)(skiph + (size_t)arow * 64);
    half8 a0 = ap[quad];
    half8 a1 = ap[4 + quad];

    const half8* b1 = (const half8*)wp1;
    f32x4 d[6];
#pragma unroll
    for (int t = 0; t < 6; ++t) {
        f32x4 acc = {0.0f, 0.0f, 0.0f, 0.0f};
        acc = __builtin_amdgcn_mfma_f32_16x16x32_f16(a0, b1[(t * 2 + 0) * 64 + l], acc, 0, 0, 0);
        acc = __builtin_amdgcn_mfma_f32_16x16x32_f16(a1, b1[(t * 2 + 1) * 64 + l], acc, 0, 0, 0);
        d[t] = acc;
    }

    float bi0 = bsum1[c],      bi1 = bsum1[16 + c];
    float bg0 = bsum1[64 + c], bg1 = bsum1[80 + c];
    float bo0 = bsum1[96 + c], bo1 = bsum1[112 + c];
    float lwc0 = lw[c], lwc1 = lw[c + 16];

    float pa[4];
#pragma unroll
    for (int r = 0; r < 4; ++r) {
        float cc0 = fsig(d[0][r] + bi0) * ftanh(d[2][r] + bg0);
        float h0 = fsig(d[4][r] + bo0) * ftanh(cc0);
        float cc1 = fsig(d[1][r] + bi1) * ftanh(d[3][r] + bg1);
        float h1 = fsig(d[5][r] + bo1) * ftanh(cc1);
        pa[r] = fmaxf(h0, 0.0f) * lwc0 + fmaxf(h1, 0.0f) * lwc1;
        __half* hp = H1lds + (w * 16 + quad * 4 + r) * 40;
        hp[c] = __float2half(h0);
        hp[c + 16] = __float2half(h1);
    }
    __syncthreads();

    half8 a2 = *(const half8*)(H1lds + (w * 16 + c) * 40 + quad * 8);

    const half8* b2 = (const half8*)wp2;
    f32x4 e[6];
#pragma unroll
    for (int t = 0; t < 6; ++t) {
        f32x4 acc = {0.0f, 0.0f, 0.0f, 0.0f};
        e[t] = __builtin_amdgcn_mfma_f32_16x16x32_f16(a2, b2[t * 64 + l], acc, 0, 0, 0);
    }

    float ci0 = bsum2[c],      ci1 = bsum2[16 + c];
    float cg0 = bsum2[64 + c], cg1 = bsum2[80 + c];
    float co0 = bsum2[96 + c], co1 = bsum2[112 + c];
    float lw2c0 = lw[32 + c], lw2c1 = lw[48 + c];
#pragma unroll
    for (int r = 0; r < 4; ++r) {
        float cc0 = fsig(e[0][r] + ci0) * ftanh(e[2][r] + cg0);
        float h0 = fsig(e[4][r] + co0) * ftanh(cc0);
        float cc1 = fsig(e[1][r] + ci1) * ftanh(e[3][r] + cg1);
        float h1 = fsig(e[5][r] + co1) * ftanh(cc1);
        pa[r] += fmaxf(h0, 0.0f) * lw2c0 + fmaxf(h1, 0.0f) * lw2c1;
    }

#pragma unroll
    for (int m = 1; m < 16; m <<= 1) {
#pragma unroll
        for (int r = 0; r < 4; ++r) pa[r] += __shfl_xor(pa[r], m, 64);
    }

    if (c < 4) {
        int node = node_base + quad * 4 + c;
        if (node < n) {
            const float4 xv = *(const float4*)(x + (size_t)node * 4);
            out[node] = pa[c] + lb[0]
                + fmaxf(xv.x, 0.0f) * lw[64] + fmaxf(xv.y, 0.0f) * lw[65]
                + fmaxf(xv.z, 0.0f) * lw[66] + fmaxf(xv.w, 0.0f) * lw[67];
        }
    }
}

// ================= fallback (atomic scatter, fp32) =================

__global__ void k_initdeg(float* __restrict__ deg, int n) {
    int i = blockIdx.x * blockDim.x + threadIdx.x;
    if (i < n) deg[i] = 1.0f;
}

__global__ void k_deg_only(const int* __restrict__ dst, const float* __restrict__ ew,
                           float* __restrict__ deg, int E) {
    int e = blockIdx.x * blockDim.x + threadIdx.x;
    if (e < E) atomicAdd(&deg[dst[e]], ew[e]);
}

__global__ void k_dinv_f(float* __restrict__ deg, int n) {
    int i = blockIdx.x * blockDim.x + threadIdx.x;
    if (i < n) {
        float d = deg[i];
        deg[i] = d > 0.0f ? rsqrtf(d) : 0.0f;
    }
}

__global__ void k_xw1_f(const float* __restrict__ x, const float* __restrict__ W,
                        float* __restrict__ out, int n) {
    int idx = blockIdx.x * blockDim.x + threadIdx.x;
    if (idx >= n * HF) return;
    int nn = idx >> 5, f = idx & 31;
    const float4 xr = *(const float4*)(x + (size_t)nn * 4);
    out[idx] = xr.x * W[f] + xr.y * W[32 + f] + xr.z * W[64 + f] + xr.w * W[96 + f];
}

__global__ void k_xw2_f(const float* __restrict__ Hin, const float* __restrict__ W,
                        float* __restrict__ out, int n) {
    __shared__ float sW[32 * 32];
    __shared__ float sH[8][32];
    int tid = threadIdx.x;
    for (int i = tid; i < 1024; i += 256) sW[i] = W[i];
    int r = tid >> 5, f = tid & 31;
    int nn = blockIdx.x * 8 + r;
    if (nn < n) sH[r][f] = Hin[(size_t)nn * HF + f];
    __syncthreads();
    if (nn >= n) return;
    float acc = 0.0f;
#pragma unroll
    for (int k = 0; k < 32; ++k) acc += sH[r][k] * sW[k * 32 + f];
    out[(size_t)nn * HF + f] = acc;
}

__global__ void k_selfloop(const float* __restrict__ A, const float* __restrict__ dinv,
                           float* __restrict__ B, int n) {
    int idx = blockIdx.x * blockDim.x + threadIdx.x;
    if (idx >= n * HF) return;
    int nn = idx >> 5;
    float di = dinv[nn];
    B[idx] = di * di * A[idx];
}

__global__ void k_scatter(const int* __restrict__ src, const int* __restrict__ dst,
                          const float* __restrict__ ew, const float* __restrict__ dinv,
                          const float* __restrict__ A, float* __restrict__ B, int total) {
    int idx = blockIdx.x * blockDim.x + threadIdx.x;
    if (idx >= total) return;
    int e = idx >> 5, f = idx & 31;
    int s = src[e], d = dst[e];
    float norm = dinv[s] * ew[e] * dinv[d];
    atomicAdd(&B[d * HF + f], norm * A[s * HF + f]);
}

__global__ void k_post(const float* __restrict__ B, const float* __restrict__ bias,
                       const float* __restrict__ gamma, const float* __restrict__ beta,
                       const float* __restrict__ mean, const float* __restrict__ var,
                       float* __restrict__ Hout, int n) {
    int idx = blockIdx.x * blockDim.x + threadIdx.x;
    if (idx >= n * HF) return;
    int f = idx & 31;
    float v = fmaxf(B[idx] + bias[f], 0.0f);
    float sc = gamma[f] * rsqrtf(var[f] + BN_EPS);
    Hout[idx] = (v - mean[f]) * sc + beta[f];
}

__global__ __launch_bounds__(256) void k_head(
        const float* __restrict__ h1, const float* __restrict__ h2,
        const float* __restrict__ x,
        const float* __restrict__ wih1, const float* __restrict__ bih1, const float* __restrict__ bhh1,
        const float* __restrict__ wih2, const float* __restrict__ bih2, const float* __restrict__ bhh2,
        const float* __restrict__ lw, const float* __restrict__ lb,
        float* __restrict__ out, int n) {
    __shared__ float sH1[32 * 256];
    int tid = threadIdx.x;
    int nn = blockIdx.x * 256 + tid;
    if (nn >= n) return;

    const float4* a = (const float4*)(h1 + (size_t)nn * HF);
    const float4* b = (const float4*)(h2 + (size_t)nn * HF);
    float skip[64];
#pragma unroll
    for (int q = 0; q < 8; ++q) {
        float4 v = a[q];
        skip[4 * q] = v.x; skip[4 * q + 1] = v.y; skip[4 * q + 2] = v.z; skip[4 * q + 3] = v.w;
        float4 u = b[q];
        skip[32 + 4 * q] = u.x; skip[33 + 4 * q] = u.y; skip[34 + 4 * q] = u.z; skip[35 + 4 * q] = u.w;
    }

    float oa = lb[0];
#pragma unroll 1
    for (int j = 0; j < 32; ++j) {
        const float4* wi = (const float4*)(wih1 + (size_t)j * 64);
        const float4* wg = (const float4*)(wih1 + (size_t)(64 + j) * 64);
        const float4* wo = (const float4*)(wih1 + (size_t)(96 + j) * 64);
        float gi = bih1[j] + bhh1[j];
        float gg = bih1[64 + j] + bhh1[64 + j];
        float go = bih1[96 + j] + bhh1[96 + j];
#pragma unroll
        for (int q = 0; q < 16; ++q) {
            float4 aa = wi[q], bb = wg[q], cc4 = wo[q];
            float s0 = skip[4 * q], s1 = skip[4 * q + 1], s2 = skip[4 * q + 2], s3 = skip[4 * q + 3];
            gi += aa.x * s0 + aa.y * s1 + aa.z * s2 + aa.w * s3;
            gg += bb.x * s0 + bb.y * s1 + bb.z * s2 + bb.w * s3;
            go += cc4.x * s0 + cc4.y * s1 + cc4.z * s2 + cc4.w * s3;
        }
        float cc = fsig(gi) * ftanh(gg);
        float hh = fsig(go) * ftanh(cc);
        sH1[j * 256 + tid] = hh;
        oa += fmaxf(hh, 0.0f) * lw[j];
    }

#pragma unroll 1
    for (int j = 0; j < 32; ++j) {
        const float4* wi = (const float4*)(wih2 + (size_t)j * 32);
        const float4* wg = (const float4*)(wih2 + (size_t)(64 + j) * 32);
        const float4* wo = (const float4*)(wih2 + (size_t)(96 + j) * 32);
        float gi = bih2[j] + bhh2[j];
        float gg = bih2[64 + j] + bhh2[64 + j];
        float go = bih2[96 + j] + bhh2[96 + j];
#pragma unroll
        for (int q = 0; q < 8; ++q) {
            float4 aa = wi[q], bb = wg[q], cc4 = wo[q];
            float s0 = sH1[(4 * q) * 256 + tid], s1 = sH1[(4 * q + 1) * 256 + tid];
            float s2 = sH1[(4 * q + 2) * 256 + tid], s3 = sH1[(4 * q + 3) * 256 + tid];
            gi += aa.x * s0 + aa.y * s1 + aa.z * s2 + aa.w * s3;
            gg += bb.x * s0 + bb.y * s1 + bb.z * s2 + bb.w * s3;
            go += cc4.x * s0 + cc4.y * s1 + cc4.z * s2 + cc4.w * s3;
        }
        float cc = fsig(gi) * ftanh(gg);
        float hh = fsig(go) * ftanh(cc);
        oa += fmaxf(hh, 0.0f) * lw[32 + j];
    }

    const float4 xv = *(const float4*)(x + (size_t)nn * 4);
    oa += fmaxf(xv.x, 0.0f) * lw[64] + fmaxf(xv.y, 0.0f) * lw[65] +
          fmaxf(xv.z, 0.0f) * lw[66] + fmaxf(xv.w, 0.0f) * lw[67];
    out[nn] = oa;
}

// ================= launch =================

extern "C" void kernel_launch(void* const* d_in, const int* in_sizes, int n_in,
                              void* d_out, int out_size, void* d_ws, size_t ws_size,
                              hipStream_t stream) {
    const float* x   = (const float*)d_in[0];
    const int*   ei  = (const int*)d_in[1];
    const float* ew  = (const float*)d_in[2];
    const float* g1w = (const float*)d_in[3];
    const float* g1b = (const float*)d_in[4];
    const float* g2w = (const float*)d_in[5];
    const float* g2b = (const float*)d_in[6];
    const float* bn1g = (const float*)d_in[7];
    const float* bn1b = (const float*)d_in[8];
    const float* bn1m = (const float*)d_in[9];
    const float* bn1v = (const float*)d_in[10];
    const float* bn2g = (const float*)d_in[11];
    const float* bn2b = (const float*)d_in[12];
    const float* bn2m = (const float*)d_in[13];
    const float* bn2v = (const float*)d_in[14];
    const float* w1ih = (const float*)d_in[15];
    const float* b1ih = (const float*)d_in[17];
    const float* b1hh = (const float*)d_in[18];
    const float* w2ih = (const float*)d_in[19];
    const float* b2ih = (const float*)d_in[21];
    const float* b2hh = (const float*)d_in[22];
    const float* lw   = (const float*)d_in[23];
    const float* lb   = (const float*)d_in[24];
    float* out = (float*)d_out;

    const int N = in_sizes[0] / 4;
    const int E = in_sizes[2];
    const int* src = ei;
    const int* dst = ei + E;

    const int T = 256;
    const int NB = (N + BS - 1) / BS;
    long long meanb = ((long long)BS * E) / (N > 0 ? N : 1);
    int bcap = (int)(meanb + meanb / 4 + 128);

    // workspace layout (256B-aligned regions)
    char* p = (char*)d_ws;
    auto alloc = [&](size_t bytes) { char* q = p; p += (bytes + 255) & ~(size_t)255; return q; };
    int*      gcur   = (int*)alloc(sizeof(int) * NB);
    uint2*    recs   = (uint2*)alloc(sizeof(uint2) * (size_t)NB * bcap);
    unsigned* recs4  = (unsigned*)alloc(sizeof(unsigned) * (size_t)NB * bcap);
    float*    dinv   = (float*)alloc(sizeof(float) * N);
    int*      pstart = (int*)alloc(sizeof(int) * N);
    int*      pcnt   = (int*)alloc(sizeof(int) * N);
    unsigned char* A8 = (unsigned char*)alloc((size_t)N * HF);          // fp8 xw2 output
    __half*   skiph  = (__half*)alloc(sizeof(__half) * (size_t)N * 64); // h1|h2 f16
    __half*   wp1    = (__half*)alloc(sizeof(__half) * 6144);
    __half*   wp2    = (__half*)alloc(sizeof(__half) * 3072);
    float*    bsum1  = (float*)alloc(sizeof(float) * 128);
    float*    bsum2  = (float*)alloc(sizeof(float) * 128);
    size_t need = (size_t)(p - (char*)d_ws);

    int bN  = (N + T - 1) / T;
    int bE  = (E + T - 1) / T;
    int bNF = (N * HF + T - 1) / T;
    int bN8 = (N + 7) / 8;
    int bG  = (N + 63) / 64;
    int bBin = (E + KEDGE - 1) / KEDGE;
    int bPack = (9472 + NB + 255) / 256;

    if (ws_size >= need && NB <= MAXNB && N <= (1 << 18)) {
        // ---- build ----
        k_pack<<<bPack, 256, 0, stream>>>(w1ih, b1ih, b1hh, w2ih, b2ih, b2hh,
                                          wp1, wp2, bsum1, bsum2, gcur, NB);
        k_binsort<<<bBin, 512, 0, stream>>>(src, dst, ew, E, NB, bcap, gcur, recs);
        k_sortb<<<NB, 512, 0, stream>>>(recs, gcur, bcap, recs4, pstart, pcnt, dinv, N);

        // ---- layer 1 fused with xw2: -> skiph[0:32], A8 (fp8) ----
        k_gx1w2<<<bG, T, 0, stream>>>(recs4, pstart, pcnt, dinv, x, g1w, g2w,
                                      g1b, bn1g, bn1b, bn1m, bn1v, skiph, A8, N);
        // ---- layer 2: fp8 gather -> skiph[32:64] ----
        k_gather8<<<bG, T, 0, stream>>>(recs4, pstart, pcnt, dinv, A8,
                                        g2b, bn2g, bn2b, bn2m, bn2v, skiph, 32, N);
        // ---- MFMA head ----
        k_headm<<<bG, T, 0, stream>>>(skiph, x, wp1, wp2, bsum1, bsum2,
                                      lw, lb, out, N);
    } else {
        // ---- fallback: atomic scatter, fp32 ----
        size_t Npad = ((size_t)N + 255) & ~(size_t)255;
        float* fdinv = (float*)d_ws;
        float* fA = fdinv + Npad;
        float* fB = fA + (size_t)N * HF;
        float* fC = fB + (size_t)N * HF;
        int bEF = (int)(((long long)E * HF + T - 1) / T);
        int bH = (N + 255) / 256;

        k_initdeg<<<bN, T, 0, stream>>>(fdinv, N);
        k_deg_only<<<bE, T, 0, stream>>>(dst, ew, fdinv, E);
        k_dinv_f<<<bN, T, 0, stream>>>(fdinv, N);

        k_xw1_f<<<bNF, T, 0, stream>>>(x, g1w, fA, N);
        k_selfloop<<<bNF, T, 0, stream>>>(fA, fdinv, fB, N);
        k_scatter<<<bEF, T, 0, stream>>>(src, dst, ew, fdinv, fA, fB, E * HF);
        k_post<<<bNF, T, 0, stream>>>(fB, g1b, bn1g, bn1b, bn1m, bn1v, fC, N);

        k_xw2_f<<<bN8, T, 0, stream>>>(fC, g2w, fA, N);
        k_selfloop<<<bNF, T, 0, stream>>>(fA, fdinv, fB, N);
        k_scatter<<<bEF, T, 0, stream>>>(src, dst, ew, fdinv, fA, fB, E * HF);
        k_post<<<bNF, T, 0, stream>>>(fB, g2b, bn2g, bn2b, bn2m, bn2v, fB, N);

        k_head<<<bH, T, 0, stream>>>(fC, fB, x, w1ih, b1ih, b1hh, w2ih, b2ih, b2hh,
                                     lw, lb, out, N);
    }
}

// Round 14
// 331.056 us; speedup vs baseline: 2.3693x; 1.0161x over previous
//
#include <hip/hip_runtime.h>
#include <hip/hip_fp16.h>
#include <math.h>

#define BN_EPS 1e-5f
#define HF 32          // hidden features
#define BS 256         // nodes per bucket (8-bit dloc)
#define KEDGE 4096     // edges per binsort block
#define MAXNB 800      // max buckets (NB=782 for N=200k)
#define WQ14 16383.0f  // 14-bit norm quantization
#define WQ22 4194303.0f // 22-bit raw-weight quantization (binsort staging)

typedef _Float16 half8 __attribute__((ext_vector_type(8)));
typedef float f32x4 __attribute__((ext_vector_type(4)));
typedef float f32x2 __attribute__((ext_vector_type(2)));

// fast transcendentals (trans pipe)
__device__ __forceinline__ float fsig(float x) {
    return __builtin_amdgcn_rcpf(1.0f + __expf(-x));
}
__device__ __forceinline__ float ftanh(float x) {
    return 1.0f - 2.0f * __builtin_amdgcn_rcpf(1.0f + __expf(2.0f * x));
}

// ---------- fp8 e4m3 (OCP) helpers: HW converters with SW fallback ----------

__device__ __forceinline__ float e4m3_to_f32_sw(unsigned v) {
    unsigned s = v & 0x80u, E = (v >> 3) & 0xFu, m = v & 7u;
    float r = E ? ldexpf((float)(8 + m), (int)E - 10) : ldexpf((float)m, -9);
    return s ? -r : r;
}

__device__ __forceinline__ unsigned f32_to_e4m3_sw(float x) {
    float ax = fabsf(x);
    unsigned s = x < 0.0f ? 0x80u : 0u;
    if (!(ax > 0.0f)) return s;
    if (ax >= 448.0f) return s | 0x7Eu;
    int e;
    float m = frexpf(ax, &e);      // ax = m * 2^e, m in [0.5,1)
    int E = e - 1 + 7;
    if (E >= 1) {
        int q = (int)(m * 16.0f + 0.5f);
        if (q == 16) { q = 8; E += 1; if (E > 15) return s | 0x7Eu; }
        return s | (unsigned)(E << 3) | (unsigned)(q - 8);
    }
    int q = (int)(ax * 512.0f + 0.5f);
    if (q > 7) return s | 0x08u;
    return s | (unsigned)q;
}

__device__ __forceinline__ void dec8(uint2 r, float* f) {
#if __has_builtin(__builtin_amdgcn_cvt_pk_f32_fp8)
    f32x2 p0 = __builtin_amdgcn_cvt_pk_f32_fp8((int)r.x, false);
    f32x2 p1 = __builtin_amdgcn_cvt_pk_f32_fp8((int)r.x, true);
    f32x2 p2 = __builtin_amdgcn_cvt_pk_f32_fp8((int)r.y, false);
    f32x2 p3 = __builtin_amdgcn_cvt_pk_f32_fp8((int)r.y, true);
    f[0] = p0[0]; f[1] = p0[1]; f[2] = p1[0]; f[3] = p1[1];
    f[4] = p2[0]; f[5] = p2[1]; f[6] = p3[0]; f[7] = p3[1];
#else
#pragma unroll
    for (int k = 0; k < 4; ++k) f[k] = e4m3_to_f32_sw((r.x >> (8 * k)) & 0xFFu);
#pragma unroll
    for (int k = 0; k < 4; ++k) f[4 + k] = e4m3_to_f32_sw((r.y >> (8 * k)) & 0xFFu);
#endif
}

__device__ __forceinline__ uint2 enc8(const float* o) {
#if __has_builtin(__builtin_amdgcn_cvt_pk_fp8_f32)
    int w0 = 0, w1 = 0;
    w0 = __builtin_amdgcn_cvt_pk_fp8_f32(o[0], o[1], w0, false);
    w0 = __builtin_amdgcn_cvt_pk_fp8_f32(o[2], o[3], w0, true);
    w1 = __builtin_amdgcn_cvt_pk_fp8_f32(o[4], o[5], w1, false);
    w1 = __builtin_amdgcn_cvt_pk_fp8_f32(o[6], o[7], w1, true);
    return make_uint2((unsigned)w0, (unsigned)w1);
#else
    unsigned a = 0, b = 0;
#pragma unroll
    for (int k = 0; k < 4; ++k) a |= f32_to_e4m3_sw(o[k]) << (8 * k);
#pragma unroll
    for (int k = 0; k < 4; ++k) b |= f32_to_e4m3_sw(o[4 + k]) << (8 * k);
    return make_uint2(a, b);
#endif
}

// ================= Phase A: block-local counting sort into buckets =================

__global__ __launch_bounds__(512) void k_binsort(
        const int* __restrict__ src, const int* __restrict__ dst,
        const float* __restrict__ ew, int E, int NB, int bcap,
        int* __restrict__ gcur, uint2* __restrict__ recs) {
    __shared__ uint2 srec[KEDGE];
    __shared__ int hist[MAXNB], excl[MAXNB], curs[MAXNB], sbase[MAXNB];

    int tid = threadIdx.x;
    int base = blockIdx.x * KEDGE;
    int cnt = min(KEDGE, E - base);

    for (int i = tid; i < NB; i += 512) hist[i] = 0;
    __syncthreads();

    for (int i = tid; i < cnt; i += 512)
        atomicAdd(&hist[dst[base + i] >> 8], 1);
    __syncthreads();

    if (tid < 64) {
        int run = 0;
        for (int c = 0; c < NB; c += 64) {
            int idx = c + tid;
            int v = (idx < NB) ? hist[idx] : 0;
            int incl = v;
#pragma unroll
            for (int o = 1; o < 64; o <<= 1) {
                int up = __shfl_up(incl, o, 64);
                if (tid >= o) incl += up;
            }
            if (idx < NB) { int e = run + incl - v; excl[idx] = e; curs[idx] = e; }
            run += __shfl(incl, 63, 64);
        }
    }
    __syncthreads();

    for (int i = tid; i < cnt; i += 512) {
        int s = src[base + i];
        int d = dst[base + i];
        float w = ew[base + i];
        unsigned q = (unsigned)(w * WQ22 + 0.5f);
        if (q > 4194303u) q = 4194303u;
        int b = d >> 8;
        int pos = atomicAdd(&curs[b], 1);
        srec[pos] = make_uint2(((unsigned)s << 8) | (unsigned)(d & 255),
                               ((unsigned)b << 22) | q);
    }
    __syncthreads();

    for (int b = tid; b < NB; b += 512) {
        int len = hist[b];
        sbase[b] = len ? atomicAdd(&gcur[b], len) : 0;
    }
    __syncthreads();

    for (int i = tid; i < cnt; i += 512) {
        uint2 u = srec[i];
        int b = u.y >> 22;
        int off = sbase[b] + (i - excl[b]);
        if (off < bcap) recs[(size_t)b * bcap + off] = u;
    }
}

// ================= Phase B: per-bucket 4B records + CSR + dinv (4 KB LDS) =================

__global__ __launch_bounds__(512) void k_sortb(
        const uint2* __restrict__ recs, const int* __restrict__ gcur, int bcap,
        unsigned* __restrict__ recs4, int* __restrict__ pstart,
        int* __restrict__ pcnt, float* __restrict__ dinv, int n) {
    __shared__ int hist[BS], excl[BS], curs[BS];
    __shared__ float wsum[BS];

    int b = blockIdx.x, tid = threadIdx.x;
    int cnt = min(gcur[b], bcap);
    const uint2* r = recs + (size_t)b * bcap;
    const float dq = 1.0f / WQ22;

    if (tid < BS) { hist[tid] = 0; wsum[tid] = 1.0f; }  // self-loop weight
    __syncthreads();

    for (int i = tid; i < cnt; i += 512) {
        uint2 u = r[i];
        int dl = u.x & 255;
        atomicAdd(&hist[dl], 1);
        atomicAdd(&wsum[dl], (float)(u.y & 4194303u) * dq);
    }
    __syncthreads();

    if (tid < BS) wsum[tid] = rsqrtf(wsum[tid]);  // -> dinv_d
    if (tid < 64) {
        int run = 0;
        for (int c = 0; c < BS; c += 64) {
            int idx = c + tid;
            int v = hist[idx];
            int incl = v;
#pragma unroll
            for (int o = 1; o < 64; o <<= 1) {
                int up = __shfl_up(incl, o, 64);
                if (tid >= o) incl += up;
            }
            int e = run + incl - v;
            excl[idx] = e; curs[idx] = e;
            run += __shfl(incl, 63, 64);
        }
    }
    __syncthreads();

    unsigned* out4 = recs4 + (size_t)b * bcap;
    for (int i = tid; i < cnt; i += 512) {
        uint2 u = r[i];
        int dl = u.x & 255;
        int pos = atomicAdd(&curs[dl], 1);
        float qn = (float)(u.y & 4194303u) * dq * wsum[dl];  // w * dinv_d
        unsigned q = (unsigned)(qn * WQ14 + 0.5f);
        if (q > 16383u) q = 16383u;
        out4[pos] = ((u.x >> 8) << 14) | q;
    }

    if (tid < BS) {
        int g = b * BS + tid;
        if (g < n) {
            pstart[g] = b * bcap + excl[tid];
            pcnt[g] = hist[tid];
            dinv[g] = wsum[tid];
        }
    }
}

// ====== prep (runs once): MFMA weight pack + gcur zero + y1 = x@W1 -> fp8 ======

__global__ __launch_bounds__(256) void k_prep(
        const float* __restrict__ wih1, const float* __restrict__ bih1,
        const float* __restrict__ bhh1, const float* __restrict__ wih2,
        const float* __restrict__ bih2, const float* __restrict__ bhh2,
        __half* __restrict__ wp1, __half* __restrict__ wp2,
        float* __restrict__ bsum1, float* __restrict__ bsum2,
        int* __restrict__ gcur, int NB,
        const float* __restrict__ x, const float* __restrict__ W1,
        unsigned char* __restrict__ y18, int n) {
    const int tg[6] = {0, 16, 64, 80, 96, 112};
    __shared__ float sW[128];
    int tid = threadIdx.x;
    if (tid < 128) sW[tid] = W1[tid];
    __syncthreads();

    int idx = blockIdx.x * 256 + tid;
    if (idx < 6144) {
        int t = idx >> 10, rem = idx & 1023;
        int kc = rem >> 9, rem2 = rem & 511;
        int lane = rem2 >> 3, j = rem2 & 7;
        int g = tg[t] + (lane & 15);
        int k = kc * 32 + (lane >> 4) * 8 + j;
        wp1[idx] = __float2half(wih1[g * 64 + k]);
    } else if (idx < 9216) {
        int i2 = idx - 6144;
        int t = i2 >> 9, rem2 = i2 & 511;
        int lane = rem2 >> 3, j = rem2 & 7;
        int g = tg[t] + (lane & 15);
        int k = (lane >> 4) * 8 + j;
        wp2[i2] = __float2half(wih2[g * 32 + k]);
    } else if (idx < 9344) {
        int i = idx - 9216;
        bsum1[i] = bih1[i] + bhh1[i];
    } else if (idx < 9472) {
        int i = idx - 9344;
        bsum2[i] = bih2[i] + bhh2[i];
    } else if (idx < 9472 + NB) {
        gcur[idx - 9472] = 0;
    } else if (idx >= 16384) {
        int j = idx - 16384;
        int node = j >> 2, lane = j & 3;
        if (node < n) {
            float4 xv = *(const float4*)(x + (size_t)node * 4);
            int fq = lane * 8;
            float o[8];
#pragma unroll
            for (int k = 0; k < 8; ++k)
                o[k] = xv.x * sW[fq + k] + xv.y * sW[32 + fq + k] +
                       xv.z * sW[64 + fq + k] + xv.w * sW[96 + fq + k];
            ((uint2*)(y18 + ((size_t)node << 5)))[lane] = enc8(o);
        }
    }
}

// ====== layer 1: fp8-row gather over y1 + BN + fused xw2 -> A8, skiph[0:32] ======

__global__ __launch_bounds__(256) void k_g1w2(
        const unsigned* __restrict__ recs4, const int* __restrict__ pstart,
        const int* __restrict__ pcnt, const float* __restrict__ dinv,
        const unsigned char* __restrict__ y18, const float* __restrict__ W2,
        const float* __restrict__ bias, const float* __restrict__ gamma,
        const float* __restrict__ beta, const float* __restrict__ mean,
        const float* __restrict__ var,
        __half* __restrict__ skiph, unsigned char* __restrict__ A8, int n) {
    __shared__ float sW2[1024];
    __shared__ float sh1[64][33];
    int tid = threadIdx.x;
    for (int i = tid; i < 1024; i += 256) sW2[i] = W2[i];
    __syncthreads();

    int nl = tid >> 2;
    int g = blockIdx.x * 64 + nl;
    int lane = tid & 3;
    int fq = lane * 8;
    bool act = g < n;

    float acc[8];
#pragma unroll
    for (int k = 0; k < 8; ++k) acc[k] = 0.0f;

    if (act) {
        float dig = dinv[g];
        float sl = dig * dig;
        {
            uint2 sr = ((const uint2*)(y18 + ((size_t)g << 5)))[lane];
            float f[8];
            dec8(sr, f);
#pragma unroll
            for (int k = 0; k < 8; ++k) acc[k] = sl * f[k];
        }

        const float qs = 1.0f / WQ14;
        int cn = pcnt[g];
        const unsigned* r = recs4 + pstart[g];
        int e = 0;
        for (; e + 8 <= cn; e += 8) {
            unsigned u[8];
            uint2 rw[8];
            float nm[8];
#pragma unroll
            for (int q = 0; q < 8; ++q) u[q] = r[e + q];
#pragma unroll
            for (int q = 0; q < 8; ++q)
                rw[q] = ((const uint2*)(y18 + ((size_t)(u[q] >> 14) << 5)))[lane];
#pragma unroll
            for (int q = 0; q < 8; ++q)
                nm[q] = (float)(u[q] & 16383u) * qs * dinv[u[q] >> 14];
#pragma unroll
            for (int q = 0; q < 8; ++q) {
                float f[8];
                dec8(rw[q], f);
#pragma unroll
                for (int k = 0; k < 8; ++k) acc[k] += nm[q] * f[k];
            }
        }
        for (; e < cn; ++e) {
            unsigned u0 = r[e];
            uint2 r0 = ((const uint2*)(y18 + ((size_t)(u0 >> 14) << 5)))[lane];
            float n0 = (float)(u0 & 16383u) * qs * dinv[u0 >> 14];
            float f[8];
            dec8(r0, f);
#pragma unroll
            for (int k = 0; k < 8; ++k) acc[k] += n0 * f[k];
        }
    }

    // h1 epilogue: bias + relu + BN; stage for xw2; emit fp16 skip slice
    float o[8];
#pragma unroll
    for (int k = 0; k < 8; ++k) {
        float v = fmaxf(acc[k] + bias[fq + k], 0.0f);
        o[k] = (v - mean[fq + k]) * gamma[fq + k] * rsqrtf(var[fq + k] + BN_EPS) + beta[fq + k];
        sh1[nl][fq + k] = o[k];
    }
    if (act) {
        union { __half h[8]; uint4 q; } hv;
#pragma unroll
        for (int k = 0; k < 8; ++k) hv.h[k] = __float2half(o[k]);
        *(uint4*)(skiph + (size_t)g * 64 + fq) = hv.q;
    }
    __syncthreads();

    // phase 2: A[g] = h1[g] @ W2 -> fp8
    if (act) {
        float a2[8];
#pragma unroll
        for (int j = 0; j < 8; ++j) a2[j] = 0.0f;
#pragma unroll 4
        for (int k = 0; k < 32; ++k) {
            float h = sh1[nl][k];
            const float* wr = sW2 + k * 32 + fq;
#pragma unroll
            for (int j = 0; j < 8; ++j) a2[j] += h * wr[j];
        }
        ((uint2*)(A8 + ((size_t)g << 5)))[lane] = enc8(a2);
    }
}

// ================= gather layer 2: fp8 A rows (32B) + fused epilogue =================

__global__ __launch_bounds__(256) void k_gather8(
        const unsigned* __restrict__ recs4, const int* __restrict__ pstart,
        const int* __restrict__ pcnt, const float* __restrict__ dinv,
        const unsigned char* __restrict__ A8,
        const float* __restrict__ bias, const float* __restrict__ gamma,
        const float* __restrict__ beta, const float* __restrict__ mean,
        const float* __restrict__ var,
        __half* __restrict__ skiph, int uoff, int n) {
    int g = blockIdx.x * 64 + (threadIdx.x >> 2);
    int lane = threadIdx.x & 3;
    if (g >= n) return;

    float dig = dinv[g];
    float sl = dig * dig;
    float acc[8];
    {
        uint2 sr = ((const uint2*)(A8 + ((size_t)g << 5)))[lane];
        float f[8];
        dec8(sr, f);
#pragma unroll
        for (int k = 0; k < 8; ++k) acc[k] = sl * f[k];
    }

    const float qs = 1.0f / WQ14;
    int cn = pcnt[g];
    const unsigned* r = recs4 + pstart[g];
    int e = 0;
    for (; e + 8 <= cn; e += 8) {
        unsigned u[8];
        uint2 rw[8];
        float nm[8];
#pragma unroll
        for (int q = 0; q < 8; ++q) u[q] = r[e + q];
#pragma unroll
        for (int q = 0; q < 8; ++q)
            rw[q] = ((const uint2*)(A8 + ((size_t)(u[q] >> 14) << 5)))[lane];
#pragma unroll
        for (int q = 0; q < 8; ++q)
            nm[q] = (float)(u[q] & 16383u) * qs * dinv[u[q] >> 14];
#pragma unroll
        for (int q = 0; q < 8; ++q) {
            float f[8];
            dec8(rw[q], f);
#pragma unroll
            for (int k = 0; k < 8; ++k) acc[k] += nm[q] * f[k];
        }
    }
    for (; e < cn; ++e) {
        unsigned u0 = r[e];
        uint2 r0 = ((const uint2*)(A8 + ((size_t)(u0 >> 14) << 5)))[lane];
        float n0 = (float)(u0 & 16383u) * qs * dinv[u0 >> 14];
        float f0[8];
        dec8(r0, f0);
#pragma unroll
        for (int k = 0; k < 8; ++k) acc[k] += n0 * f0[k];
    }

    int fq = lane * 8;
    union { __half h[8]; uint4 q; } hv;
#pragma unroll
    for (int k = 0; k < 8; ++k) {
        float v = fmaxf(acc[k] + bias[fq + k], 0.0f);
        hv.h[k] = __float2half((v - mean[fq + k]) * gamma[fq + k] * rsqrtf(var[fq + k] + BN_EPS) + beta[fq + k]);
    }
    *(uint4*)(skiph + (size_t)g * 64 + uoff + fq) = hv.q;
}

// ================= MFMA fused head: LSTM1 + LSTM2 + linear =================

__global__ __launch_bounds__(256) void k_headm(
        const __half* __restrict__ skiph, const float* __restrict__ x,
        const __half* __restrict__ wp1, const __half* __restrict__ wp2,
        const float* __restrict__ bsum1, const float* __restrict__ bsum2,
        const float* __restrict__ lw, const float* __restrict__ lb,
        float* __restrict__ out, int n) {
    __shared__ __align__(16) __half H1lds[4 * 16 * 40];
    int tid = threadIdx.x;
    int w = tid >> 6, l = tid & 63;
    int quad = l >> 4, c = l & 15;
    int node_base = blockIdx.x * 64 + w * 16;

    int arow = node_base + c; if (arow > n - 1) arow = n - 1;
    const half8* ap = (const half8*)(skiph + (size_t)arow * 64);
    half8 a0 = ap[quad];
    half8 a1 = ap[4 + quad];

    const half8* b1 = (const half8*)wp1;
    f32x4 d[6];
#pragma unroll
    for (int t = 0; t < 6; ++t) {
        f32x4 acc = {0.0f, 0.0f, 0.0f, 0.0f};
        acc = __builtin_amdgcn_mfma_f32_16x16x32_f16(a0, b1[(t * 2 + 0) * 64 + l], acc, 0, 0, 0);
        acc = __builtin_amdgcn_mfma_f32_16x16x32_f16(a1, b1[(t * 2 + 1) * 64 + l], acc, 0, 0, 0);
        d[t] = acc;
    }

    float bi0 = bsum1[c],      bi1 = bsum1[16 + c];
    float bg0 = bsum1[64 + c], bg1 = bsum1[80 + c];
    float bo0 = bsum1[96 + c], bo1 = bsum1[112 + c];
    float lwc0 = lw[c], lwc1 = lw[c + 16];

    float pa[4];
#pragma unroll
    for (int r = 0; r < 4; ++r) {
        float cc0 = fsig(d[0][r] + bi0) * ftanh(d[2][r] + bg0);
        float h0 = fsig(d[4][r] + bo0) * ftanh(cc0);
        float cc1 = fsig(d[1][r] + bi1) * ftanh(d[3][r] + bg1);
        float h1 = fsig(d[5][r] + bo1) * ftanh(cc1);
        pa[r] = fmaxf(h0, 0.0f) * lwc0 + fmaxf(h1, 0.0f) * lwc1;
        __half* hp = H1lds + (w * 16 + quad * 4 + r) * 40;
        hp[c] = __float2half(h0);
        hp[c + 16] = __float2half(h1);
    }
    __syncthreads();

    half8 a2 = *(const half8*)(H1lds + (w * 16 + c) * 40 + quad * 8);

    const half8* b2 = (const half8*)wp2;
    f32x4 e[6];
#pragma unroll
    for (int t = 0; t < 6; ++t) {
        f32x4 acc = {0.0f, 0.0f, 0.0f, 0.0f};
        e[t] = __builtin_amdgcn_mfma_f32_16x16x32_f16(a2, b2[t * 64 + l], acc, 0, 0, 0);
    }

    float ci0 = bsum2[c],      ci1 = bsum2[16 + c];
    float cg0 = bsum2[64 + c], cg1 = bsum2[80 + c];
    float co0 = bsum2[96 + c], co1 = bsum2[112 + c];
    float lw2c0 = lw[32 + c], lw2c1 = lw[48 + c];
#pragma unroll
    for (int r = 0; r < 4; ++r) {
        float cc0 = fsig(e[0][r] + ci0) * ftanh(e[2][r] + cg0);
        float h0 = fsig(e[4][r] + co0) * ftanh(cc0);
        float cc1 = fsig(e[1][r] + ci1) * ftanh(e[3][r] + cg1);
        float h1 = fsig(e[5][r] + co1) * ftanh(cc1);
        pa[r] += fmaxf(h0, 0.0f) * lw2c0 + fmaxf(h1, 0.0f) * lw2c1;
    }

#pragma unroll
    for (int m = 1; m < 16; m <<= 1) {
#pragma unroll
        for (int r = 0; r < 4; ++r) pa[r] += __shfl_xor(pa[r], m, 64);
    }

    if (c < 4) {
        int node = node_base + quad * 4 + c;
        if (node < n) {
            const float4 xv = *(const float4*)(x + (size_t)node * 4);
            out[node] = pa[c] + lb[0]
                + fmaxf(xv.x, 0.0f) * lw[64] + fmaxf(xv.y, 0.0f) * lw[65]
                + fmaxf(xv.z, 0.0f) * lw[66] + fmaxf(xv.w, 0.0f) * lw[67];
        }
    }
}

// ================= fallback (atomic scatter, fp32) =================

__global__ void k_initdeg(float* __restrict__ deg, int n) {
    int i = blockIdx.x * blockDim.x + threadIdx.x;
    if (i < n) deg[i] = 1.0f;
}

__global__ void k_deg_only(const int* __restrict__ dst, const float* __restrict__ ew,
                           float* __restrict__ deg, int E) {
    int e = blockIdx.x * blockDim.x + threadIdx.x;
    if (e < E) atomicAdd(&deg[dst[e]], ew[e]);
}

__global__ void k_dinv_f(float* __restrict__ deg, int n) {
    int i = blockIdx.x * blockDim.x + threadIdx.x;
    if (i < n) {
        float d = deg[i];
        deg[i] = d > 0.0f ? rsqrtf(d) : 0.0f;
    }
}

__global__ void k_xw1_f(const float* __restrict__ x, const float* __restrict__ W,
                        float* __restrict__ out, int n) {
    int idx = blockIdx.x * blockDim.x + threadIdx.x;
    if (idx >= n * HF) return;
    int nn = idx >> 5, f = idx & 31;
    const float4 xr = *(const float4*)(x + (size_t)nn * 4);
    out[idx] = xr.x * W[f] + xr.y * W[32 + f] + xr.z * W[64 + f] + xr.w * W[96 + f];
}

__global__ void k_xw2_f(const float* __restrict__ Hin, const float* __restrict__ W,
                        float* __restrict__ out, int n) {
    __shared__ float sW[32 * 32];
    __shared__ float sH[8][32];
    int tid = threadIdx.x;
    for (int i = tid; i < 1024; i += 256) sW[i] = W[i];
    int r = tid >> 5, f = tid & 31;
    int nn = blockIdx.x * 8 + r;
    if (nn < n) sH[r][f] = Hin[(size_t)nn * HF + f];
    __syncthreads();
    if (nn >= n) return;
    float acc = 0.0f;
#pragma unroll
    for (int k = 0; k < 32; ++k) acc += sH[r][k] * sW[k * 32 + f];
    out[(size_t)nn * HF + f] = acc;
}

__global__ void k_selfloop(const float* __restrict__ A, const float* __restrict__ dinv,
                           float* __restrict__ B, int n) {
    int idx = blockIdx.x * blockDim.x + threadIdx.x;
    if (idx >= n * HF) return;
    int nn = idx >> 5;
    float di = dinv[nn];
    B[idx] = di * di * A[idx];
}

__global__ void k_scatter(const int* __restrict__ src, const int* __restrict__ dst,
                          const float* __restrict__ ew, const float* __restrict__ dinv,
                          const float* __restrict__ A, float* __restrict__ B, int total) {
    int idx = blockIdx.x * blockDim.x + threadIdx.x;
    if (idx >= total) return;
    int e = idx >> 5, f = idx & 31;
    int s = src[e], d = dst[e];
    float norm = dinv[s] * ew[e] * dinv[d];
    atomicAdd(&B[d * HF + f], norm * A[s * HF + f]);
}

__global__ void k_post(const float* __restrict__ B, const float* __restrict__ bias,
                       const float* __restrict__ gamma, const float* __restrict__ beta,
                       const float* __restrict__ mean, const float* __restrict__ var,
                       float* __restrict__ Hout, int n) {
    int idx = blockIdx.x * blockDim.x + threadIdx.x;
    if (idx >= n * HF) return;
    int f = idx & 31;
    float v = fmaxf(B[idx] + bias[f], 0.0f);
    float sc = gamma[f] * rsqrtf(var[f] + BN_EPS);
    Hout[idx] = (v - mean[f]) * sc + beta[f];
}

__global__ __launch_bounds__(256) void k_head(
        const float* __restrict__ h1, const float* __restrict__ h2,
        const float* __restrict__ x,
        const float* __restrict__ wih1, const float* __restrict__ bih1, const float* __restrict__ bhh1,
        const float* __restrict__ wih2, const float* __restrict__ bih2, const float* __restrict__ bhh2,
        const float* __restrict__ lw, const float* __restrict__ lb,
        float* __restrict__ out, int n) {
    __shared__ float sH1[32 * 256];
    int tid = threadIdx.x;
    int nn = blockIdx.x * 256 + tid;
    if (nn >= n) return;

    const float4* a = (const float4*)(h1 + (size_t)nn * HF);
    const float4* b = (const float4*)(h2 + (size_t)nn * HF);
    float skip[64];
#pragma unroll
    for (int q = 0; q < 8; ++q) {
        float4 v = a[q];
        skip[4 * q] = v.x; skip[4 * q + 1] = v.y; skip[4 * q + 2] = v.z; skip[4 * q + 3] = v.w;
        float4 u = b[q];
        skip[32 + 4 * q] = u.x; skip[33 + 4 * q] = u.y; skip[34 + 4 * q] = u.z; skip[35 + 4 * q] = u.w;
    }

    float oa = lb[0];
#pragma unroll 1
    for (int j = 0; j < 32; ++j) {
        const float4* wi = (const float4*)(wih1 + (size_t)j * 64);
        const float4* wg = (const float4*)(wih1 + (size_t)(64 + j) * 64);
        const float4* wo = (const float4*)(wih1 + (size_t)(96 + j) * 64);
        float gi = bih1[j] + bhh1[j];
        float gg = bih1[64 + j] + bhh1[64 + j];
        float go = bih1[96 + j] + bhh1[96 + j];
#pragma unroll
        for (int q = 0; q < 16; ++q) {
            float4 aa = wi[q], bb = wg[q], cc4 = wo[q];
            float s0 = skip[4 * q], s1 = skip[4 * q + 1], s2 = skip[4 * q + 2], s3 = skip[4 * q + 3];
            gi += aa.x * s0 + aa.y * s1 + aa.z * s2 + aa.w * s3;
            gg += bb.x * s0 + bb.y * s1 + bb.z * s2 + bb.w * s3;
            go += cc4.x * s0 + cc4.y * s1 + cc4.z * s2 + cc4.w * s3;
        }
        float cc = fsig(gi) * ftanh(gg);
        float hh = fsig(go) * ftanh(cc);
        sH1[j * 256 + tid] = hh;
        oa += fmaxf(hh, 0.0f) * lw[j];
    }

#pragma unroll 1
    for (int j = 0; j < 32; ++j) {
        const float4* wi = (const float4*)(wih2 + (size_t)j * 32);
        const float4* wg = (const float4*)(wih2 + (size_t)(64 + j) * 32);
        const float4* wo = (const float4*)(wih2 + (size_t)(96 + j) * 32);
        float gi = bih2[j] + bhh2[j];
        float gg = bih2[64 + j] + bhh2[64 + j];
        float go = bih2[96 + j] + bhh2[96 + j];
#pragma unroll
        for (int q = 0; q < 8; ++q) {
            float4 aa = wi[q], bb = wg[q], cc4 = wo[q];
            float s0 = sH1[(4 * q) * 256 + tid], s1 = sH1[(4 * q + 1) * 256 + tid];
            float s2 = sH1[(4 * q + 2) * 256 + tid], s3 = sH1[(4 * q + 3) * 256 + tid];
            gi += aa.x * s0 + aa.y * s1 + aa.z * s2 + aa.w * s3;
            gg += bb.x * s0 + bb.y * s1 + bb.z * s2 + bb.w * s3;
            go += cc4.x * s0 + cc4.y * s1 + cc4.z * s2 + cc4.w * s3;
        }
        float cc = fsig(gi) * ftanh(gg);
        float hh = fsig(go) * ftanh(cc);
        oa += fmaxf(hh, 0.0f) * lw[32 + j];
    }

    const float4 xv = *(const float4*)(x + (size_t)nn * 4);
    oa += fmaxf(xv.x, 0.0f) * lw[64] + fmaxf(xv.y, 0.0f) * lw[65] +
          fmaxf(xv.z, 0.0f) * lw[66] + fmaxf(xv.w, 0.0f) * lw[67];
    out[nn] = oa;
}

// ================= launch =================

extern "C" void kernel_launch(void* const* d_in, const int* in_sizes, int n_in,
                              void* d_out, int out_size, void* d_ws, size_t ws_size,
                              hipStream_t stream) {
    const float* x   = (const float*)d_in[0];
    const int*   ei  = (const int*)d_in[1];
    const float* ew  = (const float*)d_in[2];
    const float* g1w = (const float*)d_in[3];
    const float* g1b = (const float*)d_in[4];
    const float* g2w = (const float*)d_in[5];
    const float* g2b = (const float*)d_in[6];
    const float* bn1g = (const float*)d_in[7];
    const float* bn1b = (const float*)d_in[8];
    const float* bn1m = (const float*)d_in[9];
    const float* bn1v = (const float*)d_in[10];
    const float* bn2g = (const float*)d_in[11];
    const float* bn2b = (const float*)d_in[12];
    const float* bn2m = (const float*)d_in[13];
    const float* bn2v = (const float*)d_in[14];
    const float* w1ih = (const float*)d_in[15];
    const float* b1ih = (const float*)d_in[17];
    const float* b1hh = (const float*)d_in[18];
    const float* w2ih = (const float*)d_in[19];
    const float* b2ih = (const float*)d_in[21];
    const float* b2hh = (const float*)d_in[22];
    const float* lw   = (const float*)d_in[23];
    const float* lb   = (const float*)d_in[24];
    float* out = (float*)d_out;

    const int N = in_sizes[0] / 4;
    const int E = in_sizes[2];
    const int* src = ei;
    const int* dst = ei + E;

    const int T = 256;
    const int NB = (N + BS - 1) / BS;
    long long meanb = ((long long)BS * E) / (N > 0 ? N : 1);
    int bcap = (int)(meanb + meanb / 4 + 128);

    // workspace layout (256B-aligned regions)
    char* p = (char*)d_ws;
    auto alloc = [&](size_t bytes) { char* q = p; p += (bytes + 255) & ~(size_t)255; return q; };
    int*      gcur   = (int*)alloc(sizeof(int) * NB);
    uint2*    recs   = (uint2*)alloc(sizeof(uint2) * (size_t)NB * bcap);
    unsigned* recs4  = (unsigned*)alloc(sizeof(unsigned) * (size_t)NB * bcap);
    float*    dinv   = (float*)alloc(sizeof(float) * N);
    int*      pstart = (int*)alloc(sizeof(int) * N);
    int*      pcnt   = (int*)alloc(sizeof(int) * N);
    unsigned char* y18 = (unsigned char*)alloc((size_t)N * HF);         // fp8 x@W1
    unsigned char* A8  = (unsigned char*)alloc((size_t)N * HF);         // fp8 h1@W2
    __half*   skiph  = (__half*)alloc(sizeof(__half) * (size_t)N * 64); // h1|h2 f16
    __half*   wp1    = (__half*)alloc(sizeof(__half) * 6144);
    __half*   wp2    = (__half*)alloc(sizeof(__half) * 3072);
    float*    bsum1  = (float*)alloc(sizeof(float) * 128);
    float*    bsum2  = (float*)alloc(sizeof(float) * 128);
    size_t need = (size_t)(p - (char*)d_ws);

    int bN  = (N + T - 1) / T;
    int bE  = (E + T - 1) / T;
    int bNF = (N * HF + T - 1) / T;
    int bN8 = (N + 7) / 8;
    int bG  = (N + 63) / 64;
    int bBin = (E + KEDGE - 1) / KEDGE;
    int bPrep = (16384 + 4 * N + 255) / 256;

    if (ws_size >= need && NB <= MAXNB && N <= (1 << 18)) {
        // ---- build + prep ----
        k_prep<<<bPrep, 256, 0, stream>>>(w1ih, b1ih, b1hh, w2ih, b2ih, b2hh,
                                          wp1, wp2, bsum1, bsum2, gcur, NB,
                                          x, g1w, y18, N);
        k_binsort<<<bBin, 512, 0, stream>>>(src, dst, ew, E, NB, bcap, gcur, recs);
        k_sortb<<<NB, 512, 0, stream>>>(recs, gcur, bcap, recs4, pstart, pcnt, dinv, N);

        // ---- layer 1: fp8 gather over y1 + fused xw2 -> skiph[0:32], A8 ----
        k_g1w2<<<bG, T, 0, stream>>>(recs4, pstart, pcnt, dinv, y18, g2w,
                                     g1b, bn1g, bn1b, bn1m, bn1v, skiph, A8, N);
        // ---- layer 2: fp8 gather -> skiph[32:64] ----
        k_gather8<<<bG, T, 0, stream>>>(recs4, pstart, pcnt, dinv, A8,
                                        g2b, bn2g, bn2b, bn2m, bn2v, skiph, 32, N);
        // ---- MFMA head ----
        k_headm<<<bG, T, 0, stream>>>(skiph, x, wp1, wp2, bsum1, bsum2,
                                      lw, lb, out, N);
    } else {
        // ---- fallback: atomic scatter, fp32 ----
        size_t Npad = ((size_t)N + 255) & ~(size_t)255;
        float* fdinv = (float*)d_ws;
        float* fA = fdinv + Npad;
        float* fB = fA + (size_t)N * HF;
        float* fC = fB + (size_t)N * HF;
        int bEF = (int)(((long long)E * HF + T - 1) / T);
        int bH = (N + 255) / 256;

        k_initdeg<<<bN, T, 0, stream>>>(fdinv, N);
        k_deg_only<<<bE, T, 0, stream>>>(dst, ew, fdinv, E);
        k_dinv_f<<<bN, T, 0, stream>>>(fdinv, N);

        k_xw1_f<<<bNF, T, 0, stream>>>(x, g1w, fA, N);
        k_selfloop<<<bNF, T, 0, stream>>>(fA, fdinv, fB, N);
        k_scatter<<<bEF, T, 0, stream>>>(src, dst, ew, fdinv, fA, fB, E * HF);
        k_post<<<bNF, T, 0, stream>>>(fB, g1b, bn1g, bn1b, bn1m, bn1v, fC, N);

        k_xw2_f<<<bN8, T, 0, stream>>>(fC, g2w, fA, N);
        k_selfloop<<<bNF, T, 0, stream>>>(fA, fdinv, fB, N);
        k_scatter<<<bEF, T, 0, stream>>>(src, dst, ew, fdinv, fA, fB, E * HF);
        k_post<<<bNF, T, 0, stream>>>(fB, g2b, bn2g, bn2b, bn2m, bn2v, fB, N);

        k_head<<<bH, T, 0, stream>>>(fC, fB, x, w1ih, b1ih, b1hh, w2ih, b2ih, b2hh,
                                     lw, lb, out, N);
    }
}